// Round 8
// baseline (791.099 us; speedup 1.0000x reference)
//
#include <hip/hip_runtime.h>
#include <math.h>

#define NT 65536
#define DH 256
#define DO 128
#define NE 16

struct RInfo { int e1, e2; float s1, s2; };

typedef __attribute__((ext_vector_type(8))) short bh8;   // 8 bf16 (4 VGPR)
typedef __attribute__((ext_vector_type(4))) float fx4;   // MFMA acc

static __device__ __forceinline__ short f2bf(float f) {
    union { float f; unsigned u; } v; v.f = f;
    return (short)((v.u + 0x7FFFu + ((v.u >> 16) & 1u)) >> 16);   // RNE
}

// ------------------------------------------------------------------
// fp32 dense GEMM (gate-critical layer 0). FMA order identical to R3/R4
// -> bit-exact. Register-prefetch pipeline: loads for K-step t+1 issue
// before compute of step t (no arithmetic change).
// ------------------------------------------------------------------
template<bool RELU>
__global__ __launch_bounds__(256)
void gemm_dense(const float* __restrict__ A, const float* __restrict__ B,
                const float* __restrict__ bias, float* __restrict__ C,
                int ncols)
{
    __shared__ float As[128][36];
    __shared__ float Bs[32][132];
    const int tid = threadIdx.x;
    const int tx = tid & 15, ty = tid >> 4;
    const int rowBase = blockIdx.x * 128;
    const int colBase = blockIdx.y * 128;

    const int ra = tid >> 3, k4a = (tid & 7) << 2;     // A staging coords
    const int krb = tid >> 5, c4b = (tid & 31) << 2;   // B staging coords

    float4 apre[4], bpre[4];
#pragma unroll
    for (int it = 0; it < 4; ++it)
        apre[it] = *reinterpret_cast<const float4*>(
            &A[(size_t)(rowBase + ra + 32 * it) * DH + k4a]);
#pragma unroll
    for (int it = 0; it < 4; ++it)
        bpre[it] = *reinterpret_cast<const float4*>(
            &B[(size_t)(krb + 8 * it) * ncols + colBase + c4b]);

    float acc[8][8];
#pragma unroll
    for (int i = 0; i < 8; ++i)
#pragma unroll
        for (int j = 0; j < 8; ++j) acc[i][j] = 0.f;

    for (int kt = 0; kt < DH; kt += 32) {
#pragma unroll
        for (int it = 0; it < 4; ++it)
            *reinterpret_cast<float4*>(&As[ra + 32 * it][k4a]) = apre[it];
#pragma unroll
        for (int it = 0; it < 4; ++it)
            *reinterpret_cast<float4*>(&Bs[krb + 8 * it][c4b]) = bpre[it];
        __syncthreads();
        if (kt + 32 < DH) {   // issue next-step loads early; latency hides under compute
            const int kn = kt + 32;
#pragma unroll
            for (int it = 0; it < 4; ++it)
                apre[it] = *reinterpret_cast<const float4*>(
                    &A[(size_t)(rowBase + ra + 32 * it) * DH + kn + k4a]);
#pragma unroll
            for (int it = 0; it < 4; ++it)
                bpre[it] = *reinterpret_cast<const float4*>(
                    &B[(size_t)(kn + krb + 8 * it) * ncols + colBase + c4b]);
        }
#pragma unroll
        for (int k4 = 0; k4 < 32; k4 += 4) {
            alignas(16) float ar[8][4];
#pragma unroll
            for (int i = 0; i < 8; ++i)
                *reinterpret_cast<float4*>(ar[i]) =
                    *reinterpret_cast<const float4*>(&As[ty * 8 + i][k4]);
#pragma unroll
            for (int kk = 0; kk < 4; ++kk) {
                alignas(16) float br[8];
                *reinterpret_cast<float4*>(&br[0]) =
                    *reinterpret_cast<const float4*>(&Bs[k4 + kk][tx * 8]);
                *reinterpret_cast<float4*>(&br[4]) =
                    *reinterpret_cast<const float4*>(&Bs[k4 + kk][tx * 8 + 4]);
#pragma unroll
                for (int i = 0; i < 8; ++i) {
                    const float a = ar[i][kk];
#pragma unroll
                    for (int j = 0; j < 8; ++j)
                        acc[i][j] = fmaf(a, br[j], acc[i][j]);
                }
            }
        }
        __syncthreads();
    }
    alignas(16) float bb[8];
#pragma unroll
    for (int j = 0; j < 8; ++j) bb[j] = bias[colBase + tx * 8 + j];
#pragma unroll
    for (int i = 0; i < 8; ++i) {
        const size_t row = rowBase + ty * 8 + i;
        alignas(16) float o[8];
#pragma unroll
        for (int j = 0; j < 8; ++j) {
            float v = acc[i][j] + bb[j];
            if (RELU) v = fmaxf(v, 0.f);
            o[j] = v;
        }
        float* p = &C[row * (size_t)ncols + colBase + tx * 8];
        *reinterpret_cast<float4*>(p)     = *reinterpret_cast<float4*>(&o[0]);
        *reinterpret_cast<float4*>(p + 4) = *reinterpret_cast<float4*>(&o[4]);
    }
}

// ------------------------------------------------------------------
// Gate (unchanged numerics from R3..R6)
// ------------------------------------------------------------------
__global__ __launch_bounds__(256)
void gate_kernel(const float* __restrict__ H, const float* __restrict__ Wg,
                 const float* __restrict__ bg, RInfo* __restrict__ info,
                 float* gsum)
{
    __shared__ float wgs[256][17];
    __shared__ float hs[16][260];
    __shared__ float lg[16][17];
    __shared__ float sbg[16];
    __shared__ float sds[16];
    const int tid = threadIdx.x;
    const int rowBase = blockIdx.x * 16;

#pragma unroll
    for (int i = 0; i < 16; ++i) {
        const int idx = tid + 256 * i;
        wgs[idx >> 4][idx & 15] = Wg[idx];
    }
    if (tid < 16) sbg[tid] = bg[tid];
#pragma unroll
    for (int it = 0; it < 4; ++it) {
        const int flat = (tid + 256 * it) * 4;
        const int r = flat >> 8, k = flat & 255;
        *reinterpret_cast<float4*>(&hs[r][k]) =
            *reinterpret_cast<const float4*>(&H[(size_t)(rowBase + r) * DH + k]);
    }
    __syncthreads();
    {
        const int r = tid >> 4, e = tid & 15;
        float acc = 0.f;
#pragma unroll 8
        for (int k = 0; k < 256; ++k) acc = fmaf(hs[r][k], wgs[k][e], acc);
        lg[r][e] = acc + sbg[e];
    }
    __syncthreads();
    if (tid < 16) {
        const int row = rowBase + tid;
        float l[16];
#pragma unroll
        for (int i = 0; i < 16; ++i) l[i] = lg[tid][i];
        int i1 = 0; float v1 = l[0];
#pragma unroll
        for (int i = 1; i < 16; ++i) if (l[i] > v1) { v1 = l[i]; i1 = i; }
        int i2 = -1; float v2 = -INFINITY;
#pragma unroll
        for (int i = 0; i < 16; ++i) if (i != i1 && l[i] > v2) { v2 = l[i]; i2 = i; }
        const float t = expf(v2 - v1);
        const float s1 = 1.f / (1.f + t);
        const float s2 = t / (1.f + t);
        float p[16]; float S = 0.f;
#pragma unroll
        for (int i = 0; i < 16; ++i) { p[i] = expf(l[i] - v1); S += p[i]; }
        const float inv = 1.f / S;
        float sq = 0.f;
#pragma unroll
        for (int i = 0; i < 16; ++i) { const float q = p[i] * inv; sq = fmaf(q, q, sq); }
        const float var = (sq - 1.0f / 16.0f) * (1.0f / 15.0f);
        const float sd = sqrtf(fmaxf(var, 0.f));

        RInfo ri; ri.e1 = i1; ri.e2 = i2; ri.s1 = s1; ri.s2 = s2;
        info[row] = ri;
        sds[tid] = sd;
    }
    __syncthreads();
    if (tid == 0) {
        float s = 0.f;
#pragma unroll
        for (int i = 0; i < 16; ++i) s += sds[i];
        atomicAdd(gsum, s);
    }
}

__global__ void zero_gsum(float* gsum)
{
    if (threadIdx.x < 2) gsum[threadIdx.x] = 0.f;
}

// ------------------------------------------------------------------
// Bucketing (unchanged)
// ------------------------------------------------------------------
__global__ __launch_bounds__(256)
void count_kernel(const RInfo* __restrict__ info, int* __restrict__ bc0,
                  int* __restrict__ bc1)
{
    __shared__ int h0[NE], h1[NE];
    const int tid = threadIdx.x, b = blockIdx.x;
    if (tid < NE) { h0[tid] = 0; h1[tid] = 0; }
    __syncthreads();
    const RInfo ri = info[b * 256 + tid];
    atomicAdd(&h0[ri.e1], 1);
    atomicAdd(&h1[ri.e2], 1);
    __syncthreads();
    if (tid < NE) {
        bc0[tid * 256 + b] = h0[tid];
        bc1[tid * 256 + b] = h1[tid];
    }
}

__global__ void scan2_kernel(const int* __restrict__ bc0, const int* __restrict__ bc1,
                             int* cnt0, int* cnt1, int* off0, int* off1,
                             int* __restrict__ bo0, int* __restrict__ bo1)
{
    __shared__ int tot0[NE], tot1[NE], base0[NE], base1[NE];
    const int t = threadIdx.x;
    if (t < NE) {
        int s = 0;
        for (int b = 0; b < 256; ++b) s += bc0[t * 256 + b];
        tot0[t] = s; cnt0[t] = s;
    } else if (t < 2 * NE) {
        const int e = t - NE;
        int s = 0;
        for (int b = 0; b < 256; ++b) s += bc1[e * 256 + b];
        tot1[e] = s; cnt1[e] = s;
    }
    __syncthreads();
    if (t == 0) { int a = 0; for (int e = 0; e < NE; ++e) { base0[e] = a; off0[e] = a; a += tot0[e]; } }
    if (t == 1) { int a = 0; for (int e = 0; e < NE; ++e) { base1[e] = a; off1[e] = a; a += tot1[e]; } }
    __syncthreads();
    if (t < NE) {
        int run = base0[t];
        for (int b = 0; b < 256; ++b) { bo0[t * 256 + b] = run; run += bc0[t * 256 + b]; }
    } else if (t < 2 * NE) {
        const int e = t - NE;
        int run = base1[e];
        for (int b = 0; b < 256; ++b) { bo1[e * 256 + b] = run; run += bc1[e * 256 + b]; }
    }
}

__global__ __launch_bounds__(256)
void scatter2_kernel(const RInfo* __restrict__ info, const int* __restrict__ bo0,
                     const int* __restrict__ bo1, int* __restrict__ l0,
                     int* __restrict__ l1)
{
    __shared__ int h0[NE], h1[NE];
    const int tid = threadIdx.x, b = blockIdx.x;
    if (tid < NE) { h0[tid] = 0; h1[tid] = 0; }
    __syncthreads();
    const int r = b * 256 + tid;
    const RInfo ri = info[r];
    const int p0 = atomicAdd(&h0[ri.e1], 1);
    const int p1 = atomicAdd(&h1[ri.e2], 1);
    l0[bo0[ri.e1 * 256 + b] + p0] = r;
    l1[bo1[ri.e2 * 256 + b] + p1] = r;
}

// ------------------------------------------------------------------
// fp32 grouped expert GEMM (MoE layer 1, gate-critical). FMA order
// unchanged -> bit-exact. Register-prefetch pipeline + hoisted row bases.
// SLOT 0: P[g] = s1*(h@We+be); SLOT 1: P[g] = relu(P[g] + s2*(h@We+be))
// ------------------------------------------------------------------
template<int SLOT>
__global__ __launch_bounds__(256)
void gemm_expert(const float* __restrict__ Hin, const float* __restrict__ We,
                 const float* __restrict__ be, const RInfo* __restrict__ info,
                 const int* __restrict__ list, const int* __restrict__ cnts,
                 const int* __restrict__ offs, float* __restrict__ P)
{
    __shared__ float As[128][36];
    __shared__ float Bs[32][132];
    __shared__ int   rs[128];
    __shared__ float ss[128];

    int c = blockIdx.x, e;
    int cnt = 0;
    for (e = 0; e < NE; ++e) {
        cnt = cnts[e];
        const int nch = (cnt + 127) >> 7;
        if (c < nch) break;
        c -= nch;
    }
    if (e >= NE) return;
    const int m = min(128, cnt - c * 128);
    const int base = offs[e] + c * 128;
    const int tid = threadIdx.x;
    const int tx = tid & 15, ty = tid >> 4;
    const int colBase = blockIdx.y * 128;

    if (tid < 128) {
        const int g = list[base + min(tid, m - 1)];
        rs[tid] = g;
        const RInfo ri = info[g];
        ss[tid] = (SLOT == 0) ? ri.s1 : ri.s2;
    }
    __syncthreads();

    const float* B = We + (size_t)e * DH * DH;
    const int ra = tid >> 3, k4a = (tid & 7) << 2;
    const int krb = tid >> 5, c4b = (tid & 31) << 2;

    size_t abase[4];
#pragma unroll
    for (int it = 0; it < 4; ++it) abase[it] = (size_t)rs[ra + 32 * it] * DH;

    float4 apre[4], bpre[4];
#pragma unroll
    for (int it = 0; it < 4; ++it)
        apre[it] = *reinterpret_cast<const float4*>(&Hin[abase[it] + k4a]);
#pragma unroll
    for (int it = 0; it < 4; ++it)
        bpre[it] = *reinterpret_cast<const float4*>(
            &B[(size_t)(krb + 8 * it) * DH + colBase + c4b]);

    float acc[8][8];
#pragma unroll
    for (int i = 0; i < 8; ++i)
#pragma unroll
        for (int j = 0; j < 8; ++j) acc[i][j] = 0.f;

    for (int kt = 0; kt < DH; kt += 32) {
#pragma unroll
        for (int it = 0; it < 4; ++it)
            *reinterpret_cast<float4*>(&As[ra + 32 * it][k4a]) = apre[it];
#pragma unroll
        for (int it = 0; it < 4; ++it)
            *reinterpret_cast<float4*>(&Bs[krb + 8 * it][c4b]) = bpre[it];
        __syncthreads();
        if (kt + 32 < DH) {
            const int kn = kt + 32;
#pragma unroll
            for (int it = 0; it < 4; ++it)
                apre[it] = *reinterpret_cast<const float4*>(&Hin[abase[it] + kn + k4a]);
#pragma unroll
            for (int it = 0; it < 4; ++it)
                bpre[it] = *reinterpret_cast<const float4*>(
                    &B[(size_t)(kn + krb + 8 * it) * DH + colBase + c4b]);
        }
#pragma unroll
        for (int k4 = 0; k4 < 32; k4 += 4) {
            alignas(16) float ar[8][4];
#pragma unroll
            for (int i = 0; i < 8; ++i)
                *reinterpret_cast<float4*>(ar[i]) =
                    *reinterpret_cast<const float4*>(&As[ty * 8 + i][k4]);
#pragma unroll
            for (int kk = 0; kk < 4; ++kk) {
                alignas(16) float br[8];
                *reinterpret_cast<float4*>(&br[0]) =
                    *reinterpret_cast<const float4*>(&Bs[k4 + kk][tx * 8]);
                *reinterpret_cast<float4*>(&br[4]) =
                    *reinterpret_cast<const float4*>(&Bs[k4 + kk][tx * 8 + 4]);
#pragma unroll
                for (int i = 0; i < 8; ++i) {
                    const float a = ar[i][kk];
#pragma unroll
                    for (int j = 0; j < 8; ++j)
                        acc[i][j] = fmaf(a, br[j], acc[i][j]);
                }
            }
        }
        __syncthreads();
    }

    alignas(16) float bb[8];
#pragma unroll
    for (int j = 0; j < 8; ++j) bb[j] = be[(size_t)e * DH + colBase + tx * 8 + j];
#pragma unroll
    for (int i = 0; i < 8; ++i) {
        const int rl = ty * 8 + i;
        if (rl < m) {
            const int g = rs[rl];
            const float s = ss[rl];
            alignas(16) float o[8];
#pragma unroll
            for (int j = 0; j < 8; ++j) o[j] = s * (acc[i][j] + bb[j]);
            float* pp = &P[(size_t)g * DH + colBase + tx * 8];
            if (SLOT == 0) {
                *reinterpret_cast<float4*>(pp)     = *reinterpret_cast<float4*>(&o[0]);
                *reinterpret_cast<float4*>(pp + 4) = *reinterpret_cast<float4*>(&o[4]);
            } else {
                const float4 p0 = *reinterpret_cast<const float4*>(pp);
                const float4 p1 = *reinterpret_cast<const float4*>(pp + 4);
                alignas(16) float h[8];
                h[0] = fmaxf(o[0] + p0.x, 0.f); h[1] = fmaxf(o[1] + p0.y, 0.f);
                h[2] = fmaxf(o[2] + p0.z, 0.f); h[3] = fmaxf(o[3] + p0.w, 0.f);
                h[4] = fmaxf(o[4] + p1.x, 0.f); h[5] = fmaxf(o[5] + p1.y, 0.f);
                h[6] = fmaxf(o[6] + p1.z, 0.f); h[7] = fmaxf(o[7] + p1.w, 0.f);
                *reinterpret_cast<float4*>(pp)     = *reinterpret_cast<float4*>(&h[0]);
                *reinterpret_cast<float4*>(pp + 4) = *reinterpret_cast<float4*>(&h[4]);
            }
        }
    }
}

// ------------------------------------------------------------------
// Weight transpose+convert: W[K][N] fp32 -> WT[N][K] bf16 (per z-slab)
// ------------------------------------------------------------------
__global__ __launch_bounds__(256)
void transp_bf16(const float* __restrict__ W, short* __restrict__ WT,
                 int K, int N)
{
    __shared__ float t[32][33];
    const int k0 = blockIdx.x * 32, n0 = blockIdx.y * 32;
    const size_t off = (size_t)blockIdx.z * K * N;
    const int c = threadIdx.x & 31, r8 = threadIdx.x >> 5;
#pragma unroll
    for (int it = 0; it < 4; ++it) {
        const int r = r8 + it * 8;
        t[r][c] = W[off + (size_t)(k0 + r) * N + n0 + c];
    }
    __syncthreads();
#pragma unroll
    for (int it = 0; it < 4; ++it) {
        const int r = r8 + it * 8;
        WT[off + (size_t)(n0 + r) * K + k0 + c] = f2bf(t[c][r]);
    }
}

// ------------------------------------------------------------------
// bf16-MFMA grouped expert GEMM (MoE layer 2, output path) — R4 numerics,
// register-prefetch pipeline added (no arithmetic change).
// SLOT 0: P[g] = s1*(acc+be) ; SLOT 1: P[g] = relu(P[g] + s2*(acc+be))
// ------------------------------------------------------------------
template<int SLOT>
__global__ __launch_bounds__(256)
void gemm_expert_bf16(const float* __restrict__ Yin, const short* __restrict__ WeT,
                      const float* __restrict__ be, const RInfo* __restrict__ info,
                      const int* __restrict__ list, const int* __restrict__ cnts,
                      const int* __restrict__ offs, float* __restrict__ P)
{
    __shared__ bh8 As8[512];   // 128 rows x 4 granules (8 bf16 each)
    __shared__ bh8 Bs8[512];   // 128 cols x 4 granules
    __shared__ int   rs[128];
    __shared__ float ss[128];

    int c = blockIdx.x, e;
    int cnt = 0;
    for (e = 0; e < NE; ++e) {
        cnt = cnts[e];
        const int nch = (cnt + 127) >> 7;
        if (c < nch) break;
        c -= nch;
    }
    if (e >= NE) return;
    const int m = min(128, cnt - c * 128);
    const int base = offs[e] + c * 128;
    const int tid = threadIdx.x;

    if (tid < 128) {
        const int g = list[base + min(tid, m - 1)];
        rs[tid] = g;
        const RInfo ri = info[g];
        ss[tid] = (SLOT == 0) ? ri.s1 : ri.s2;
    }
    __syncthreads();

    const int colBase = blockIdx.y * 128;
    const int lane = tid & 63, wave = tid >> 6;
    const int wr = wave >> 1, wc = wave & 1;
    const short* Bw = WeT + (size_t)e * DH * DH;   // [n][k] bf16

    fx4 acc[4][4];
    const fx4 z = {0.f, 0.f, 0.f, 0.f};
#pragma unroll
    for (int i = 0; i < 4; ++i)
#pragma unroll
        for (int j = 0; j < 4; ++j) acc[i][j] = z;

    const int d0 = tid, d1 = tid + 256;
    const int ar0 = d0 >> 2, ak0 = d0 & 3;
    const int ar1 = d1 >> 2, ak1 = d1 & 3;
    const int g0 = ar0 * 4 + (ak0 ^ ((ar0 >> 1) & 3));
    const int g1 = ar1 * 4 + (ak1 ^ ((ar1 >> 1) & 3));
    const size_t arow0 = (size_t)rs[ar0] * DH, arow1 = (size_t)rs[ar1] * DH;
    const size_t brow0 = (size_t)(colBase + ar0) * DH, brow1 = (size_t)(colBase + ar1) * DH;

    // prefetch kt=0
    float4 a0p, a1p, a2p, a3p; bh8 b0p, b1p;
    a0p = *reinterpret_cast<const float4*>(&Yin[arow0 + ak0 * 8]);
    a1p = *reinterpret_cast<const float4*>(&Yin[arow0 + ak0 * 8 + 4]);
    a2p = *reinterpret_cast<const float4*>(&Yin[arow1 + ak1 * 8]);
    a3p = *reinterpret_cast<const float4*>(&Yin[arow1 + ak1 * 8 + 4]);
    b0p = *reinterpret_cast<const bh8*>(&Bw[brow0 + ak0 * 8]);
    b1p = *reinterpret_cast<const bh8*>(&Bw[brow1 + ak1 * 8]);

    for (int kt = 0; kt < DH; kt += 32) {
        {   // write staged data (convert A fp32->bf16 here)
            bh8 v;
            v[0]=f2bf(a0p.x); v[1]=f2bf(a0p.y); v[2]=f2bf(a0p.z); v[3]=f2bf(a0p.w);
            v[4]=f2bf(a1p.x); v[5]=f2bf(a1p.y); v[6]=f2bf(a1p.z); v[7]=f2bf(a1p.w);
            As8[g0] = v;
            bh8 w;
            w[0]=f2bf(a2p.x); w[1]=f2bf(a2p.y); w[2]=f2bf(a2p.z); w[3]=f2bf(a2p.w);
            w[4]=f2bf(a3p.x); w[5]=f2bf(a3p.y); w[6]=f2bf(a3p.z); w[7]=f2bf(a3p.w);
            As8[g1] = w;
            Bs8[g0] = b0p;
            Bs8[g1] = b1p;
        }
        __syncthreads();
        if (kt + 32 < DH) {
            const int kn = kt + 32;
            a0p = *reinterpret_cast<const float4*>(&Yin[arow0 + kn + ak0 * 8]);
            a1p = *reinterpret_cast<const float4*>(&Yin[arow0 + kn + ak0 * 8 + 4]);
            a2p = *reinterpret_cast<const float4*>(&Yin[arow1 + kn + ak1 * 8]);
            a3p = *reinterpret_cast<const float4*>(&Yin[arow1 + kn + ak1 * 8 + 4]);
            b0p = *reinterpret_cast<const bh8*>(&Bw[brow0 + kn + ak0 * 8]);
            b1p = *reinterpret_cast<const bh8*>(&Bw[brow1 + kn + ak1 * 8]);
        }
        const int kq = lane >> 4, lm = lane & 15;
        bh8 af[4], bfr[4];
#pragma unroll
        for (int i = 0; i < 4; ++i) {
            const int rl = wr * 64 + i * 16 + lm;
            af[i] = As8[rl * 4 + (kq ^ ((rl >> 1) & 3))];
            const int cl = wc * 64 + i * 16 + lm;
            bfr[i] = Bs8[cl * 4 + (kq ^ ((cl >> 1) & 3))];
        }
#pragma unroll
        for (int i = 0; i < 4; ++i)
#pragma unroll
            for (int j = 0; j < 4; ++j)
                acc[i][j] = __builtin_amdgcn_mfma_f32_16x16x32_bf16(
                    af[i], bfr[j], acc[i][j], 0, 0, 0);
        __syncthreads();
    }

    // epilogue: C/D layout col=lane&15, row=(lane>>4)*4+reg [m89]
    const int rq = lane >> 4, lm = lane & 15;
#pragma unroll
    for (int i = 0; i < 4; ++i) {
#pragma unroll
        for (int j = 0; j < 4; ++j) {
            const int rl = wr * 64 + i * 16 + rq * 4 + j;
            if (rl < m) {
                const int g = rs[rl];
                const float s = ss[rl];
#pragma unroll
                for (int nf = 0; nf < 4; ++nf) {
                    const int cl = colBase + wc * 64 + nf * 16 + lm;
                    float* pp = &P[(size_t)g * DH + cl];
                    const float o = s * (acc[i][nf][j] + be[(size_t)e * DH + cl]);
                    if (SLOT == 0) *pp = o;
                    else           *pp = fmaxf(*pp + o, 0.f);
                }
            }
        }
    }
}

// ------------------------------------------------------------------
// bf16-MFMA final GEMM: out = H@Wf + bf (+ scalar) — R4 numerics,
// register-prefetch pipeline added.
// ------------------------------------------------------------------
__global__ __launch_bounds__(256)
void gemm_final_bf16(const float* __restrict__ Hin, const short* __restrict__ WT,
                     const float* __restrict__ bias, float* __restrict__ C,
                     const float* gsum, float* scalar_out)
{
    __shared__ bh8 As8[512];
    __shared__ bh8 Bs8[512];
    const int tid = threadIdx.x;
    const int rowBase = blockIdx.x * 128;

    if (blockIdx.x == 0 && tid == 0)
        *scalar_out = (gsum[0] + gsum[1]) * (0.5f / (float)NT);

    const int lane = tid & 63, wave = tid >> 6;
    const int wr = wave >> 1, wc = wave & 1;

    fx4 acc[4][4];
    const fx4 z = {0.f, 0.f, 0.f, 0.f};
#pragma unroll
    for (int i = 0; i < 4; ++i)
#pragma unroll
        for (int j = 0; j < 4; ++j) acc[i][j] = z;

    const int d0 = tid, d1 = tid + 256;
    const int ar0 = d0 >> 2, ak0 = d0 & 3;
    const int ar1 = d1 >> 2, ak1 = d1 & 3;
    const int g0 = ar0 * 4 + (ak0 ^ ((ar0 >> 1) & 3));
    const int g1 = ar1 * 4 + (ak1 ^ ((ar1 >> 1) & 3));
    const size_t arow0 = (size_t)(rowBase + ar0) * DH, arow1 = (size_t)(rowBase + ar1) * DH;
    const size_t brow0 = (size_t)ar0 * DH, brow1 = (size_t)ar1 * DH;

    float4 a0p, a1p, a2p, a3p; bh8 b0p, b1p;
    a0p = *reinterpret_cast<const float4*>(&Hin[arow0 + ak0 * 8]);
    a1p = *reinterpret_cast<const float4*>(&Hin[arow0 + ak0 * 8 + 4]);
    a2p = *reinterpret_cast<const float4*>(&Hin[arow1 + ak1 * 8]);
    a3p = *reinterpret_cast<const float4*>(&Hin[arow1 + ak1 * 8 + 4]);
    b0p = *reinterpret_cast<const bh8*>(&WT[brow0 + ak0 * 8]);
    b1p = *reinterpret_cast<const bh8*>(&WT[brow1 + ak1 * 8]);

    for (int kt = 0; kt < DH; kt += 32) {
        {
            bh8 v;
            v[0]=f2bf(a0p.x); v[1]=f2bf(a0p.y); v[2]=f2bf(a0p.z); v[3]=f2bf(a0p.w);
            v[4]=f2bf(a1p.x); v[5]=f2bf(a1p.y); v[6]=f2bf(a1p.z); v[7]=f2bf(a1p.w);
            As8[g0] = v;
            bh8 w;
            w[0]=f2bf(a2p.x); w[1]=f2bf(a2p.y); w[2]=f2bf(a2p.z); w[3]=f2bf(a2p.w);
            w[4]=f2bf(a3p.x); w[5]=f2bf(a3p.y); w[6]=f2bf(a3p.z); w[7]=f2bf(a3p.w);
            As8[g1] = w;
            Bs8[g0] = b0p;
            Bs8[g1] = b1p;
        }
        __syncthreads();
        if (kt + 32 < DH) {
            const int kn = kt + 32;
            a0p = *reinterpret_cast<const float4*>(&Hin[arow0 + kn + ak0 * 8]);
            a1p = *reinterpret_cast<const float4*>(&Hin[arow0 + kn + ak0 * 8 + 4]);
            a2p = *reinterpret_cast<const float4*>(&Hin[arow1 + kn + ak1 * 8]);
            a3p = *reinterpret_cast<const float4*>(&Hin[arow1 + kn + ak1 * 8 + 4]);
            b0p = *reinterpret_cast<const bh8*>(&WT[brow0 + kn + ak0 * 8]);
            b1p = *reinterpret_cast<const bh8*>(&WT[brow1 + kn + ak1 * 8]);
        }
        const int kq = lane >> 4, lm = lane & 15;
        bh8 af[4], bfr[4];
#pragma unroll
        for (int i = 0; i < 4; ++i) {
            const int rl = wr * 64 + i * 16 + lm;
            af[i] = As8[rl * 4 + (kq ^ ((rl >> 1) & 3))];
            const int cl = wc * 64 + i * 16 + lm;
            bfr[i] = Bs8[cl * 4 + (kq ^ ((cl >> 1) & 3))];
        }
#pragma unroll
        for (int i = 0; i < 4; ++i)
#pragma unroll
            for (int j = 0; j < 4; ++j)
                acc[i][j] = __builtin_amdgcn_mfma_f32_16x16x32_bf16(
                    af[i], bfr[j], acc[i][j], 0, 0, 0);
        __syncthreads();
    }

    const int rq = lane >> 4, lm = lane & 15;
#pragma unroll
    for (int i = 0; i < 4; ++i) {
#pragma unroll
        for (int j = 0; j < 4; ++j) {
            const int rl = rowBase + wr * 64 + i * 16 + rq * 4 + j;
#pragma unroll
            for (int nf = 0; nf < 4; ++nf) {
                const int cl = wc * 64 + nf * 16 + lm;
                C[(size_t)rl * DO + cl] = acc[i][nf][j] + bias[cl];
            }
        }
    }
}

// ------------------------------------------------------------------
extern "C" void kernel_launch(void* const* d_in, const int* in_sizes, int n_in,
                              void* d_out, int out_size, void* d_ws, size_t ws_size,
                              hipStream_t stream)
{
    const float* x   = (const float*)d_in[0];
    const float* W0  = (const float*)d_in[1];
    const float* b0  = (const float*)d_in[2];
    const float* Wg1 = (const float*)d_in[3];
    const float* bg1 = (const float*)d_in[4];
    const float* We1 = (const float*)d_in[5];
    const float* be1 = (const float*)d_in[6];
    const float* Wg2 = (const float*)d_in[7];
    const float* bg2 = (const float*)d_in[8];
    const float* We2 = (const float*)d_in[9];
    const float* be2 = (const float*)d_in[10];
    const float* Wf  = (const float*)d_in[11];
    const float* bf  = (const float*)d_in[12];
    float* out = (float*)d_out;

    char* w = (char*)d_ws;
    float* H    = (float*)w; w += (size_t)NT * DH * 4;
    float* Y    = (float*)w; w += (size_t)NT * DH * 4;
    RInfo* info = (RInfo*)w; w += (size_t)NT * sizeof(RInfo);
    int* l0   = (int*)w; w += (size_t)NT * 4;
    int* l1   = (int*)w; w += (size_t)NT * 4;
    int* bc0  = (int*)w; w += NE * 256 * 4;
    int* bc1  = (int*)w; w += NE * 256 * 4;
    int* bo0  = (int*)w; w += NE * 256 * 4;
    int* bo1  = (int*)w; w += NE * 256 * 4;
    int* cnt0 = (int*)w; w += 64;
    int* cnt1 = (int*)w; w += 64;
    int* off0 = (int*)w; w += 64;
    int* off1 = (int*)w; w += 64;
    float* gsum = (float*)w; w += 64;
    short* WeT = (short*)w; w += (size_t)NE * DH * DH * 2;   // 2 MB
    short* WfT = (short*)w; w += (size_t)DH * DO * 2;        // 64 KB

    const int MAXCH = NT / 128 + NE;   // 528

    zero_gsum<<<dim3(1), dim3(64), 0, stream>>>(gsum);
    transp_bf16<<<dim3(8, 8, 16), dim3(256), 0, stream>>>(We2, WeT, DH, DH);
    transp_bf16<<<dim3(8, 4, 1),  dim3(256), 0, stream>>>(Wf,  WfT, DH, DO);

    // layer 0 (fp32, gate-critical): H = relu(x @ W0 + b0)
    gemm_dense<true><<<dim3(NT / 128, 2), dim3(256), 0, stream>>>(x, W0, b0, H, DH);

    // MoE layer 1 (fp32, gate-critical): read H, build Y
    gate_kernel<<<dim3(NT / 16), dim3(256), 0, stream>>>(H, Wg1, bg1, info, &gsum[0]);
    count_kernel<<<dim3(NT / 256), dim3(256), 0, stream>>>(info, bc0, bc1);
    scan2_kernel<<<dim3(1), dim3(64), 0, stream>>>(bc0, bc1, cnt0, cnt1, off0, off1, bo0, bo1);
    scatter2_kernel<<<dim3(NT / 256), dim3(256), 0, stream>>>(info, bo0, bo1, l0, l1);
    gemm_expert<0><<<dim3(MAXCH, 2), dim3(256), 0, stream>>>(H, We1, be1, info, l0, cnt0, off0, Y);
    gemm_expert<1><<<dim3(MAXCH, 2), dim3(256), 0, stream>>>(H, We1, be1, info, l1, cnt1, off1, Y);

    // MoE layer 2 (bf16 MFMA, output path): read Y, build H
    gate_kernel<<<dim3(NT / 16), dim3(256), 0, stream>>>(Y, Wg2, bg2, info, &gsum[1]);
    count_kernel<<<dim3(NT / 256), dim3(256), 0, stream>>>(info, bc0, bc1);
    scan2_kernel<<<dim3(1), dim3(64), 0, stream>>>(bc0, bc1, cnt0, cnt1, off0, off1, bo0, bo1);
    scatter2_kernel<<<dim3(NT / 256), dim3(256), 0, stream>>>(info, bo0, bo1, l0, l1);
    gemm_expert_bf16<0><<<dim3(MAXCH, 2), dim3(256), 0, stream>>>(Y, WeT, be2, info, l0, cnt0, off0, H);
    gemm_expert_bf16<1><<<dim3(MAXCH, 2), dim3(256), 0, stream>>>(Y, WeT, be2, info, l1, cnt1, off1, H);

    // final (bf16 MFMA): out = H @ Wf + bf, plus scalar
    gemm_final_bf16<<<dim3(NT / 128), dim3(256), 0, stream>>>(H, WfT, bf, out, gsum, out + (size_t)NT * DO);
}

// Round 9
// 634.339 us; speedup vs baseline: 1.2471x; 1.2471x over previous
//
#include <hip/hip_runtime.h>
#include <math.h>

#define NT 65536
#define DH 256
#define DO 128
#define NE 16

struct RInfo { int e1, e2; float s1, s2; };

typedef __attribute__((ext_vector_type(8))) short bh8;   // 8 bf16 (4 VGPR)
typedef __attribute__((ext_vector_type(4))) float fx4;   // MFMA acc

static __device__ __forceinline__ short f2bf(float f) {
    union { float f; unsigned u; } v; v.f = f;
    return (short)((v.u + 0x7FFFu + ((v.u >> 16) & 1u)) >> 16);   // RNE
}

// ------------------------------------------------------------------
// fp32 dense GEMM (gate-critical layer 0). 512 threads on the SAME
// 128x128 tile (4x8 outputs/thread): per-output FMA chain over k is
// unchanged -> bit-exact vs R3/R4. Doubles waves/block for latency hiding.
// ------------------------------------------------------------------
template<bool RELU>
__global__ __launch_bounds__(512)
void gemm_dense(const float* __restrict__ A, const float* __restrict__ B,
                const float* __restrict__ bias, float* __restrict__ C,
                int ncols)
{
    __shared__ float As[128][36];
    __shared__ float Bs[32][132];
    const int tid = threadIdx.x;
    const int tx = tid & 15, ty = tid >> 4;   // ty 0..31, 4 rows each
    const int rowBase = blockIdx.x * 128;
    const int colBase = blockIdx.y * 128;

    float acc[4][8];
#pragma unroll
    for (int i = 0; i < 4; ++i)
#pragma unroll
        for (int j = 0; j < 8; ++j) acc[i][j] = 0.f;

    for (int kt = 0; kt < DH; kt += 32) {
        {   // A: 128 rows x 8 granules = 1024 slots, 2 per thread
            const int s0 = tid, s1 = tid + 512;
            const int r0 = s0 >> 3, g0 = s0 & 7;
            const int r1 = s1 >> 3, g1 = s1 & 7;
            *reinterpret_cast<float4*>(&As[r0][g0 * 4]) =
                *reinterpret_cast<const float4*>(&A[(size_t)(rowBase + r0) * DH + kt + g0 * 4]);
            *reinterpret_cast<float4*>(&As[r1][g1 * 4]) =
                *reinterpret_cast<const float4*>(&A[(size_t)(rowBase + r1) * DH + kt + g1 * 4]);
        }
        {   // B: 32 k x 32 granules = 1024 slots, 2 per thread
            const int s0 = tid, s1 = tid + 512;
            const int k0 = s0 >> 5, c0 = s0 & 31;
            const int k1 = s1 >> 5, c1 = s1 & 31;
            *reinterpret_cast<float4*>(&Bs[k0][c0 * 4]) =
                *reinterpret_cast<const float4*>(&B[(size_t)(kt + k0) * ncols + colBase + c0 * 4]);
            *reinterpret_cast<float4*>(&Bs[k1][c1 * 4]) =
                *reinterpret_cast<const float4*>(&B[(size_t)(kt + k1) * ncols + colBase + c1 * 4]);
        }
        __syncthreads();
#pragma unroll
        for (int k4 = 0; k4 < 32; k4 += 4) {
            alignas(16) float ar[4][4];
#pragma unroll
            for (int i = 0; i < 4; ++i)
                *reinterpret_cast<float4*>(ar[i]) =
                    *reinterpret_cast<const float4*>(&As[ty * 4 + i][k4]);
#pragma unroll
            for (int kk = 0; kk < 4; ++kk) {
                alignas(16) float br[8];
                *reinterpret_cast<float4*>(&br[0]) =
                    *reinterpret_cast<const float4*>(&Bs[k4 + kk][tx * 8]);
                *reinterpret_cast<float4*>(&br[4]) =
                    *reinterpret_cast<const float4*>(&Bs[k4 + kk][tx * 8 + 4]);
#pragma unroll
                for (int i = 0; i < 4; ++i) {
                    const float a = ar[i][kk];
#pragma unroll
                    for (int j = 0; j < 8; ++j)
                        acc[i][j] = fmaf(a, br[j], acc[i][j]);
                }
            }
        }
        __syncthreads();
    }
    alignas(16) float bb[8];
#pragma unroll
    for (int j = 0; j < 8; ++j) bb[j] = bias[colBase + tx * 8 + j];
#pragma unroll
    for (int i = 0; i < 4; ++i) {
        const size_t row = rowBase + ty * 4 + i;
        alignas(16) float o[8];
#pragma unroll
        for (int j = 0; j < 8; ++j) {
            float v = acc[i][j] + bb[j];
            if (RELU) v = fmaxf(v, 0.f);
            o[j] = v;
        }
        float* p = &C[row * (size_t)ncols + colBase + tx * 8];
        *reinterpret_cast<float4*>(p)     = *reinterpret_cast<float4*>(&o[0]);
        *reinterpret_cast<float4*>(p + 4) = *reinterpret_cast<float4*>(&o[4]);
    }
}

// ------------------------------------------------------------------
// Gate (unchanged numerics)
// ------------------------------------------------------------------
__global__ __launch_bounds__(256)
void gate_kernel(const float* __restrict__ H, const float* __restrict__ Wg,
                 const float* __restrict__ bg, RInfo* __restrict__ info,
                 float* gsum)
{
    __shared__ float wgs[256][17];
    __shared__ float hs[16][260];
    __shared__ float lg[16][17];
    __shared__ float sbg[16];
    __shared__ float sds[16];
    const int tid = threadIdx.x;
    const int rowBase = blockIdx.x * 16;

#pragma unroll
    for (int i = 0; i < 16; ++i) {
        const int idx = tid + 256 * i;
        wgs[idx >> 4][idx & 15] = Wg[idx];
    }
    if (tid < 16) sbg[tid] = bg[tid];
#pragma unroll
    for (int it = 0; it < 4; ++it) {
        const int flat = (tid + 256 * it) * 4;
        const int r = flat >> 8, k = flat & 255;
        *reinterpret_cast<float4*>(&hs[r][k]) =
            *reinterpret_cast<const float4*>(&H[(size_t)(rowBase + r) * DH + k]);
    }
    __syncthreads();
    {
        const int r = tid >> 4, e = tid & 15;
        float acc = 0.f;
#pragma unroll 8
        for (int k = 0; k < 256; ++k) acc = fmaf(hs[r][k], wgs[k][e], acc);
        lg[r][e] = acc + sbg[e];
    }
    __syncthreads();
    if (tid < 16) {
        const int row = rowBase + tid;
        float l[16];
#pragma unroll
        for (int i = 0; i < 16; ++i) l[i] = lg[tid][i];
        int i1 = 0; float v1 = l[0];
#pragma unroll
        for (int i = 1; i < 16; ++i) if (l[i] > v1) { v1 = l[i]; i1 = i; }
        int i2 = -1; float v2 = -INFINITY;
#pragma unroll
        for (int i = 0; i < 16; ++i) if (i != i1 && l[i] > v2) { v2 = l[i]; i2 = i; }
        const float t = expf(v2 - v1);
        const float s1 = 1.f / (1.f + t);
        const float s2 = t / (1.f + t);
        float p[16]; float S = 0.f;
#pragma unroll
        for (int i = 0; i < 16; ++i) { p[i] = expf(l[i] - v1); S += p[i]; }
        const float inv = 1.f / S;
        float sq = 0.f;
#pragma unroll
        for (int i = 0; i < 16; ++i) { const float q = p[i] * inv; sq = fmaf(q, q, sq); }
        const float var = (sq - 1.0f / 16.0f) * (1.0f / 15.0f);
        const float sd = sqrtf(fmaxf(var, 0.f));

        RInfo ri; ri.e1 = i1; ri.e2 = i2; ri.s1 = s1; ri.s2 = s2;
        info[row] = ri;
        sds[tid] = sd;
    }
    __syncthreads();
    if (tid == 0) {
        float s = 0.f;
#pragma unroll
        for (int i = 0; i < 16; ++i) s += sds[i];
        atomicAdd(gsum, s);
    }
}

__global__ void zero_gsum(float* gsum)
{
    if (threadIdx.x < 2) gsum[threadIdx.x] = 0.f;
}

// ------------------------------------------------------------------
// Bucketing (unchanged)
// ------------------------------------------------------------------
__global__ __launch_bounds__(256)
void count_kernel(const RInfo* __restrict__ info, int* __restrict__ bc0,
                  int* __restrict__ bc1)
{
    __shared__ int h0[NE], h1[NE];
    const int tid = threadIdx.x, b = blockIdx.x;
    if (tid < NE) { h0[tid] = 0; h1[tid] = 0; }
    __syncthreads();
    const RInfo ri = info[b * 256 + tid];
    atomicAdd(&h0[ri.e1], 1);
    atomicAdd(&h1[ri.e2], 1);
    __syncthreads();
    if (tid < NE) {
        bc0[tid * 256 + b] = h0[tid];
        bc1[tid * 256 + b] = h1[tid];
    }
}

__global__ void scan2_kernel(const int* __restrict__ bc0, const int* __restrict__ bc1,
                             int* cnt0, int* cnt1, int* off0, int* off1,
                             int* __restrict__ bo0, int* __restrict__ bo1)
{
    __shared__ int tot0[NE], tot1[NE], base0[NE], base1[NE];
    const int t = threadIdx.x;
    if (t < NE) {
        int s = 0;
        for (int b = 0; b < 256; ++b) s += bc0[t * 256 + b];
        tot0[t] = s; cnt0[t] = s;
    } else if (t < 2 * NE) {
        const int e = t - NE;
        int s = 0;
        for (int b = 0; b < 256; ++b) s += bc1[e * 256 + b];
        tot1[e] = s; cnt1[e] = s;
    }
    __syncthreads();
    if (t == 0) { int a = 0; for (int e = 0; e < NE; ++e) { base0[e] = a; off0[e] = a; a += tot0[e]; } }
    if (t == 1) { int a = 0; for (int e = 0; e < NE; ++e) { base1[e] = a; off1[e] = a; a += tot1[e]; } }
    __syncthreads();
    if (t < NE) {
        int run = base0[t];
        for (int b = 0; b < 256; ++b) { bo0[t * 256 + b] = run; run += bc0[t * 256 + b]; }
    } else if (t < 2 * NE) {
        const int e = t - NE;
        int run = base1[e];
        for (int b = 0; b < 256; ++b) { bo1[e * 256 + b] = run; run += bc1[e * 256 + b]; }
    }
}

__global__ __launch_bounds__(256)
void scatter2_kernel(const RInfo* __restrict__ info, const int* __restrict__ bo0,
                     const int* __restrict__ bo1, int* __restrict__ l0,
                     int* __restrict__ l1)
{
    __shared__ int h0[NE], h1[NE];
    const int tid = threadIdx.x, b = blockIdx.x;
    if (tid < NE) { h0[tid] = 0; h1[tid] = 0; }
    __syncthreads();
    const int r = b * 256 + tid;
    const RInfo ri = info[r];
    const int p0 = atomicAdd(&h0[ri.e1], 1);
    const int p1 = atomicAdd(&h1[ri.e2], 1);
    l0[bo0[ri.e1 * 256 + b] + p0] = r;
    l1[bo1[ri.e2 * 256 + b] + p1] = r;
}

// ------------------------------------------------------------------
// fp32 grouped expert GEMM (MoE layer 1, gate-critical). 512 threads on
// the same 128x128 tile, 4x8 outputs/thread -> bit-exact FMA chains.
// SLOT 0: P[g] = s1*(h@We+be); SLOT 1: P[g] = relu(P[g] + s2*(h@We+be))
// ------------------------------------------------------------------
template<int SLOT>
__global__ __launch_bounds__(512)
void gemm_expert(const float* __restrict__ Hin, const float* __restrict__ We,
                 const float* __restrict__ be, const RInfo* __restrict__ info,
                 const int* __restrict__ list, const int* __restrict__ cnts,
                 const int* __restrict__ offs, float* __restrict__ P)
{
    __shared__ float As[128][36];
    __shared__ float Bs[32][132];
    __shared__ int   rs[128];
    __shared__ float ss[128];

    int c = blockIdx.x, e;
    int cnt = 0;
    for (e = 0; e < NE; ++e) {
        cnt = cnts[e];
        const int nch = (cnt + 127) >> 7;
        if (c < nch) break;
        c -= nch;
    }
    if (e >= NE) return;
    const int m = min(128, cnt - c * 128);
    const int base = offs[e] + c * 128;
    const int tid = threadIdx.x;
    const int tx = tid & 15, ty = tid >> 4;   // ty 0..31
    const int colBase = blockIdx.y * 128;

    if (tid < 128) {
        const int g = list[base + min(tid, m - 1)];
        rs[tid] = g;
        const RInfo ri = info[g];
        ss[tid] = (SLOT == 0) ? ri.s1 : ri.s2;
    }
    __syncthreads();

    const float* B = We + (size_t)e * DH * DH;

    float acc[4][8];
#pragma unroll
    for (int i = 0; i < 4; ++i)
#pragma unroll
        for (int j = 0; j < 8; ++j) acc[i][j] = 0.f;

    // staging coords (2 slots per thread)
    const int r0 = tid >> 3, ga0 = tid & 7;
    const int r1 = (tid + 512) >> 3, ga1 = tid & 7;
    const int k0 = tid >> 5, cb0 = tid & 31;
    const int k1 = (tid + 512) >> 5, cb1 = tid & 31;

    for (int kt = 0; kt < DH; kt += 32) {
        {
            const int g0r = rs[r0], g1r = rs[r1];
            *reinterpret_cast<float4*>(&As[r0][ga0 * 4]) =
                *reinterpret_cast<const float4*>(&Hin[(size_t)g0r * DH + kt + ga0 * 4]);
            *reinterpret_cast<float4*>(&As[r1][ga1 * 4]) =
                *reinterpret_cast<const float4*>(&Hin[(size_t)g1r * DH + kt + ga1 * 4]);
        }
        {
            *reinterpret_cast<float4*>(&Bs[k0][cb0 * 4]) =
                *reinterpret_cast<const float4*>(&B[(size_t)(kt + k0) * DH + colBase + cb0 * 4]);
            *reinterpret_cast<float4*>(&Bs[k1][cb1 * 4]) =
                *reinterpret_cast<const float4*>(&B[(size_t)(kt + k1) * DH + colBase + cb1 * 4]);
        }
        __syncthreads();
#pragma unroll
        for (int k4 = 0; k4 < 32; k4 += 4) {
            alignas(16) float ar[4][4];
#pragma unroll
            for (int i = 0; i < 4; ++i)
                *reinterpret_cast<float4*>(ar[i]) =
                    *reinterpret_cast<const float4*>(&As[ty * 4 + i][k4]);
#pragma unroll
            for (int kk = 0; kk < 4; ++kk) {
                alignas(16) float br[8];
                *reinterpret_cast<float4*>(&br[0]) =
                    *reinterpret_cast<const float4*>(&Bs[k4 + kk][tx * 8]);
                *reinterpret_cast<float4*>(&br[4]) =
                    *reinterpret_cast<const float4*>(&Bs[k4 + kk][tx * 8 + 4]);
#pragma unroll
                for (int i = 0; i < 4; ++i) {
                    const float a = ar[i][kk];
#pragma unroll
                    for (int j = 0; j < 8; ++j)
                        acc[i][j] = fmaf(a, br[j], acc[i][j]);
                }
            }
        }
        __syncthreads();
    }

    alignas(16) float bb[8];
#pragma unroll
    for (int j = 0; j < 8; ++j) bb[j] = be[(size_t)e * DH + colBase + tx * 8 + j];
#pragma unroll
    for (int i = 0; i < 4; ++i) {
        const int rl = ty * 4 + i;
        if (rl < m) {
            const int g = rs[rl];
            const float s = ss[rl];
            alignas(16) float o[8];
#pragma unroll
            for (int j = 0; j < 8; ++j) o[j] = s * (acc[i][j] + bb[j]);
            float* pp = &P[(size_t)g * DH + colBase + tx * 8];
            if (SLOT == 0) {
                *reinterpret_cast<float4*>(pp)     = *reinterpret_cast<float4*>(&o[0]);
                *reinterpret_cast<float4*>(pp + 4) = *reinterpret_cast<float4*>(&o[4]);
            } else {
                const float4 p0 = *reinterpret_cast<const float4*>(pp);
                const float4 p1 = *reinterpret_cast<const float4*>(pp + 4);
                alignas(16) float h[8];
                h[0] = fmaxf(o[0] + p0.x, 0.f); h[1] = fmaxf(o[1] + p0.y, 0.f);
                h[2] = fmaxf(o[2] + p0.z, 0.f); h[3] = fmaxf(o[3] + p0.w, 0.f);
                h[4] = fmaxf(o[4] + p1.x, 0.f); h[5] = fmaxf(o[5] + p1.y, 0.f);
                h[6] = fmaxf(o[6] + p1.z, 0.f); h[7] = fmaxf(o[7] + p1.w, 0.f);
                *reinterpret_cast<float4*>(pp)     = *reinterpret_cast<float4*>(&h[0]);
                *reinterpret_cast<float4*>(pp + 4) = *reinterpret_cast<float4*>(&h[4]);
            }
        }
    }
}

// ------------------------------------------------------------------
// Weight transpose+convert: W[K][N] fp32 -> WT[N][K] bf16 (per z-slab)
// ------------------------------------------------------------------
__global__ __launch_bounds__(256)
void transp_bf16(const float* __restrict__ W, short* __restrict__ WT,
                 int K, int N)
{
    __shared__ float t[32][33];
    const int k0 = blockIdx.x * 32, n0 = blockIdx.y * 32;
    const size_t off = (size_t)blockIdx.z * K * N;
    const int c = threadIdx.x & 31, r8 = threadIdx.x >> 5;
#pragma unroll
    for (int it = 0; it < 4; ++it) {
        const int r = r8 + it * 8;
        t[r][c] = W[off + (size_t)(k0 + r) * N + n0 + c];
    }
    __syncthreads();
#pragma unroll
    for (int it = 0; it < 4; ++it) {
        const int r = r8 + it * 8;
        WT[off + (size_t)(n0 + r) * K + k0 + c] = f2bf(t[c][r]);
    }
}

// ------------------------------------------------------------------
// bf16-MFMA grouped expert GEMM (MoE layer 2, output path) — R4 verbatim.
// SLOT 0: P[g] = s1*(acc+be) ; SLOT 1: P[g] = relu(P[g] + s2*(acc+be))
// ------------------------------------------------------------------
template<int SLOT>
__global__ __launch_bounds__(256)
void gemm_expert_bf16(const float* __restrict__ Yin, const short* __restrict__ WeT,
                      const float* __restrict__ be, const RInfo* __restrict__ info,
                      const int* __restrict__ list, const int* __restrict__ cnts,
                      const int* __restrict__ offs, float* __restrict__ P)
{
    __shared__ bh8 As8[512];   // 128 rows x 4 granules (8 bf16 each)
    __shared__ bh8 Bs8[512];   // 128 cols x 4 granules
    __shared__ int   rs[128];
    __shared__ float ss[128];

    int c = blockIdx.x, e;
    int cnt = 0;
    for (e = 0; e < NE; ++e) {
        cnt = cnts[e];
        const int nch = (cnt + 127) >> 7;
        if (c < nch) break;
        c -= nch;
    }
    if (e >= NE) return;
    const int m = min(128, cnt - c * 128);
    const int base = offs[e] + c * 128;
    const int tid = threadIdx.x;

    if (tid < 128) {
        const int g = list[base + min(tid, m - 1)];
        rs[tid] = g;
        const RInfo ri = info[g];
        ss[tid] = (SLOT == 0) ? ri.s1 : ri.s2;
    }
    __syncthreads();

    const int colBase = blockIdx.y * 128;
    const int lane = tid & 63, wave = tid >> 6;
    const int wr = wave >> 1, wc = wave & 1;
    const short* Bw = WeT + (size_t)e * DH * DH;   // [n][k] bf16

    fx4 acc[4][4];
    const fx4 z = {0.f, 0.f, 0.f, 0.f};
#pragma unroll
    for (int i = 0; i < 4; ++i)
#pragma unroll
        for (int j = 0; j < 4; ++j) acc[i][j] = z;

    const int d0 = tid, d1 = tid + 256;
    const int ar0 = d0 >> 2, ak0 = d0 & 3;
    const int ar1 = d1 >> 2, ak1 = d1 & 3;
    const int g0 = ar0 * 4 + (ak0 ^ ((ar0 >> 1) & 3));
    const int g1 = ar1 * 4 + (ak1 ^ ((ar1 >> 1) & 3));
    const size_t arow0 = (size_t)rs[ar0] * DH, arow1 = (size_t)rs[ar1] * DH;
    const size_t brow0 = (size_t)(colBase + ar0) * DH, brow1 = (size_t)(colBase + ar1) * DH;

    for (int kt = 0; kt < DH; kt += 32) {
        {   // A stage: fp32 -> bf16, swizzled store
            const float* s0 = &Yin[arow0 + kt + ak0 * 8];
            const float4 f0 = *reinterpret_cast<const float4*>(s0);
            const float4 f1 = *reinterpret_cast<const float4*>(s0 + 4);
            bh8 v;
            v[0]=f2bf(f0.x); v[1]=f2bf(f0.y); v[2]=f2bf(f0.z); v[3]=f2bf(f0.w);
            v[4]=f2bf(f1.x); v[5]=f2bf(f1.y); v[6]=f2bf(f1.z); v[7]=f2bf(f1.w);
            As8[g0] = v;
            const float* s1 = &Yin[arow1 + kt + ak1 * 8];
            const float4 f2 = *reinterpret_cast<const float4*>(s1);
            const float4 f3 = *reinterpret_cast<const float4*>(s1 + 4);
            bh8 w;
            w[0]=f2bf(f2.x); w[1]=f2bf(f2.y); w[2]=f2bf(f2.z); w[3]=f2bf(f2.w);
            w[4]=f2bf(f3.x); w[5]=f2bf(f3.y); w[6]=f2bf(f3.z); w[7]=f2bf(f3.w);
            As8[g1] = w;
        }
        {   // B stage: bf16 16B loads, swizzled store
            Bs8[g0] = *reinterpret_cast<const bh8*>(&Bw[brow0 + kt + ak0 * 8]);
            Bs8[g1] = *reinterpret_cast<const bh8*>(&Bw[brow1 + kt + ak1 * 8]);
        }
        __syncthreads();
        const int kq = lane >> 4, lm = lane & 15;
        bh8 af[4], bfr[4];
#pragma unroll
        for (int i = 0; i < 4; ++i) {
            const int rl = wr * 64 + i * 16 + lm;
            af[i] = As8[rl * 4 + (kq ^ ((rl >> 1) & 3))];
            const int cl = wc * 64 + i * 16 + lm;
            bfr[i] = Bs8[cl * 4 + (kq ^ ((cl >> 1) & 3))];
        }
#pragma unroll
        for (int i = 0; i < 4; ++i)
#pragma unroll
            for (int j = 0; j < 4; ++j)
                acc[i][j] = __builtin_amdgcn_mfma_f32_16x16x32_bf16(
                    af[i], bfr[j], acc[i][j], 0, 0, 0);
        __syncthreads();
    }

    // epilogue: C/D layout col=lane&15, row=(lane>>4)*4+reg [m89]
    const int rq = lane >> 4, lm = lane & 15;
#pragma unroll
    for (int i = 0; i < 4; ++i) {
#pragma unroll
        for (int j = 0; j < 4; ++j) {
            const int rl = wr * 64 + i * 16 + rq * 4 + j;
            if (rl < m) {
                const int g = rs[rl];
                const float s = ss[rl];
#pragma unroll
                for (int nf = 0; nf < 4; ++nf) {
                    const int cl = colBase + wc * 64 + nf * 16 + lm;
                    float* pp = &P[(size_t)g * DH + cl];
                    const float o = s * (acc[i][nf][j] + be[(size_t)e * DH + cl]);
                    if (SLOT == 0) *pp = o;
                    else           *pp = fmaxf(*pp + o, 0.f);
                }
            }
        }
    }
}

// ------------------------------------------------------------------
// bf16-MFMA final GEMM: out = H@Wf + bf (+ scalar) — R4 verbatim.
// ------------------------------------------------------------------
__global__ __launch_bounds__(256)
void gemm_final_bf16(const float* __restrict__ Hin, const short* __restrict__ WT,
                     const float* __restrict__ bias, float* __restrict__ C,
                     const float* gsum, float* scalar_out)
{
    __shared__ bh8 As8[512];
    __shared__ bh8 Bs8[512];
    const int tid = threadIdx.x;
    const int rowBase = blockIdx.x * 128;

    if (blockIdx.x == 0 && tid == 0)
        *scalar_out = (gsum[0] + gsum[1]) * (0.5f / (float)NT);

    const int lane = tid & 63, wave = tid >> 6;
    const int wr = wave >> 1, wc = wave & 1;

    fx4 acc[4][4];
    const fx4 z = {0.f, 0.f, 0.f, 0.f};
#pragma unroll
    for (int i = 0; i < 4; ++i)
#pragma unroll
        for (int j = 0; j < 4; ++j) acc[i][j] = z;

    const int d0 = tid, d1 = tid + 256;
    const int ar0 = d0 >> 2, ak0 = d0 & 3;
    const int ar1 = d1 >> 2, ak1 = d1 & 3;
    const int g0 = ar0 * 4 + (ak0 ^ ((ar0 >> 1) & 3));
    const int g1 = ar1 * 4 + (ak1 ^ ((ar1 >> 1) & 3));
    const size_t arow0 = (size_t)(rowBase + ar0) * DH, arow1 = (size_t)(rowBase + ar1) * DH;
    const size_t brow0 = (size_t)ar0 * DH, brow1 = (size_t)ar1 * DH;

    for (int kt = 0; kt < DH; kt += 32) {
        {
            const float* s0 = &Hin[arow0 + kt + ak0 * 8];
            const float4 f0 = *reinterpret_cast<const float4*>(s0);
            const float4 f1 = *reinterpret_cast<const float4*>(s0 + 4);
            bh8 v;
            v[0]=f2bf(f0.x); v[1]=f2bf(f0.y); v[2]=f2bf(f0.z); v[3]=f2bf(f0.w);
            v[4]=f2bf(f1.x); v[5]=f2bf(f1.y); v[6]=f2bf(f1.z); v[7]=f2bf(f1.w);
            As8[g0] = v;
            const float* s1 = &Hin[arow1 + kt + ak1 * 8];
            const float4 f2 = *reinterpret_cast<const float4*>(s1);
            const float4 f3 = *reinterpret_cast<const float4*>(s1 + 4);
            bh8 w;
            w[0]=f2bf(f2.x); w[1]=f2bf(f2.y); w[2]=f2bf(f2.z); w[3]=f2bf(f2.w);
            w[4]=f2bf(f3.x); w[5]=f2bf(f3.y); w[6]=f2bf(f3.z); w[7]=f2bf(f3.w);
            As8[g1] = w;
        }
        {
            Bs8[g0] = *reinterpret_cast<const bh8*>(&WT[brow0 + kt + ak0 * 8]);
            Bs8[g1] = *reinterpret_cast<const bh8*>(&WT[brow1 + kt + ak1 * 8]);
        }
        __syncthreads();
        const int kq = lane >> 4, lm = lane & 15;
        bh8 af[4], bfr[4];
#pragma unroll
        for (int i = 0; i < 4; ++i) {
            const int rl = wr * 64 + i * 16 + lm;
            af[i] = As8[rl * 4 + (kq ^ ((rl >> 1) & 3))];
            const int cl = wc * 64 + i * 16 + lm;
            bfr[i] = Bs8[cl * 4 + (kq ^ ((cl >> 1) & 3))];
        }
#pragma unroll
        for (int i = 0; i < 4; ++i)
#pragma unroll
            for (int j = 0; j < 4; ++j)
                acc[i][j] = __builtin_amdgcn_mfma_f32_16x16x32_bf16(
                    af[i], bfr[j], acc[i][j], 0, 0, 0);
        __syncthreads();
    }

    const int rq = lane >> 4, lm = lane & 15;
#pragma unroll
    for (int i = 0; i < 4; ++i) {
#pragma unroll
        for (int j = 0; j < 4; ++j) {
            const int rl = rowBase + wr * 64 + i * 16 + rq * 4 + j;
#pragma unroll
            for (int nf = 0; nf < 4; ++nf) {
                const int cl = wc * 64 + nf * 16 + lm;
                C[(size_t)rl * DO + cl] = acc[i][nf][j] + bias[cl];
            }
        }
    }
}

// ------------------------------------------------------------------
extern "C" void kernel_launch(void* const* d_in, const int* in_sizes, int n_in,
                              void* d_out, int out_size, void* d_ws, size_t ws_size,
                              hipStream_t stream)
{
    const float* x   = (const float*)d_in[0];
    const float* W0  = (const float*)d_in[1];
    const float* b0  = (const float*)d_in[2];
    const float* Wg1 = (const float*)d_in[3];
    const float* bg1 = (const float*)d_in[4];
    const float* We1 = (const float*)d_in[5];
    const float* be1 = (const float*)d_in[6];
    const float* Wg2 = (const float*)d_in[7];
    const float* bg2 = (const float*)d_in[8];
    const float* We2 = (const float*)d_in[9];
    const float* be2 = (const float*)d_in[10];
    const float* Wf  = (const float*)d_in[11];
    const float* bf  = (const float*)d_in[12];
    float* out = (float*)d_out;

    char* w = (char*)d_ws;
    float* H    = (float*)w; w += (size_t)NT * DH * 4;
    float* Y    = (float*)w; w += (size_t)NT * DH * 4;
    RInfo* info = (RInfo*)w; w += (size_t)NT * sizeof(RInfo);
    int* l0   = (int*)w; w += (size_t)NT * 4;
    int* l1   = (int*)w; w += (size_t)NT * 4;
    int* bc0  = (int*)w; w += NE * 256 * 4;
    int* bc1  = (int*)w; w += NE * 256 * 4;
    int* bo0  = (int*)w; w += NE * 256 * 4;
    int* bo1  = (int*)w; w += NE * 256 * 4;
    int* cnt0 = (int*)w; w += 64;
    int* cnt1 = (int*)w; w += 64;
    int* off0 = (int*)w; w += 64;
    int* off1 = (int*)w; w += 64;
    float* gsum = (float*)w; w += 64;
    short* WeT = (short*)w; w += (size_t)NE * DH * DH * 2;   // 2 MB
    short* WfT = (short*)w; w += (size_t)DH * DO * 2;        // 64 KB

    const int MAXCH = NT / 128 + NE;   // 528

    zero_gsum<<<dim3(1), dim3(64), 0, stream>>>(gsum);
    transp_bf16<<<dim3(8, 8, 16), dim3(256), 0, stream>>>(We2, WeT, DH, DH);
    transp_bf16<<<dim3(8, 4, 1),  dim3(256), 0, stream>>>(Wf,  WfT, DH, DO);

    // layer 0 (fp32, gate-critical): H = relu(x @ W0 + b0)
    gemm_dense<true><<<dim3(NT / 128, 2), dim3(512), 0, stream>>>(x, W0, b0, H, DH);

    // MoE layer 1 (fp32, gate-critical): read H, build Y
    gate_kernel<<<dim3(NT / 16), dim3(256), 0, stream>>>(H, Wg1, bg1, info, &gsum[0]);
    count_kernel<<<dim3(NT / 256), dim3(256), 0, stream>>>(info, bc0, bc1);
    scan2_kernel<<<dim3(1), dim3(64), 0, stream>>>(bc0, bc1, cnt0, cnt1, off0, off1, bo0, bo1);
    scatter2_kernel<<<dim3(NT / 256), dim3(256), 0, stream>>>(info, bo0, bo1, l0, l1);
    gemm_expert<0><<<dim3(MAXCH, 2), dim3(512), 0, stream>>>(H, We1, be1, info, l0, cnt0, off0, Y);
    gemm_expert<1><<<dim3(MAXCH, 2), dim3(512), 0, stream>>>(H, We1, be1, info, l1, cnt1, off1, Y);

    // MoE layer 2 (bf16 MFMA, output path): read Y, build H
    gate_kernel<<<dim3(NT / 16), dim3(256), 0, stream>>>(Y, Wg2, bg2, info, &gsum[1]);
    count_kernel<<<dim3(NT / 256), dim3(256), 0, stream>>>(info, bc0, bc1);
    scan2_kernel<<<dim3(1), dim3(64), 0, stream>>>(bc0, bc1, cnt0, cnt1, off0, off1, bo0, bo1);
    scatter2_kernel<<<dim3(NT / 256), dim3(256), 0, stream>>>(info, bo0, bo1, l0, l1);
    gemm_expert_bf16<0><<<dim3(MAXCH, 2), dim3(256), 0, stream>>>(Y, WeT, be2, info, l0, cnt0, off0, H);
    gemm_expert_bf16<1><<<dim3(MAXCH, 2), dim3(256), 0, stream>>>(Y, WeT, be2, info, l1, cnt1, off1, H);

    // final (bf16 MFMA): out = H @ Wf + bf, plus scalar
    gemm_final_bf16<<<dim3(NT / 128), dim3(256), 0, stream>>>(H, WfT, bf, out, gsum, out + (size_t)NT * DO);
}

// Round 10
// 629.978 us; speedup vs baseline: 1.2558x; 1.0069x over previous
//
#include <hip/hip_runtime.h>
#include <math.h>

#define NT 65536
#define DH 256
#define DO 128
#define NE 16

struct RInfo { int e1, e2; float s1, s2; };

typedef __attribute__((ext_vector_type(8))) short bh8;   // 8 bf16 (4 VGPR)
typedef __attribute__((ext_vector_type(4))) float fx4;   // MFMA acc

static __device__ __forceinline__ short f2bf(float f) {
    union { float f; unsigned u; } v; v.f = f;
    return (short)((v.u + 0x7FFFu + ((v.u >> 16) & 1u)) >> 16);   // RNE
}

// ------------------------------------------------------------------
// fp32 dense GEMM (gate-critical layer 0). 256 thr, 128x128 tile, 8x8
// per thread — EXACT R4 FMA order (bit-exact). K-step 16 (was 32):
// LDS 21KB -> 7 blocks/CU (was 4) for cross-block latency hiding.
// ------------------------------------------------------------------
template<bool RELU>
__global__ __launch_bounds__(256)
void gemm_dense(const float* __restrict__ A, const float* __restrict__ B,
                const float* __restrict__ bias, float* __restrict__ C,
                int ncols)
{
    __shared__ float As[128][24];   // 16 k + pad to 96B rows (16B-aligned)
    __shared__ float Bs[16][132];
    const int tid = threadIdx.x;
    const int tx = tid & 15, ty = tid >> 4;
    const int rowBase = blockIdx.x * 128;
    const int colBase = blockIdx.y * 128;

    const int ra0 = tid >> 2, ga = tid & 3;    // A: rows ra0, ra0+64; granule ga
    const int kb0 = tid >> 5, cb = tid & 31;   // B: k-rows kb0, kb0+8; col granule cb

    float acc[8][8];
#pragma unroll
    for (int i = 0; i < 8; ++i)
#pragma unroll
        for (int j = 0; j < 8; ++j) acc[i][j] = 0.f;

    for (int kt = 0; kt < DH; kt += 16) {
        *reinterpret_cast<float4*>(&As[ra0][ga * 4]) =
            *reinterpret_cast<const float4*>(&A[(size_t)(rowBase + ra0) * DH + kt + ga * 4]);
        *reinterpret_cast<float4*>(&As[ra0 + 64][ga * 4]) =
            *reinterpret_cast<const float4*>(&A[(size_t)(rowBase + ra0 + 64) * DH + kt + ga * 4]);
        *reinterpret_cast<float4*>(&Bs[kb0][cb * 4]) =
            *reinterpret_cast<const float4*>(&B[(size_t)(kt + kb0) * ncols + colBase + cb * 4]);
        *reinterpret_cast<float4*>(&Bs[kb0 + 8][cb * 4]) =
            *reinterpret_cast<const float4*>(&B[(size_t)(kt + kb0 + 8) * ncols + colBase + cb * 4]);
        __syncthreads();
#pragma unroll
        for (int k4 = 0; k4 < 16; k4 += 4) {
            alignas(16) float ar[8][4];
#pragma unroll
            for (int i = 0; i < 8; ++i)
                *reinterpret_cast<float4*>(ar[i]) =
                    *reinterpret_cast<const float4*>(&As[ty * 8 + i][k4]);
#pragma unroll
            for (int kk = 0; kk < 4; ++kk) {
                alignas(16) float br[8];
                *reinterpret_cast<float4*>(&br[0]) =
                    *reinterpret_cast<const float4*>(&Bs[k4 + kk][tx * 8]);
                *reinterpret_cast<float4*>(&br[4]) =
                    *reinterpret_cast<const float4*>(&Bs[k4 + kk][tx * 8 + 4]);
#pragma unroll
                for (int i = 0; i < 8; ++i) {
                    const float a = ar[i][kk];
#pragma unroll
                    for (int j = 0; j < 8; ++j)
                        acc[i][j] = fmaf(a, br[j], acc[i][j]);
                }
            }
        }
        __syncthreads();
    }
    alignas(16) float bb[8];
#pragma unroll
    for (int j = 0; j < 8; ++j) bb[j] = bias[colBase + tx * 8 + j];
#pragma unroll
    for (int i = 0; i < 8; ++i) {
        const size_t row = rowBase + ty * 8 + i;
        alignas(16) float o[8];
#pragma unroll
        for (int j = 0; j < 8; ++j) {
            float v = acc[i][j] + bb[j];
            if (RELU) v = fmaxf(v, 0.f);
            o[j] = v;
        }
        float* p = &C[row * (size_t)ncols + colBase + tx * 8];
        *reinterpret_cast<float4*>(p)     = *reinterpret_cast<float4*>(&o[0]);
        *reinterpret_cast<float4*>(p + 4) = *reinterpret_cast<float4*>(&o[4]);
    }
}

// ------------------------------------------------------------------
// Gate (unchanged numerics)
// ------------------------------------------------------------------
__global__ __launch_bounds__(256)
void gate_kernel(const float* __restrict__ H, const float* __restrict__ Wg,
                 const float* __restrict__ bg, RInfo* __restrict__ info,
                 float* gsum)
{
    __shared__ float wgs[256][17];
    __shared__ float hs[16][260];
    __shared__ float lg[16][17];
    __shared__ float sbg[16];
    __shared__ float sds[16];
    const int tid = threadIdx.x;
    const int rowBase = blockIdx.x * 16;

#pragma unroll
    for (int i = 0; i < 16; ++i) {
        const int idx = tid + 256 * i;
        wgs[idx >> 4][idx & 15] = Wg[idx];
    }
    if (tid < 16) sbg[tid] = bg[tid];
#pragma unroll
    for (int it = 0; it < 4; ++it) {
        const int flat = (tid + 256 * it) * 4;
        const int r = flat >> 8, k = flat & 255;
        *reinterpret_cast<float4*>(&hs[r][k]) =
            *reinterpret_cast<const float4*>(&H[(size_t)(rowBase + r) * DH + k]);
    }
    __syncthreads();
    {
        const int r = tid >> 4, e = tid & 15;
        float acc = 0.f;
#pragma unroll 8
        for (int k = 0; k < 256; ++k) acc = fmaf(hs[r][k], wgs[k][e], acc);
        lg[r][e] = acc + sbg[e];
    }
    __syncthreads();
    if (tid < 16) {
        const int row = rowBase + tid;
        float l[16];
#pragma unroll
        for (int i = 0; i < 16; ++i) l[i] = lg[tid][i];
        int i1 = 0; float v1 = l[0];
#pragma unroll
        for (int i = 1; i < 16; ++i) if (l[i] > v1) { v1 = l[i]; i1 = i; }
        int i2 = -1; float v2 = -INFINITY;
#pragma unroll
        for (int i = 0; i < 16; ++i) if (i != i1 && l[i] > v2) { v2 = l[i]; i2 = i; }
        const float t = expf(v2 - v1);
        const float s1 = 1.f / (1.f + t);
        const float s2 = t / (1.f + t);
        float p[16]; float S = 0.f;
#pragma unroll
        for (int i = 0; i < 16; ++i) { p[i] = expf(l[i] - v1); S += p[i]; }
        const float inv = 1.f / S;
        float sq = 0.f;
#pragma unroll
        for (int i = 0; i < 16; ++i) { const float q = p[i] * inv; sq = fmaf(q, q, sq); }
        const float var = (sq - 1.0f / 16.0f) * (1.0f / 15.0f);
        const float sd = sqrtf(fmaxf(var, 0.f));

        RInfo ri; ri.e1 = i1; ri.e2 = i2; ri.s1 = s1; ri.s2 = s2;
        info[row] = ri;
        sds[tid] = sd;
    }
    __syncthreads();
    if (tid == 0) {
        float s = 0.f;
#pragma unroll
        for (int i = 0; i < 16; ++i) s += sds[i];
        atomicAdd(gsum, s);
    }
}

__global__ void zero_gsum(float* gsum)
{
    if (threadIdx.x < 2) gsum[threadIdx.x] = 0.f;
}

// ------------------------------------------------------------------
// Bucketing (unchanged)
// ------------------------------------------------------------------
__global__ __launch_bounds__(256)
void count_kernel(const RInfo* __restrict__ info, int* __restrict__ bc0,
                  int* __restrict__ bc1)
{
    __shared__ int h0[NE], h1[NE];
    const int tid = threadIdx.x, b = blockIdx.x;
    if (tid < NE) { h0[tid] = 0; h1[tid] = 0; }
    __syncthreads();
    const RInfo ri = info[b * 256 + tid];
    atomicAdd(&h0[ri.e1], 1);
    atomicAdd(&h1[ri.e2], 1);
    __syncthreads();
    if (tid < NE) {
        bc0[tid * 256 + b] = h0[tid];
        bc1[tid * 256 + b] = h1[tid];
    }
}

__global__ void scan2_kernel(const int* __restrict__ bc0, const int* __restrict__ bc1,
                             int* cnt0, int* cnt1, int* off0, int* off1,
                             int* __restrict__ bo0, int* __restrict__ bo1)
{
    __shared__ int tot0[NE], tot1[NE], base0[NE], base1[NE];
    const int t = threadIdx.x;
    if (t < NE) {
        int s = 0;
        for (int b = 0; b < 256; ++b) s += bc0[t * 256 + b];
        tot0[t] = s; cnt0[t] = s;
    } else if (t < 2 * NE) {
        const int e = t - NE;
        int s = 0;
        for (int b = 0; b < 256; ++b) s += bc1[e * 256 + b];
        tot1[e] = s; cnt1[e] = s;
    }
    __syncthreads();
    if (t == 0) { int a = 0; for (int e = 0; e < NE; ++e) { base0[e] = a; off0[e] = a; a += tot0[e]; } }
    if (t == 1) { int a = 0; for (int e = 0; e < NE; ++e) { base1[e] = a; off1[e] = a; a += tot1[e]; } }
    __syncthreads();
    if (t < NE) {
        int run = base0[t];
        for (int b = 0; b < 256; ++b) { bo0[t * 256 + b] = run; run += bc0[t * 256 + b]; }
    } else if (t < 2 * NE) {
        const int e = t - NE;
        int run = base1[e];
        for (int b = 0; b < 256; ++b) { bo1[e * 256 + b] = run; run += bc1[e * 256 + b]; }
    }
}

__global__ __launch_bounds__(256)
void scatter2_kernel(const RInfo* __restrict__ info, const int* __restrict__ bo0,
                     const int* __restrict__ bo1, int* __restrict__ l0,
                     int* __restrict__ l1)
{
    __shared__ int h0[NE], h1[NE];
    const int tid = threadIdx.x, b = blockIdx.x;
    if (tid < NE) { h0[tid] = 0; h1[tid] = 0; }
    __syncthreads();
    const int r = b * 256 + tid;
    const RInfo ri = info[r];
    const int p0 = atomicAdd(&h0[ri.e1], 1);
    const int p1 = atomicAdd(&h1[ri.e2], 1);
    l0[bo0[ri.e1 * 256 + b] + p0] = r;
    l1[bo1[ri.e2 * 256 + b] + p1] = r;
}

// ------------------------------------------------------------------
// fp32 grouped expert GEMM (MoE layer 1, gate-critical). 256 thr,
// 128x128, 8x8/thread — EXACT R4 FMA order. K-step 16 for occupancy.
// SLOT 1 additionally emits Ybf (bf16 of the final Y) when provided —
// identical bits to consumer-side f2bf, so downstream is unchanged.
// ------------------------------------------------------------------
template<int SLOT>
__global__ __launch_bounds__(256)
void gemm_expert(const float* __restrict__ Hin, const float* __restrict__ We,
                 const float* __restrict__ be, const RInfo* __restrict__ info,
                 const int* __restrict__ list, const int* __restrict__ cnts,
                 const int* __restrict__ offs, float* __restrict__ P,
                 short* __restrict__ Ybf)
{
    __shared__ float As[128][24];
    __shared__ float Bs[16][132];
    __shared__ int   rs[128];
    __shared__ float ss[128];

    int c = blockIdx.x, e;
    int cnt = 0;
    for (e = 0; e < NE; ++e) {
        cnt = cnts[e];
        const int nch = (cnt + 127) >> 7;
        if (c < nch) break;
        c -= nch;
    }
    if (e >= NE) return;
    const int m = min(128, cnt - c * 128);
    const int base = offs[e] + c * 128;
    const int tid = threadIdx.x;
    const int tx = tid & 15, ty = tid >> 4;
    const int colBase = blockIdx.y * 128;

    if (tid < 128) {
        const int g = list[base + min(tid, m - 1)];
        rs[tid] = g;
        const RInfo ri = info[g];
        ss[tid] = (SLOT == 0) ? ri.s1 : ri.s2;
    }
    __syncthreads();

    const float* B = We + (size_t)e * DH * DH;
    const int ra0 = tid >> 2, ga = tid & 3;
    const int kb0 = tid >> 5, cb = tid & 31;
    const size_t arow0 = (size_t)rs[ra0] * DH;
    const size_t arow1 = (size_t)rs[ra0 + 64] * DH;

    float acc[8][8];
#pragma unroll
    for (int i = 0; i < 8; ++i)
#pragma unroll
        for (int j = 0; j < 8; ++j) acc[i][j] = 0.f;

    for (int kt = 0; kt < DH; kt += 16) {
        *reinterpret_cast<float4*>(&As[ra0][ga * 4]) =
            *reinterpret_cast<const float4*>(&Hin[arow0 + kt + ga * 4]);
        *reinterpret_cast<float4*>(&As[ra0 + 64][ga * 4]) =
            *reinterpret_cast<const float4*>(&Hin[arow1 + kt + ga * 4]);
        *reinterpret_cast<float4*>(&Bs[kb0][cb * 4]) =
            *reinterpret_cast<const float4*>(&B[(size_t)(kt + kb0) * DH + colBase + cb * 4]);
        *reinterpret_cast<float4*>(&Bs[kb0 + 8][cb * 4]) =
            *reinterpret_cast<const float4*>(&B[(size_t)(kt + kb0 + 8) * DH + colBase + cb * 4]);
        __syncthreads();
#pragma unroll
        for (int k4 = 0; k4 < 16; k4 += 4) {
            alignas(16) float ar[8][4];
#pragma unroll
            for (int i = 0; i < 8; ++i)
                *reinterpret_cast<float4*>(ar[i]) =
                    *reinterpret_cast<const float4*>(&As[ty * 8 + i][k4]);
#pragma unroll
            for (int kk = 0; kk < 4; ++kk) {
                alignas(16) float br[8];
                *reinterpret_cast<float4*>(&br[0]) =
                    *reinterpret_cast<const float4*>(&Bs[k4 + kk][tx * 8]);
                *reinterpret_cast<float4*>(&br[4]) =
                    *reinterpret_cast<const float4*>(&Bs[k4 + kk][tx * 8 + 4]);
#pragma unroll
                for (int i = 0; i < 8; ++i) {
                    const float a = ar[i][kk];
#pragma unroll
                    for (int j = 0; j < 8; ++j)
                        acc[i][j] = fmaf(a, br[j], acc[i][j]);
                }
            }
        }
        __syncthreads();
    }

    alignas(16) float bb[8];
#pragma unroll
    for (int j = 0; j < 8; ++j) bb[j] = be[(size_t)e * DH + colBase + tx * 8 + j];
#pragma unroll
    for (int i = 0; i < 8; ++i) {
        const int rl = ty * 8 + i;
        if (rl < m) {
            const int g = rs[rl];
            const float s = ss[rl];
            alignas(16) float o[8];
#pragma unroll
            for (int j = 0; j < 8; ++j) o[j] = s * (acc[i][j] + bb[j]);
            float* pp = &P[(size_t)g * DH + colBase + tx * 8];
            if (SLOT == 0) {
                *reinterpret_cast<float4*>(pp)     = *reinterpret_cast<float4*>(&o[0]);
                *reinterpret_cast<float4*>(pp + 4) = *reinterpret_cast<float4*>(&o[4]);
            } else {
                const float4 p0 = *reinterpret_cast<const float4*>(pp);
                const float4 p1 = *reinterpret_cast<const float4*>(pp + 4);
                alignas(16) float h[8];
                h[0] = fmaxf(o[0] + p0.x, 0.f); h[1] = fmaxf(o[1] + p0.y, 0.f);
                h[2] = fmaxf(o[2] + p0.z, 0.f); h[3] = fmaxf(o[3] + p0.w, 0.f);
                h[4] = fmaxf(o[4] + p1.x, 0.f); h[5] = fmaxf(o[5] + p1.y, 0.f);
                h[6] = fmaxf(o[6] + p1.z, 0.f); h[7] = fmaxf(o[7] + p1.w, 0.f);
                *reinterpret_cast<float4*>(pp)     = *reinterpret_cast<float4*>(&h[0]);
                *reinterpret_cast<float4*>(pp + 4) = *reinterpret_cast<float4*>(&h[4]);
                if (Ybf) {
                    bh8 yb;
#pragma unroll
                    for (int j = 0; j < 8; ++j) yb[j] = f2bf(h[j]);
                    *reinterpret_cast<bh8*>(&Ybf[(size_t)g * DH + colBase + tx * 8]) = yb;
                }
            }
        }
    }
}

// ------------------------------------------------------------------
// Weight transpose+convert: W[K][N] fp32 -> WT[N][K] bf16 (per z-slab)
// ------------------------------------------------------------------
__global__ __launch_bounds__(256)
void transp_bf16(const float* __restrict__ W, short* __restrict__ WT,
                 int K, int N)
{
    __shared__ float t[32][33];
    const int k0 = blockIdx.x * 32, n0 = blockIdx.y * 32;
    const size_t off = (size_t)blockIdx.z * K * N;
    const int c = threadIdx.x & 31, r8 = threadIdx.x >> 5;
#pragma unroll
    for (int it = 0; it < 4; ++it) {
        const int r = r8 + it * 8;
        t[r][c] = W[off + (size_t)(k0 + r) * N + n0 + c];
    }
    __syncthreads();
#pragma unroll
    for (int it = 0; it < 4; ++it) {
        const int r = r8 + it * 8;
        WT[off + (size_t)(n0 + r) * K + k0 + c] = f2bf(t[c][r]);
    }
}

// ------------------------------------------------------------------
// bf16-MFMA grouped expert GEMM (MoE layer 2, output path) — R4 numerics.
// BFA=1: A read directly from pre-converted bf16 (identical bits);
// SLOT 1 + BFA=1 writes only Hbf (bf16 final H) instead of fp32 H.
// ------------------------------------------------------------------
template<int SLOT, int BFA>
__global__ __launch_bounds__(256)
void gemm_expert_bf16(const float* __restrict__ Yf, const short* __restrict__ Abf,
                      const short* __restrict__ WeT,
                      const float* __restrict__ be, const RInfo* __restrict__ info,
                      const int* __restrict__ list, const int* __restrict__ cnts,
                      const int* __restrict__ offs, float* __restrict__ P,
                      short* __restrict__ Hbf)
{
    __shared__ bh8 As8[512];
    __shared__ bh8 Bs8[512];
    __shared__ int   rs[128];
    __shared__ float ss[128];

    int c = blockIdx.x, e;
    int cnt = 0;
    for (e = 0; e < NE; ++e) {
        cnt = cnts[e];
        const int nch = (cnt + 127) >> 7;
        if (c < nch) break;
        c -= nch;
    }
    if (e >= NE) return;
    const int m = min(128, cnt - c * 128);
    const int base = offs[e] + c * 128;
    const int tid = threadIdx.x;

    if (tid < 128) {
        const int g = list[base + min(tid, m - 1)];
        rs[tid] = g;
        const RInfo ri = info[g];
        ss[tid] = (SLOT == 0) ? ri.s1 : ri.s2;
    }
    __syncthreads();

    const int colBase = blockIdx.y * 128;
    const int lane = tid & 63, wave = tid >> 6;
    const int wr = wave >> 1, wc = wave & 1;
    const short* Bw = WeT + (size_t)e * DH * DH;

    fx4 acc[4][4];
    const fx4 z = {0.f, 0.f, 0.f, 0.f};
#pragma unroll
    for (int i = 0; i < 4; ++i)
#pragma unroll
        for (int j = 0; j < 4; ++j) acc[i][j] = z;

    const int d0 = tid, d1 = tid + 256;
    const int ar0 = d0 >> 2, ak0 = d0 & 3;
    const int ar1 = d1 >> 2, ak1 = d1 & 3;
    const int g0 = ar0 * 4 + (ak0 ^ ((ar0 >> 1) & 3));
    const int g1 = ar1 * 4 + (ak1 ^ ((ar1 >> 1) & 3));
    const size_t arow0 = (size_t)rs[ar0] * DH, arow1 = (size_t)rs[ar1] * DH;
    const size_t brow0 = (size_t)(colBase + ar0) * DH, brow1 = (size_t)(colBase + ar1) * DH;

    for (int kt = 0; kt < DH; kt += 32) {
        if (BFA) {   // A already bf16 (same bits as f2bf in-flight)
            As8[g0] = *reinterpret_cast<const bh8*>(&Abf[arow0 + kt + ak0 * 8]);
            As8[g1] = *reinterpret_cast<const bh8*>(&Abf[arow1 + kt + ak1 * 8]);
        } else {
            const float* s0 = &Yf[arow0 + kt + ak0 * 8];
            const float4 f0 = *reinterpret_cast<const float4*>(s0);
            const float4 f1 = *reinterpret_cast<const float4*>(s0 + 4);
            bh8 v;
            v[0]=f2bf(f0.x); v[1]=f2bf(f0.y); v[2]=f2bf(f0.z); v[3]=f2bf(f0.w);
            v[4]=f2bf(f1.x); v[5]=f2bf(f1.y); v[6]=f2bf(f1.z); v[7]=f2bf(f1.w);
            As8[g0] = v;
            const float* s1 = &Yf[arow1 + kt + ak1 * 8];
            const float4 f2 = *reinterpret_cast<const float4*>(s1);
            const float4 f3 = *reinterpret_cast<const float4*>(s1 + 4);
            bh8 w;
            w[0]=f2bf(f2.x); w[1]=f2bf(f2.y); w[2]=f2bf(f2.z); w[3]=f2bf(f2.w);
            w[4]=f2bf(f3.x); w[5]=f2bf(f3.y); w[6]=f2bf(f3.z); w[7]=f2bf(f3.w);
            As8[g1] = w;
        }
        {
            Bs8[g0] = *reinterpret_cast<const bh8*>(&Bw[brow0 + kt + ak0 * 8]);
            Bs8[g1] = *reinterpret_cast<const bh8*>(&Bw[brow1 + kt + ak1 * 8]);
        }
        __syncthreads();
        const int kq = lane >> 4, lm = lane & 15;
        bh8 af[4], bfr[4];
#pragma unroll
        for (int i = 0; i < 4; ++i) {
            const int rl = wr * 64 + i * 16 + lm;
            af[i] = As8[rl * 4 + (kq ^ ((rl >> 1) & 3))];
            const int cl = wc * 64 + i * 16 + lm;
            bfr[i] = Bs8[cl * 4 + (kq ^ ((cl >> 1) & 3))];
        }
#pragma unroll
        for (int i = 0; i < 4; ++i)
#pragma unroll
            for (int j = 0; j < 4; ++j)
                acc[i][j] = __builtin_amdgcn_mfma_f32_16x16x32_bf16(
                    af[i], bfr[j], acc[i][j], 0, 0, 0);
        __syncthreads();
    }

    const int rq = lane >> 4, lm = lane & 15;
#pragma unroll
    for (int i = 0; i < 4; ++i) {
#pragma unroll
        for (int j = 0; j < 4; ++j) {
            const int rl = wr * 64 + i * 16 + rq * 4 + j;
            if (rl < m) {
                const int g = rs[rl];
                const float s = ss[rl];
#pragma unroll
                for (int nf = 0; nf < 4; ++nf) {
                    const int cl = colBase + wc * 64 + nf * 16 + lm;
                    float* pp = &P[(size_t)g * DH + cl];
                    const float o = s * (acc[i][nf][j] + be[(size_t)e * DH + cl]);
                    if (SLOT == 0) {
                        *pp = o;
                    } else {
                        const float v = fmaxf(*pp + o, 0.f);
                        if (BFA) Hbf[(size_t)g * DH + cl] = f2bf(v);
                        else     *pp = v;
                    }
                }
            }
        }
    }
}

// ------------------------------------------------------------------
// bf16-MFMA final GEMM: out = H@Wf + bf (+ scalar). BFA=1 reads bf16 H.
// ------------------------------------------------------------------
template<int BFA>
__global__ __launch_bounds__(256)
void gemm_final_bf16(const float* __restrict__ Hf, const short* __restrict__ Habf,
                     const short* __restrict__ WT,
                     const float* __restrict__ bias, float* __restrict__ C,
                     const float* gsum, float* scalar_out)
{
    __shared__ bh8 As8[512];
    __shared__ bh8 Bs8[512];
    const int tid = threadIdx.x;
    const int rowBase = blockIdx.x * 128;

    if (blockIdx.x == 0 && tid == 0)
        *scalar_out = (gsum[0] + gsum[1]) * (0.5f / (float)NT);

    const int lane = tid & 63, wave = tid >> 6;
    const int wr = wave >> 1, wc = wave & 1;

    fx4 acc[4][4];
    const fx4 z = {0.f, 0.f, 0.f, 0.f};
#pragma unroll
    for (int i = 0; i < 4; ++i)
#pragma unroll
        for (int j = 0; j < 4; ++j) acc[i][j] = z;

    const int d0 = tid, d1 = tid + 256;
    const int ar0 = d0 >> 2, ak0 = d0 & 3;
    const int ar1 = d1 >> 2, ak1 = d1 & 3;
    const int g0 = ar0 * 4 + (ak0 ^ ((ar0 >> 1) & 3));
    const int g1 = ar1 * 4 + (ak1 ^ ((ar1 >> 1) & 3));
    const size_t arow0 = (size_t)(rowBase + ar0) * DH, arow1 = (size_t)(rowBase + ar1) * DH;
    const size_t brow0 = (size_t)ar0 * DH, brow1 = (size_t)ar1 * DH;

    for (int kt = 0; kt < DH; kt += 32) {
        if (BFA) {
            As8[g0] = *reinterpret_cast<const bh8*>(&Habf[arow0 + kt + ak0 * 8]);
            As8[g1] = *reinterpret_cast<const bh8*>(&Habf[arow1 + kt + ak1 * 8]);
        } else {
            const float* s0 = &Hf[arow0 + kt + ak0 * 8];
            const float4 f0 = *reinterpret_cast<const float4*>(s0);
            const float4 f1 = *reinterpret_cast<const float4*>(s0 + 4);
            bh8 v;
            v[0]=f2bf(f0.x); v[1]=f2bf(f0.y); v[2]=f2bf(f0.z); v[3]=f2bf(f0.w);
            v[4]=f2bf(f1.x); v[5]=f2bf(f1.y); v[6]=f2bf(f1.z); v[7]=f2bf(f1.w);
            As8[g0] = v;
            const float* s1 = &Hf[arow1 + kt + ak1 * 8];
            const float4 f2 = *reinterpret_cast<const float4*>(s1);
            const float4 f3 = *reinterpret_cast<const float4*>(s1 + 4);
            bh8 w;
            w[0]=f2bf(f2.x); w[1]=f2bf(f2.y); w[2]=f2bf(f2.z); w[3]=f2bf(f2.w);
            w[4]=f2bf(f3.x); w[5]=f2bf(f3.y); w[6]=f2bf(f3.z); w[7]=f2bf(f3.w);
            As8[g1] = w;
        }
        {
            Bs8[g0] = *reinterpret_cast<const bh8*>(&WT[brow0 + kt + ak0 * 8]);
            Bs8[g1] = *reinterpret_cast<const bh8*>(&WT[brow1 + kt + ak1 * 8]);
        }
        __syncthreads();
        const int kq = lane >> 4, lm = lane & 15;
        bh8 af[4], bfr[4];
#pragma unroll
        for (int i = 0; i < 4; ++i) {
            const int rl = wr * 64 + i * 16 + lm;
            af[i] = As8[rl * 4 + (kq ^ ((rl >> 1) & 3))];
            const int cl = wc * 64 + i * 16 + lm;
            bfr[i] = Bs8[cl * 4 + (kq ^ ((cl >> 1) & 3))];
        }
#pragma unroll
        for (int i = 0; i < 4; ++i)
#pragma unroll
            for (int j = 0; j < 4; ++j)
                acc[i][j] = __builtin_amdgcn_mfma_f32_16x16x32_bf16(
                    af[i], bfr[j], acc[i][j], 0, 0, 0);
        __syncthreads();
    }

    const int rq = lane >> 4, lm = lane & 15;
#pragma unroll
    for (int i = 0; i < 4; ++i) {
#pragma unroll
        for (int j = 0; j < 4; ++j) {
            const int rl = rowBase + wr * 64 + i * 16 + rq * 4 + j;
#pragma unroll
            for (int nf = 0; nf < 4; ++nf) {
                const int cl = wc * 64 + nf * 16 + lm;
                C[(size_t)rl * DO + cl] = acc[i][nf][j] + bias[cl];
            }
        }
    }
}

// ------------------------------------------------------------------
extern "C" void kernel_launch(void* const* d_in, const int* in_sizes, int n_in,
                              void* d_out, int out_size, void* d_ws, size_t ws_size,
                              hipStream_t stream)
{
    const float* x   = (const float*)d_in[0];
    const float* W0  = (const float*)d_in[1];
    const float* b0  = (const float*)d_in[2];
    const float* Wg1 = (const float*)d_in[3];
    const float* bg1 = (const float*)d_in[4];
    const float* We1 = (const float*)d_in[5];
    const float* be1 = (const float*)d_in[6];
    const float* Wg2 = (const float*)d_in[7];
    const float* bg2 = (const float*)d_in[8];
    const float* We2 = (const float*)d_in[9];
    const float* be2 = (const float*)d_in[10];
    const float* Wf  = (const float*)d_in[11];
    const float* bf  = (const float*)d_in[12];
    float* out = (float*)d_out;

    char* w = (char*)d_ws;
    float* H    = (float*)w; w += (size_t)NT * DH * 4;
    float* Y    = (float*)w; w += (size_t)NT * DH * 4;
    RInfo* info = (RInfo*)w; w += (size_t)NT * sizeof(RInfo);
    int* l0   = (int*)w; w += (size_t)NT * 4;
    int* l1   = (int*)w; w += (size_t)NT * 4;
    int* bc0  = (int*)w; w += NE * 256 * 4;
    int* bc1  = (int*)w; w += NE * 256 * 4;
    int* bo0  = (int*)w; w += NE * 256 * 4;
    int* bo1  = (int*)w; w += NE * 256 * 4;
    int* cnt0 = (int*)w; w += 64;
    int* cnt1 = (int*)w; w += 64;
    int* off0 = (int*)w; w += 64;
    int* off1 = (int*)w; w += 64;
    float* gsum = (float*)w; w += 64;
    short* WeT = (short*)w; w += (size_t)NE * DH * DH * 2;   // 2 MB
    short* WfT = (short*)w; w += (size_t)DH * DO * 2;        // 64 KB
    short* Ybf = (short*)w; w += (size_t)NT * DH * 2;        // 33.5 MB (optional)
    const bool roomy = (size_t)(w - (char*)d_ws) <= ws_size;
    short* Hbf = (short*)Y;   // aliases Y: Y fp32 is dead after gate2 in roomy path

    const int MAXCH = NT / 128 + NE;   // 528

    zero_gsum<<<dim3(1), dim3(64), 0, stream>>>(gsum);
    transp_bf16<<<dim3(8, 8, 16), dim3(256), 0, stream>>>(We2, WeT, DH, DH);
    transp_bf16<<<dim3(8, 4, 1),  dim3(256), 0, stream>>>(Wf,  WfT, DH, DO);

    // layer 0 (fp32, gate-critical): H = relu(x @ W0 + b0)
    gemm_dense<true><<<dim3(NT / 128, 2), dim3(256), 0, stream>>>(x, W0, b0, H, DH);

    // MoE layer 1 (fp32, gate-critical): read H, build Y (+Ybf if roomy)
    gate_kernel<<<dim3(NT / 16), dim3(256), 0, stream>>>(H, Wg1, bg1, info, &gsum[0]);
    count_kernel<<<dim3(NT / 256), dim3(256), 0, stream>>>(info, bc0, bc1);
    scan2_kernel<<<dim3(1), dim3(64), 0, stream>>>(bc0, bc1, cnt0, cnt1, off0, off1, bo0, bo1);
    scatter2_kernel<<<dim3(NT / 256), dim3(256), 0, stream>>>(info, bo0, bo1, l0, l1);
    gemm_expert<0><<<dim3(MAXCH, 2), dim3(256), 0, stream>>>(H, We1, be1, info, l0, cnt0, off0, Y, nullptr);
    gemm_expert<1><<<dim3(MAXCH, 2), dim3(256), 0, stream>>>(H, We1, be1, info, l1, cnt1, off1, Y,
                                                             roomy ? Ybf : nullptr);

    // MoE layer 2 (bf16 MFMA, output path): read Y/Ybf, build H/Hbf
    gate_kernel<<<dim3(NT / 16), dim3(256), 0, stream>>>(Y, Wg2, bg2, info, &gsum[1]);
    count_kernel<<<dim3(NT / 256), dim3(256), 0, stream>>>(info, bc0, bc1);
    scan2_kernel<<<dim3(1), dim3(64), 0, stream>>>(bc0, bc1, cnt0, cnt1, off0, off1, bo0, bo1);
    scatter2_kernel<<<dim3(NT / 256), dim3(256), 0, stream>>>(info, bo0, bo1, l0, l1);
    if (roomy) {
        gemm_expert_bf16<0,1><<<dim3(MAXCH, 2), dim3(256), 0, stream>>>(Y, Ybf, WeT, be2, info, l0, cnt0, off0, H, nullptr);
        gemm_expert_bf16<1,1><<<dim3(MAXCH, 2), dim3(256), 0, stream>>>(Y, Ybf, WeT, be2, info, l1, cnt1, off1, H, Hbf);
        gemm_final_bf16<1><<<dim3(NT / 128), dim3(256), 0, stream>>>(H, Hbf, WfT, bf, out, gsum, out + (size_t)NT * DO);
    } else {
        gemm_expert_bf16<0,0><<<dim3(MAXCH, 2), dim3(256), 0, stream>>>(Y, nullptr, WeT, be2, info, l0, cnt0, off0, H, nullptr);
        gemm_expert_bf16<1,0><<<dim3(MAXCH, 2), dim3(256), 0, stream>>>(Y, nullptr, WeT, be2, info, l1, cnt1, off1, H, nullptr);
        gemm_final_bf16<0><<<dim3(NT / 128), dim3(256), 0, stream>>>(H, nullptr, WfT, bf, out, gsum, out + (size_t)NT * DO);
    }
}

// Round 11
// 610.892 us; speedup vs baseline: 1.2950x; 1.0312x over previous
//
#include <hip/hip_runtime.h>
#include <math.h>

#define NT 65536
#define DH 256
#define DO 128
#define NE 16
#define MAXCH 528        // NT/128 + NE
#define CPX 66           // MAXCH / 8 XCDs

struct RInfo { int e1, e2; float s1, s2; };

typedef __attribute__((ext_vector_type(8))) short bh8;   // 8 bf16 (4 VGPR)
typedef __attribute__((ext_vector_type(4))) float fx4;   // MFMA acc

static __device__ __forceinline__ short f2bf(float f) {
    union { float f; unsigned u; } v; v.f = f;
    return (short)((v.u + 0x7FFFu + ((v.u >> 16) & 1u)) >> 16);   // RNE
}

// ------------------------------------------------------------------
// fp32 dense GEMM (gate-critical layer 0) — EXACT R4 body (bit-exact).
// ------------------------------------------------------------------
template<bool RELU>
__global__ __launch_bounds__(256)
void gemm_dense(const float* __restrict__ A, const float* __restrict__ B,
                const float* __restrict__ bias, float* __restrict__ C,
                int ncols)
{
    __shared__ float As[128][36];
    __shared__ float Bs[32][132];
    const int tid = threadIdx.x;
    const int tx = tid & 15, ty = tid >> 4;
    const int rowBase = blockIdx.x * 128;
    const int colBase = blockIdx.y * 128;

    float acc[8][8];
#pragma unroll
    for (int i = 0; i < 8; ++i)
#pragma unroll
        for (int j = 0; j < 8; ++j) acc[i][j] = 0.f;

    for (int kt = 0; kt < DH; kt += 32) {
        {
            const int r = tid >> 3, k4 = (tid & 7) << 2;
#pragma unroll
            for (int it = 0; it < 4; ++it) {
                const float4 v = *reinterpret_cast<const float4*>(
                    &A[(size_t)(rowBase + r + 32 * it) * DH + kt + k4]);
                *reinterpret_cast<float4*>(&As[r + 32 * it][k4]) = v;
            }
        }
        {
            const int kr = tid >> 5, c4 = (tid & 31) << 2;
#pragma unroll
            for (int it = 0; it < 4; ++it) {
                const float4 v = *reinterpret_cast<const float4*>(
                    &B[(size_t)(kt + kr + 8 * it) * ncols + colBase + c4]);
                *reinterpret_cast<float4*>(&Bs[kr + 8 * it][c4]) = v;
            }
        }
        __syncthreads();
#pragma unroll
        for (int k4 = 0; k4 < 32; k4 += 4) {
            alignas(16) float ar[8][4];
#pragma unroll
            for (int i = 0; i < 8; ++i)
                *reinterpret_cast<float4*>(ar[i]) =
                    *reinterpret_cast<const float4*>(&As[ty * 8 + i][k4]);
#pragma unroll
            for (int kk = 0; kk < 4; ++kk) {
                alignas(16) float br[8];
                *reinterpret_cast<float4*>(&br[0]) =
                    *reinterpret_cast<const float4*>(&Bs[k4 + kk][tx * 8]);
                *reinterpret_cast<float4*>(&br[4]) =
                    *reinterpret_cast<const float4*>(&Bs[k4 + kk][tx * 8 + 4]);
#pragma unroll
                for (int i = 0; i < 8; ++i) {
                    const float a = ar[i][kk];
#pragma unroll
                    for (int j = 0; j < 8; ++j)
                        acc[i][j] = fmaf(a, br[j], acc[i][j]);
                }
            }
        }
        __syncthreads();
    }
    alignas(16) float bb[8];
#pragma unroll
    for (int j = 0; j < 8; ++j) bb[j] = bias[colBase + tx * 8 + j];
#pragma unroll
    for (int i = 0; i < 8; ++i) {
        const size_t row = rowBase + ty * 8 + i;
        alignas(16) float o[8];
#pragma unroll
        for (int j = 0; j < 8; ++j) {
            float v = acc[i][j] + bb[j];
            if (RELU) v = fmaxf(v, 0.f);
            o[j] = v;
        }
        float* p = &C[row * (size_t)ncols + colBase + tx * 8];
        *reinterpret_cast<float4*>(p)     = *reinterpret_cast<float4*>(&o[0]);
        *reinterpret_cast<float4*>(p + 4) = *reinterpret_cast<float4*>(&o[4]);
    }
}

// ------------------------------------------------------------------
// Gate — logit arithmetic bit-identical to R3..R10. Adds: float4 Wg
// staging (pad 20, same values), fused per-block expert histogram
// (replaces count_kernel; fire-and-forget atomics).
// ------------------------------------------------------------------
__global__ __launch_bounds__(256)
void gate_kernel(const float* __restrict__ H, const float* __restrict__ Wg,
                 const float* __restrict__ bg, RInfo* __restrict__ info,
                 float* gsum, int* __restrict__ bc0, int* __restrict__ bc1)
{
    __shared__ float wgs[256][20];
    __shared__ float hs[16][260];
    __shared__ float lg[16][17];
    __shared__ float sbg[16];
    __shared__ float sds[16];
    __shared__ int hh0[NE], hh1[NE];
    const int tid = threadIdx.x;
    const int rowBase = blockIdx.x * 16;

#pragma unroll
    for (int it = 0; it < 4; ++it) {
        const int flat = (tid + 256 * it) * 4;      // 0..16380, %16 in {0,4,8,12}
        const int k = flat >> 4, e4 = flat & 15;
        *reinterpret_cast<float4*>(&wgs[k][e4]) =
            *reinterpret_cast<const float4*>(&Wg[flat]);
    }
    if (tid < 16) { sbg[tid] = bg[tid]; hh0[tid] = 0; hh1[tid] = 0; }
#pragma unroll
    for (int it = 0; it < 4; ++it) {
        const int flat = (tid + 256 * it) * 4;
        const int r = flat >> 8, k = flat & 255;
        *reinterpret_cast<float4*>(&hs[r][k]) =
            *reinterpret_cast<const float4*>(&H[(size_t)(rowBase + r) * DH + k]);
    }
    __syncthreads();
    {
        const int r = tid >> 4, e = tid & 15;
        float acc = 0.f;
#pragma unroll 8
        for (int k = 0; k < 256; ++k) acc = fmaf(hs[r][k], wgs[k][e], acc);
        lg[r][e] = acc + sbg[e];
    }
    __syncthreads();
    if (tid < 16) {
        const int row = rowBase + tid;
        float l[16];
#pragma unroll
        for (int i = 0; i < 16; ++i) l[i] = lg[tid][i];
        int i1 = 0; float v1 = l[0];
#pragma unroll
        for (int i = 1; i < 16; ++i) if (l[i] > v1) { v1 = l[i]; i1 = i; }
        int i2 = -1; float v2 = -INFINITY;
#pragma unroll
        for (int i = 0; i < 16; ++i) if (i != i1 && l[i] > v2) { v2 = l[i]; i2 = i; }
        const float t = expf(v2 - v1);
        const float s1 = 1.f / (1.f + t);
        const float s2 = t / (1.f + t);
        float p[16]; float S = 0.f;
#pragma unroll
        for (int i = 0; i < 16; ++i) { p[i] = expf(l[i] - v1); S += p[i]; }
        const float inv = 1.f / S;
        float sq = 0.f;
#pragma unroll
        for (int i = 0; i < 16; ++i) { const float q = p[i] * inv; sq = fmaf(q, q, sq); }
        const float var = (sq - 1.0f / 16.0f) * (1.0f / 15.0f);
        const float sd = sqrtf(fmaxf(var, 0.f));

        RInfo ri; ri.e1 = i1; ri.e2 = i2; ri.s1 = s1; ri.s2 = s2;
        info[row] = ri;
        sds[tid] = sd;
        atomicAdd(&hh0[i1], 1);
        atomicAdd(&hh1[i2], 1);
    }
    __syncthreads();
    if (tid == 0) {
        float s = 0.f;
#pragma unroll
        for (int i = 0; i < 16; ++i) s += sds[i];
        atomicAdd(gsum, s);
    }
    if (tid < 16) {
        const int b = blockIdx.x >> 4;              // 256-row super-block
        if (hh0[tid]) atomicAdd(&bc0[tid * 256 + b], hh0[tid]);
        if (hh1[tid]) atomicAdd(&bc1[tid * 256 + b], hh1[tid]);
    }
}

__global__ void zero_meta(int* bc0, int* bc1, float* gsum)
{
    const int idx = blockIdx.x * 256 + threadIdx.x;   // grid 16 -> 4096
    bc0[idx] = 0; bc1[idx] = 0;
    if (idx < 2) gsum[idx] = 0.f;
}

// ------------------------------------------------------------------
// scan: totals + per-block offsets; re-zeros bc for the next layer.
// ------------------------------------------------------------------
__global__ void scan2_kernel(int* __restrict__ bc0, int* __restrict__ bc1,
                             int* cnt0, int* cnt1, int* off0, int* off1,
                             int* __restrict__ bo0, int* __restrict__ bo1)
{
    __shared__ int tot0[NE], tot1[NE], base0[NE], base1[NE];
    const int t = threadIdx.x;
    if (t < NE) {
        int s = 0;
        for (int b = 0; b < 256; ++b) s += bc0[t * 256 + b];
        tot0[t] = s; cnt0[t] = s;
    } else if (t < 2 * NE) {
        const int e = t - NE;
        int s = 0;
        for (int b = 0; b < 256; ++b) s += bc1[e * 256 + b];
        tot1[e] = s; cnt1[e] = s;
    }
    __syncthreads();
    if (t == 0) { int a = 0; for (int e = 0; e < NE; ++e) { base0[e] = a; off0[e] = a; a += tot0[e]; } }
    if (t == 1) { int a = 0; for (int e = 0; e < NE; ++e) { base1[e] = a; off1[e] = a; a += tot1[e]; } }
    __syncthreads();
    if (t < NE) {
        int run = base0[t];
        for (int b = 0; b < 256; ++b) { bo0[t * 256 + b] = run; run += bc0[t * 256 + b]; }
    } else if (t < 2 * NE) {
        const int e = t - NE;
        int run = base1[e];
        for (int b = 0; b < 256; ++b) { bo1[e * 256 + b] = run; run += bc1[e * 256 + b]; }
    }
    __syncthreads();
    for (int i = t; i < NE * 256; i += 64) { bc0[i] = 0; bc1[i] = 0; }
}

__global__ __launch_bounds__(256)
void scatter2_kernel(const RInfo* __restrict__ info, const int* __restrict__ bo0,
                     const int* __restrict__ bo1, int* __restrict__ l0,
                     int* __restrict__ l1)
{
    __shared__ int h0[NE], h1[NE];
    const int tid = threadIdx.x, b = blockIdx.x;
    if (tid < NE) { h0[tid] = 0; h1[tid] = 0; }
    __syncthreads();
    const int r = b * 256 + tid;
    const RInfo ri = info[r];
    const int p0 = atomicAdd(&h0[ri.e1], 1);
    const int p1 = atomicAdd(&h1[ri.e2], 1);
    l0[bo0[ri.e1 * 256 + b] + p0] = r;
    l1[bo1[ri.e2 * 256 + b] + p1] = r;
}

// ------------------------------------------------------------------
// fp32 grouped expert GEMM (MoE layer 1, gate-critical) — EXACT R4 body
// (bit-exact FMA chains). Adds: XCD chunk swizzle (speed-only), Ybf emit.
// ------------------------------------------------------------------
template<int SLOT>
__global__ __launch_bounds__(256)
void gemm_expert(const float* __restrict__ Hin, const float* __restrict__ We,
                 const float* __restrict__ be, const RInfo* __restrict__ info,
                 const int* __restrict__ list, const int* __restrict__ cnts,
                 const int* __restrict__ offs, float* __restrict__ P,
                 short* __restrict__ Ybf)
{
    __shared__ float As[128][36];
    __shared__ float Bs[32][132];
    __shared__ int   rs[128];
    __shared__ float ss[128];

    int c = (blockIdx.x & 7) * CPX + (blockIdx.x >> 3);   // XCD-contiguous chunks
    int e;
    int cnt = 0;
    for (e = 0; e < NE; ++e) {
        cnt = cnts[e];
        const int nch = (cnt + 127) >> 7;
        if (c < nch) break;
        c -= nch;
    }
    if (e >= NE) return;
    const int m = min(128, cnt - c * 128);
    const int base = offs[e] + c * 128;
    const int tid = threadIdx.x;
    const int tx = tid & 15, ty = tid >> 4;
    const int colBase = blockIdx.y * 128;

    if (tid < 128) {
        const int g = list[base + min(tid, m - 1)];
        rs[tid] = g;
        const RInfo ri = info[g];
        ss[tid] = (SLOT == 0) ? ri.s1 : ri.s2;
    }
    __syncthreads();

    const float* B = We + (size_t)e * DH * DH;

    float acc[8][8];
#pragma unroll
    for (int i = 0; i < 8; ++i)
#pragma unroll
        for (int j = 0; j < 8; ++j) acc[i][j] = 0.f;

    for (int kt = 0; kt < DH; kt += 32) {
        {
            const int r = tid >> 3, k4 = (tid & 7) << 2;
#pragma unroll
            for (int it = 0; it < 4; ++it) {
                const int g = rs[r + 32 * it];
                const float4 v = *reinterpret_cast<const float4*>(
                    &Hin[(size_t)g * DH + kt + k4]);
                *reinterpret_cast<float4*>(&As[r + 32 * it][k4]) = v;
            }
        }
        {
            const int kr = tid >> 5, c4 = (tid & 31) << 2;
#pragma unroll
            for (int it = 0; it < 4; ++it) {
                const float4 v = *reinterpret_cast<const float4*>(
                    &B[(size_t)(kt + kr + 8 * it) * DH + colBase + c4]);
                *reinterpret_cast<float4*>(&Bs[kr + 8 * it][c4]) = v;
            }
        }
        __syncthreads();
#pragma unroll
        for (int k4 = 0; k4 < 32; k4 += 4) {
            alignas(16) float ar[8][4];
#pragma unroll
            for (int i = 0; i < 8; ++i)
                *reinterpret_cast<float4*>(ar[i]) =
                    *reinterpret_cast<const float4*>(&As[ty * 8 + i][k4]);
#pragma unroll
            for (int kk = 0; kk < 4; ++kk) {
                alignas(16) float br[8];
                *reinterpret_cast<float4*>(&br[0]) =
                    *reinterpret_cast<const float4*>(&Bs[k4 + kk][tx * 8]);
                *reinterpret_cast<float4*>(&br[4]) =
                    *reinterpret_cast<const float4*>(&Bs[k4 + kk][tx * 8 + 4]);
#pragma unroll
                for (int i = 0; i < 8; ++i) {
                    const float a = ar[i][kk];
#pragma unroll
                    for (int j = 0; j < 8; ++j)
                        acc[i][j] = fmaf(a, br[j], acc[i][j]);
                }
            }
        }
        __syncthreads();
    }

    alignas(16) float bb[8];
#pragma unroll
    for (int j = 0; j < 8; ++j) bb[j] = be[(size_t)e * DH + colBase + tx * 8 + j];
#pragma unroll
    for (int i = 0; i < 8; ++i) {
        const int rl = ty * 8 + i;
        if (rl < m) {
            const int g = rs[rl];
            const float s = ss[rl];
            alignas(16) float o[8];
#pragma unroll
            for (int j = 0; j < 8; ++j) o[j] = s * (acc[i][j] + bb[j]);
            float* pp = &P[(size_t)g * DH + colBase + tx * 8];
            if (SLOT == 0) {
                *reinterpret_cast<float4*>(pp)     = *reinterpret_cast<float4*>(&o[0]);
                *reinterpret_cast<float4*>(pp + 4) = *reinterpret_cast<float4*>(&o[4]);
            } else {
                const float4 p0 = *reinterpret_cast<const float4*>(pp);
                const float4 p1 = *reinterpret_cast<const float4*>(pp + 4);
                alignas(16) float h[8];
                h[0] = fmaxf(o[0] + p0.x, 0.f); h[1] = fmaxf(o[1] + p0.y, 0.f);
                h[2] = fmaxf(o[2] + p0.z, 0.f); h[3] = fmaxf(o[3] + p0.w, 0.f);
                h[4] = fmaxf(o[4] + p1.x, 0.f); h[5] = fmaxf(o[5] + p1.y, 0.f);
                h[6] = fmaxf(o[6] + p1.z, 0.f); h[7] = fmaxf(o[7] + p1.w, 0.f);
                *reinterpret_cast<float4*>(pp)     = *reinterpret_cast<float4*>(&h[0]);
                *reinterpret_cast<float4*>(pp + 4) = *reinterpret_cast<float4*>(&h[4]);
                if (Ybf) {
                    bh8 yb;
#pragma unroll
                    for (int j = 0; j < 8; ++j) yb[j] = f2bf(h[j]);
                    *reinterpret_cast<bh8*>(&Ybf[(size_t)g * DH + colBase + tx * 8]) = yb;
                }
            }
        }
    }
}

// ------------------------------------------------------------------
// Weight transpose+convert: W[K][N] fp32 -> WT[N][K] bf16 (per z-slab)
// ------------------------------------------------------------------
__global__ __launch_bounds__(256)
void transp_bf16(const float* __restrict__ W, short* __restrict__ WT,
                 int K, int N)
{
    __shared__ float t[32][33];
    const int k0 = blockIdx.x * 32, n0 = blockIdx.y * 32;
    const size_t off = (size_t)blockIdx.z * K * N;
    const int c = threadIdx.x & 31, r8 = threadIdx.x >> 5;
#pragma unroll
    for (int it = 0; it < 4; ++it) {
        const int r = r8 + it * 8;
        t[r][c] = W[off + (size_t)(k0 + r) * N + n0 + c];
    }
    __syncthreads();
#pragma unroll
    for (int it = 0; it < 4; ++it) {
        const int r = r8 + it * 8;
        WT[off + (size_t)(n0 + r) * K + k0 + c] = f2bf(t[c][r]);
    }
}

// ------------------------------------------------------------------
// bf16-MFMA grouped expert GEMM (MoE layer 2) — R4 numerics + XCD swizzle.
// BFA=1: A from pre-converted bf16 (identical bits); SLOT1+BFA writes Hbf.
// ------------------------------------------------------------------
template<int SLOT, int BFA>
__global__ __launch_bounds__(256)
void gemm_expert_bf16(const float* __restrict__ Yf, const short* __restrict__ Abf,
                      const short* __restrict__ WeT,
                      const float* __restrict__ be, const RInfo* __restrict__ info,
                      const int* __restrict__ list, const int* __restrict__ cnts,
                      const int* __restrict__ offs, float* __restrict__ P,
                      short* __restrict__ Hbf)
{
    __shared__ bh8 As8[512];
    __shared__ bh8 Bs8[512];
    __shared__ int   rs[128];
    __shared__ float ss[128];

    int c = (blockIdx.x & 7) * CPX + (blockIdx.x >> 3);
    int e;
    int cnt = 0;
    for (e = 0; e < NE; ++e) {
        cnt = cnts[e];
        const int nch = (cnt + 127) >> 7;
        if (c < nch) break;
        c -= nch;
    }
    if (e >= NE) return;
    const int m = min(128, cnt - c * 128);
    const int base = offs[e] + c * 128;
    const int tid = threadIdx.x;

    if (tid < 128) {
        const int g = list[base + min(tid, m - 1)];
        rs[tid] = g;
        const RInfo ri = info[g];
        ss[tid] = (SLOT == 0) ? ri.s1 : ri.s2;
    }
    __syncthreads();

    const int colBase = blockIdx.y * 128;
    const int lane = tid & 63, wave = tid >> 6;
    const int wr = wave >> 1, wc = wave & 1;
    const short* Bw = WeT + (size_t)e * DH * DH;

    fx4 acc[4][4];
    const fx4 z = {0.f, 0.f, 0.f, 0.f};
#pragma unroll
    for (int i = 0; i < 4; ++i)
#pragma unroll
        for (int j = 0; j < 4; ++j) acc[i][j] = z;

    const int d0 = tid, d1 = tid + 256;
    const int ar0 = d0 >> 2, ak0 = d0 & 3;
    const int ar1 = d1 >> 2, ak1 = d1 & 3;
    const int g0 = ar0 * 4 + (ak0 ^ ((ar0 >> 1) & 3));
    const int g1 = ar1 * 4 + (ak1 ^ ((ar1 >> 1) & 3));
    const size_t arow0 = (size_t)rs[ar0] * DH, arow1 = (size_t)rs[ar1] * DH;
    const size_t brow0 = (size_t)(colBase + ar0) * DH, brow1 = (size_t)(colBase + ar1) * DH;

    for (int kt = 0; kt < DH; kt += 32) {
        if (BFA) {
            As8[g0] = *reinterpret_cast<const bh8*>(&Abf[arow0 + kt + ak0 * 8]);
            As8[g1] = *reinterpret_cast<const bh8*>(&Abf[arow1 + kt + ak1 * 8]);
        } else {
            const float* s0 = &Yf[arow0 + kt + ak0 * 8];
            const float4 f0 = *reinterpret_cast<const float4*>(s0);
            const float4 f1 = *reinterpret_cast<const float4*>(s0 + 4);
            bh8 v;
            v[0]=f2bf(f0.x); v[1]=f2bf(f0.y); v[2]=f2bf(f0.z); v[3]=f2bf(f0.w);
            v[4]=f2bf(f1.x); v[5]=f2bf(f1.y); v[6]=f2bf(f1.z); v[7]=f2bf(f1.w);
            As8[g0] = v;
            const float* s1 = &Yf[arow1 + kt + ak1 * 8];
            const float4 f2 = *reinterpret_cast<const float4*>(s1);
            const float4 f3 = *reinterpret_cast<const float4*>(s1 + 4);
            bh8 w;
            w[0]=f2bf(f2.x); w[1]=f2bf(f2.y); w[2]=f2bf(f2.z); w[3]=f2bf(f2.w);
            w[4]=f2bf(f3.x); w[5]=f2bf(f3.y); w[6]=f2bf(f3.z); w[7]=f2bf(f3.w);
            As8[g1] = w;
        }
        {
            Bs8[g0] = *reinterpret_cast<const bh8*>(&Bw[brow0 + kt + ak0 * 8]);
            Bs8[g1] = *reinterpret_cast<const bh8*>(&Bw[brow1 + kt + ak1 * 8]);
        }
        __syncthreads();
        const int kq = lane >> 4, lm = lane & 15;
        bh8 af[4], bfr[4];
#pragma unroll
        for (int i = 0; i < 4; ++i) {
            const int rl = wr * 64 + i * 16 + lm;
            af[i] = As8[rl * 4 + (kq ^ ((rl >> 1) & 3))];
            const int cl = wc * 64 + i * 16 + lm;
            bfr[i] = Bs8[cl * 4 + (kq ^ ((cl >> 1) & 3))];
        }
#pragma unroll
        for (int i = 0; i < 4; ++i)
#pragma unroll
            for (int j = 0; j < 4; ++j)
                acc[i][j] = __builtin_amdgcn_mfma_f32_16x16x32_bf16(
                    af[i], bfr[j], acc[i][j], 0, 0, 0);
        __syncthreads();
    }

    const int rq = lane >> 4, lm = lane & 15;
#pragma unroll
    for (int i = 0; i < 4; ++i) {
#pragma unroll
        for (int j = 0; j < 4; ++j) {
            const int rl = wr * 64 + i * 16 + rq * 4 + j;
            if (rl < m) {
                const int g = rs[rl];
                const float s = ss[rl];
#pragma unroll
                for (int nf = 0; nf < 4; ++nf) {
                    const int cl = colBase + wc * 64 + nf * 16 + lm;
                    float* pp = &P[(size_t)g * DH + cl];
                    const float o = s * (acc[i][nf][j] + be[(size_t)e * DH + cl]);
                    if (SLOT == 0) {
                        *pp = o;
                    } else {
                        const float v = fmaxf(*pp + o, 0.f);
                        if (BFA) Hbf[(size_t)g * DH + cl] = f2bf(v);
                        else     *pp = v;
                    }
                }
            }
        }
    }
}

// ------------------------------------------------------------------
// bf16-MFMA final GEMM: out = H@Wf + bf (+ scalar). BFA=1 reads bf16 H.
// ------------------------------------------------------------------
template<int BFA>
__global__ __launch_bounds__(256)
void gemm_final_bf16(const float* __restrict__ Hf, const short* __restrict__ Habf,
                     const short* __restrict__ WT,
                     const float* __restrict__ bias, float* __restrict__ C,
                     const float* gsum, float* scalar_out)
{
    __shared__ bh8 As8[512];
    __shared__ bh8 Bs8[512];
    const int tid = threadIdx.x;
    const int rowBase = blockIdx.x * 128;

    if (blockIdx.x == 0 && tid == 0)
        *scalar_out = (gsum[0] + gsum[1]) * (0.5f / (float)NT);

    const int lane = tid & 63, wave = tid >> 6;
    const int wr = wave >> 1, wc = wave & 1;

    fx4 acc[4][4];
    const fx4 z = {0.f, 0.f, 0.f, 0.f};
#pragma unroll
    for (int i = 0; i < 4; ++i)
#pragma unroll
        for (int j = 0; j < 4; ++j) acc[i][j] = z;

    const int d0 = tid, d1 = tid + 256;
    const int ar0 = d0 >> 2, ak0 = d0 & 3;
    const int ar1 = d1 >> 2, ak1 = d1 & 3;
    const int g0 = ar0 * 4 + (ak0 ^ ((ar0 >> 1) & 3));
    const int g1 = ar1 * 4 + (ak1 ^ ((ar1 >> 1) & 3));
    const size_t arow0 = (size_t)(rowBase + ar0) * DH, arow1 = (size_t)(rowBase + ar1) * DH;
    const size_t brow0 = (size_t)ar0 * DH, brow1 = (size_t)ar1 * DH;

    for (int kt = 0; kt < DH; kt += 32) {
        if (BFA) {
            As8[g0] = *reinterpret_cast<const bh8*>(&Habf[arow0 + kt + ak0 * 8]);
            As8[g1] = *reinterpret_cast<const bh8*>(&Habf[arow1 + kt + ak1 * 8]);
        } else {
            const float* s0 = &Hf[arow0 + kt + ak0 * 8];
            const float4 f0 = *reinterpret_cast<const float4*>(s0);
            const float4 f1 = *reinterpret_cast<const float4*>(s0 + 4);
            bh8 v;
            v[0]=f2bf(f0.x); v[1]=f2bf(f0.y); v[2]=f2bf(f0.z); v[3]=f2bf(f0.w);
            v[4]=f2bf(f1.x); v[5]=f2bf(f1.y); v[6]=f2bf(f1.z); v[7]=f2bf(f1.w);
            As8[g0] = v;
            const float* s1 = &Hf[arow1 + kt + ak1 * 8];
            const float4 f2 = *reinterpret_cast<const float4*>(s1);
            const float4 f3 = *reinterpret_cast<const float4*>(s1 + 4);
            bh8 w;
            w[0]=f2bf(f2.x); w[1]=f2bf(f2.y); w[2]=f2bf(f2.z); w[3]=f2bf(f2.w);
            w[4]=f2bf(f3.x); w[5]=f2bf(f3.y); w[6]=f2bf(f3.z); w[7]=f2bf(f3.w);
            As8[g1] = w;
        }
        {
            Bs8[g0] = *reinterpret_cast<const bh8*>(&WT[brow0 + kt + ak0 * 8]);
            Bs8[g1] = *reinterpret_cast<const bh8*>(&WT[brow1 + kt + ak1 * 8]);
        }
        __syncthreads();
        const int kq = lane >> 4, lm = lane & 15;
        bh8 af[4], bfr[4];
#pragma unroll
        for (int i = 0; i < 4; ++i) {
            const int rl = wr * 64 + i * 16 + lm;
            af[i] = As8[rl * 4 + (kq ^ ((rl >> 1) & 3))];
            const int cl = wc * 64 + i * 16 + lm;
            bfr[i] = Bs8[cl * 4 + (kq ^ ((cl >> 1) & 3))];
        }
#pragma unroll
        for (int i = 0; i < 4; ++i)
#pragma unroll
            for (int j = 0; j < 4; ++j)
                acc[i][j] = __builtin_amdgcn_mfma_f32_16x16x32_bf16(
                    af[i], bfr[j], acc[i][j], 0, 0, 0);
        __syncthreads();
    }

    const int rq = lane >> 4, lm = lane & 15;
#pragma unroll
    for (int i = 0; i < 4; ++i) {
#pragma unroll
        for (int j = 0; j < 4; ++j) {
            const int rl = rowBase + wr * 64 + i * 16 + rq * 4 + j;
#pragma unroll
            for (int nf = 0; nf < 4; ++nf) {
                const int cl = wc * 64 + nf * 16 + lm;
                C[(size_t)rl * DO + cl] = acc[i][nf][j] + bias[cl];
            }
        }
    }
}

// ------------------------------------------------------------------
extern "C" void kernel_launch(void* const* d_in, const int* in_sizes, int n_in,
                              void* d_out, int out_size, void* d_ws, size_t ws_size,
                              hipStream_t stream)
{
    const float* x   = (const float*)d_in[0];
    const float* W0  = (const float*)d_in[1];
    const float* b0  = (const float*)d_in[2];
    const float* Wg1 = (const float*)d_in[3];
    const float* bg1 = (const float*)d_in[4];
    const float* We1 = (const float*)d_in[5];
    const float* be1 = (const float*)d_in[6];
    const float* Wg2 = (const float*)d_in[7];
    const float* bg2 = (const float*)d_in[8];
    const float* We2 = (const float*)d_in[9];
    const float* be2 = (const float*)d_in[10];
    const float* Wf  = (const float*)d_in[11];
    const float* bf  = (const float*)d_in[12];
    float* out = (float*)d_out;

    char* w = (char*)d_ws;
    float* H    = (float*)w; w += (size_t)NT * DH * 4;
    float* Y    = (float*)w; w += (size_t)NT * DH * 4;
    RInfo* info = (RInfo*)w; w += (size_t)NT * sizeof(RInfo);
    int* l0   = (int*)w; w += (size_t)NT * 4;
    int* l1   = (int*)w; w += (size_t)NT * 4;
    int* bc0  = (int*)w; w += NE * 256 * 4;
    int* bc1  = (int*)w; w += NE * 256 * 4;
    int* bo0  = (int*)w; w += NE * 256 * 4;
    int* bo1  = (int*)w; w += NE * 256 * 4;
    int* cnt0 = (int*)w; w += 64;
    int* cnt1 = (int*)w; w += 64;
    int* off0 = (int*)w; w += 64;
    int* off1 = (int*)w; w += 64;
    float* gsum = (float*)w; w += 64;
    short* WeT = (short*)w; w += (size_t)NE * DH * DH * 2;   // 2 MB
    short* WfT = (short*)w; w += (size_t)DH * DO * 2;        // 64 KB
    short* Ybf = (short*)w; w += (size_t)NT * DH * 2;        // 33.5 MB (optional)
    const bool roomy = (size_t)(w - (char*)d_ws) <= ws_size;
    short* Hbf = (short*)Y;   // aliases Y: Y fp32 dead after gate2 in roomy path

    zero_meta<<<dim3(16), dim3(256), 0, stream>>>(bc0, bc1, gsum);
    transp_bf16<<<dim3(8, 8, 16), dim3(256), 0, stream>>>(We2, WeT, DH, DH);
    transp_bf16<<<dim3(8, 4, 1),  dim3(256), 0, stream>>>(Wf,  WfT, DH, DO);

    // layer 0 (fp32, gate-critical): H = relu(x @ W0 + b0)
    gemm_dense<true><<<dim3(NT / 128, 2), dim3(256), 0, stream>>>(x, W0, b0, H, DH);

    // MoE layer 1 (fp32, gate-critical): read H, build Y (+Ybf)
    gate_kernel<<<dim3(NT / 16), dim3(256), 0, stream>>>(H, Wg1, bg1, info, &gsum[0], bc0, bc1);
    scan2_kernel<<<dim3(1), dim3(64), 0, stream>>>(bc0, bc1, cnt0, cnt1, off0, off1, bo0, bo1);
    scatter2_kernel<<<dim3(NT / 256), dim3(256), 0, stream>>>(info, bo0, bo1, l0, l1);
    gemm_expert<0><<<dim3(MAXCH, 2), dim3(256), 0, stream>>>(H, We1, be1, info, l0, cnt0, off0, Y, nullptr);
    gemm_expert<1><<<dim3(MAXCH, 2), dim3(256), 0, stream>>>(H, We1, be1, info, l1, cnt1, off1, Y,
                                                             roomy ? Ybf : nullptr);

    // MoE layer 2 (bf16 MFMA, output path): read Y/Ybf, build H/Hbf
    gate_kernel<<<dim3(NT / 16), dim3(256), 0, stream>>>(Y, Wg2, bg2, info, &gsum[1], bc0, bc1);
    scan2_kernel<<<dim3(1), dim3(64), 0, stream>>>(bc0, bc1, cnt0, cnt1, off0, off1, bo0, bo1);
    scatter2_kernel<<<dim3(NT / 256), dim3(256), 0, stream>>>(info, bo0, bo1, l0, l1);
    if (roomy) {
        gemm_expert_bf16<0,1><<<dim3(MAXCH, 2), dim3(256), 0, stream>>>(Y, Ybf, WeT, be2, info, l0, cnt0, off0, H, nullptr);
        gemm_expert_bf16<1,1><<<dim3(MAXCH, 2), dim3(256), 0, stream>>>(Y, Ybf, WeT, be2, info, l1, cnt1, off1, H, Hbf);
        gemm_final_bf16<1><<<dim3(NT / 128), dim3(256), 0, stream>>>(H, Hbf, WfT, bf, out, gsum, out + (size_t)NT * DO);
    } else {
        gemm_expert_bf16<0,0><<<dim3(MAXCH, 2), dim3(256), 0, stream>>>(Y, nullptr, WeT, be2, info, l0, cnt0, off0, H, nullptr);
        gemm_expert_bf16<1,0><<<dim3(MAXCH, 2), dim3(256), 0, stream>>>(Y, nullptr, WeT, be2, info, l1, cnt1, off1, H, nullptr);
        gemm_final_bf16<0><<<dim3(NT / 128), dim3(256), 0, stream>>>(H, nullptr, WfT, bf, out, gsum, out + (size_t)NT * DO);
    }
}

// Round 12
// 603.538 us; speedup vs baseline: 1.3108x; 1.0122x over previous
//
#include <hip/hip_runtime.h>
#include <math.h>

#define NT 65536
#define DH 256
#define DO 128
#define NE 16
#define MAXCH 528        // NT/128 + NE
#define CPX 66           // MAXCH / 8 XCDs

struct RInfo { int e1, e2; float s1, s2; };

typedef __attribute__((ext_vector_type(8))) short bh8;   // 8 bf16 (4 VGPR)
typedef __attribute__((ext_vector_type(4))) float fx4;   // MFMA acc

static __device__ __forceinline__ short f2bf(float f) {
    union { float f; unsigned u; } v; v.f = f;
    return (short)((v.u + 0x7FFFu + ((v.u >> 16) & 1u)) >> 16);   // RNE
}

// ------------------------------------------------------------------
// fp32 dense GEMM (gate-critical layer 0) — EXACT R4 body (bit-exact).
// ------------------------------------------------------------------
template<bool RELU>
__global__ __launch_bounds__(256)
void gemm_dense(const float* __restrict__ A, const float* __restrict__ B,
                const float* __restrict__ bias, float* __restrict__ C,
                int ncols)
{
    __shared__ float As[128][36];
    __shared__ float Bs[32][132];
    const int tid = threadIdx.x;
    const int tx = tid & 15, ty = tid >> 4;
    const int rowBase = blockIdx.x * 128;
    const int colBase = blockIdx.y * 128;

    float acc[8][8];
#pragma unroll
    for (int i = 0; i < 8; ++i)
#pragma unroll
        for (int j = 0; j < 8; ++j) acc[i][j] = 0.f;

    for (int kt = 0; kt < DH; kt += 32) {
        {
            const int r = tid >> 3, k4 = (tid & 7) << 2;
#pragma unroll
            for (int it = 0; it < 4; ++it) {
                const float4 v = *reinterpret_cast<const float4*>(
                    &A[(size_t)(rowBase + r + 32 * it) * DH + kt + k4]);
                *reinterpret_cast<float4*>(&As[r + 32 * it][k4]) = v;
            }
        }
        {
            const int kr = tid >> 5, c4 = (tid & 31) << 2;
#pragma unroll
            for (int it = 0; it < 4; ++it) {
                const float4 v = *reinterpret_cast<const float4*>(
                    &B[(size_t)(kt + kr + 8 * it) * ncols + colBase + c4]);
                *reinterpret_cast<float4*>(&Bs[kr + 8 * it][c4]) = v;
            }
        }
        __syncthreads();
#pragma unroll
        for (int k4 = 0; k4 < 32; k4 += 4) {
            alignas(16) float ar[8][4];
#pragma unroll
            for (int i = 0; i < 8; ++i)
                *reinterpret_cast<float4*>(ar[i]) =
                    *reinterpret_cast<const float4*>(&As[ty * 8 + i][k4]);
#pragma unroll
            for (int kk = 0; kk < 4; ++kk) {
                alignas(16) float br[8];
                *reinterpret_cast<float4*>(&br[0]) =
                    *reinterpret_cast<const float4*>(&Bs[k4 + kk][tx * 8]);
                *reinterpret_cast<float4*>(&br[4]) =
                    *reinterpret_cast<const float4*>(&Bs[k4 + kk][tx * 8 + 4]);
#pragma unroll
                for (int i = 0; i < 8; ++i) {
                    const float a = ar[i][kk];
#pragma unroll
                    for (int j = 0; j < 8; ++j)
                        acc[i][j] = fmaf(a, br[j], acc[i][j]);
                }
            }
        }
        __syncthreads();
    }
    alignas(16) float bb[8];
#pragma unroll
    for (int j = 0; j < 8; ++j) bb[j] = bias[colBase + tx * 8 + j];
#pragma unroll
    for (int i = 0; i < 8; ++i) {
        const size_t row = rowBase + ty * 8 + i;
        alignas(16) float o[8];
#pragma unroll
        for (int j = 0; j < 8; ++j) {
            float v = acc[i][j] + bb[j];
            if (RELU) v = fmaxf(v, 0.f);
            o[j] = v;
        }
        float* p = &C[row * (size_t)ncols + colBase + tx * 8];
        *reinterpret_cast<float4*>(p)     = *reinterpret_cast<float4*>(&o[0]);
        *reinterpret_cast<float4*>(p + 4) = *reinterpret_cast<float4*>(&o[4]);
    }
}

// ------------------------------------------------------------------
// Gate v2 — logit FMA chain bit-identical (serial k-ascending fmaf).
// Wg staged TRANSPOSED (wgsT[e][k]) so the inner loop reads BOTH
// operands as float4: 2 ds_read_b128 per 4 FMA (was 8 ds_read_b32).
// Fused per-block expert histogram (replaces count_kernel).
// ------------------------------------------------------------------
__global__ __launch_bounds__(256)
void gate_kernel(const float* __restrict__ H, const float* __restrict__ Wg,
                 const float* __restrict__ bg, RInfo* __restrict__ info,
                 float* gsum, int* __restrict__ bc0, int* __restrict__ bc1)
{
    __shared__ float wgsT[16][260];   // [e][k], transposed
    __shared__ float hs[16][260];     // [r][k]
    __shared__ float lg[16][17];
    __shared__ float sbg[16];
    __shared__ float sds[16];
    __shared__ int hh0[NE], hh1[NE];
    const int tid = threadIdx.x;
    const int rowBase = blockIdx.x * 16;

    // stage Wg[k][e] -> wgsT[e][k]; coalesced float4 global reads
#pragma unroll
    for (int it = 0; it < 4; ++it) {
        const int flat = (tid + 256 * it) * 4;      // 0..16380
        const int k = flat >> 4, e4 = flat & 15;
        const float4 v = *reinterpret_cast<const float4*>(&Wg[flat]);
        wgsT[e4 + 0][k] = v.x;
        wgsT[e4 + 1][k] = v.y;
        wgsT[e4 + 2][k] = v.z;
        wgsT[e4 + 3][k] = v.w;
    }
    if (tid < 16) { sbg[tid] = bg[tid]; hh0[tid] = 0; hh1[tid] = 0; }
#pragma unroll
    for (int it = 0; it < 4; ++it) {
        const int flat = (tid + 256 * it) * 4;
        const int r = flat >> 8, k = flat & 255;
        *reinterpret_cast<float4*>(&hs[r][k]) =
            *reinterpret_cast<const float4*>(&H[(size_t)(rowBase + r) * DH + k]);
    }
    __syncthreads();
    {
        const int r = tid >> 4, e = tid & 15;
        float acc = 0.f;
#pragma unroll 8
        for (int k = 0; k < 256; k += 4) {
            const float4 hv = *reinterpret_cast<const float4*>(&hs[r][k]);
            const float4 wv = *reinterpret_cast<const float4*>(&wgsT[e][k]);
            acc = fmaf(hv.x, wv.x, acc);
            acc = fmaf(hv.y, wv.y, acc);
            acc = fmaf(hv.z, wv.z, acc);
            acc = fmaf(hv.w, wv.w, acc);
        }
        lg[r][e] = acc + sbg[e];
    }
    __syncthreads();
    if (tid < 16) {
        const int row = rowBase + tid;
        float l[16];
#pragma unroll
        for (int i = 0; i < 16; ++i) l[i] = lg[tid][i];
        int i1 = 0; float v1 = l[0];
#pragma unroll
        for (int i = 1; i < 16; ++i) if (l[i] > v1) { v1 = l[i]; i1 = i; }
        int i2 = -1; float v2 = -INFINITY;
#pragma unroll
        for (int i = 0; i < 16; ++i) if (i != i1 && l[i] > v2) { v2 = l[i]; i2 = i; }
        const float t = expf(v2 - v1);
        const float s1 = 1.f / (1.f + t);
        const float s2 = t / (1.f + t);
        float p[16]; float S = 0.f;
#pragma unroll
        for (int i = 0; i < 16; ++i) { p[i] = expf(l[i] - v1); S += p[i]; }
        const float inv = 1.f / S;
        float sq = 0.f;
#pragma unroll
        for (int i = 0; i < 16; ++i) { const float q = p[i] * inv; sq = fmaf(q, q, sq); }
        const float var = (sq - 1.0f / 16.0f) * (1.0f / 15.0f);
        const float sd = sqrtf(fmaxf(var, 0.f));

        RInfo ri; ri.e1 = i1; ri.e2 = i2; ri.s1 = s1; ri.s2 = s2;
        info[row] = ri;
        sds[tid] = sd;
        atomicAdd(&hh0[i1], 1);
        atomicAdd(&hh1[i2], 1);
    }
    __syncthreads();
    if (tid == 0) {
        float s = 0.f;
#pragma unroll
        for (int i = 0; i < 16; ++i) s += sds[i];
        atomicAdd(gsum, s);
    }
    if (tid < 16) {
        const int b = blockIdx.x >> 4;              // 256-row super-block
        if (hh0[tid]) atomicAdd(&bc0[tid * 256 + b], hh0[tid]);
        if (hh1[tid]) atomicAdd(&bc1[tid * 256 + b], hh1[tid]);
    }
}

__global__ void zero_meta(int* bc0, int* bc1, float* gsum)
{
    const int idx = blockIdx.x * 256 + threadIdx.x;   // grid 16 -> 4096
    bc0[idx] = 0; bc1[idx] = 0;
    if (idx < 2) gsum[idx] = 0.f;
}

// ------------------------------------------------------------------
// scan: totals + per-block offsets; re-zeros bc for the next layer.
// ------------------------------------------------------------------
__global__ void scan2_kernel(int* __restrict__ bc0, int* __restrict__ bc1,
                             int* cnt0, int* cnt1, int* off0, int* off1,
                             int* __restrict__ bo0, int* __restrict__ bo1)
{
    __shared__ int tot0[NE], tot1[NE], base0[NE], base1[NE];
    const int t = threadIdx.x;
    if (t < NE) {
        int s = 0;
        for (int b = 0; b < 256; ++b) s += bc0[t * 256 + b];
        tot0[t] = s; cnt0[t] = s;
    } else if (t < 2 * NE) {
        const int e = t - NE;
        int s = 0;
        for (int b = 0; b < 256; ++b) s += bc1[e * 256 + b];
        tot1[e] = s; cnt1[e] = s;
    }
    __syncthreads();
    if (t == 0) { int a = 0; for (int e = 0; e < NE; ++e) { base0[e] = a; off0[e] = a; a += tot0[e]; } }
    if (t == 1) { int a = 0; for (int e = 0; e < NE; ++e) { base1[e] = a; off1[e] = a; a += tot1[e]; } }
    __syncthreads();
    if (t < NE) {
        int run = base0[t];
        for (int b = 0; b < 256; ++b) { bo0[t * 256 + b] = run; run += bc0[t * 256 + b]; }
    } else if (t < 2 * NE) {
        const int e = t - NE;
        int run = base1[e];
        for (int b = 0; b < 256; ++b) { bo1[e * 256 + b] = run; run += bc1[e * 256 + b]; }
    }
    __syncthreads();
    for (int i = t; i < NE * 256; i += 64) { bc0[i] = 0; bc1[i] = 0; }
}

__global__ __launch_bounds__(256)
void scatter2_kernel(const RInfo* __restrict__ info, const int* __restrict__ bo0,
                     const int* __restrict__ bo1, int* __restrict__ l0,
                     int* __restrict__ l1)
{
    __shared__ int h0[NE], h1[NE];
    const int tid = threadIdx.x, b = blockIdx.x;
    if (tid < NE) { h0[tid] = 0; h1[tid] = 0; }
    __syncthreads();
    const int r = b * 256 + tid;
    const RInfo ri = info[r];
    const int p0 = atomicAdd(&h0[ri.e1], 1);
    const int p1 = atomicAdd(&h1[ri.e2], 1);
    l0[bo0[ri.e1 * 256 + b] + p0] = r;
    l1[bo1[ri.e2 * 256 + b] + p1] = r;
}

// ------------------------------------------------------------------
// fp32 grouped expert GEMM (MoE layer 1, gate-critical) — EXACT R4 body
// (bit-exact FMA chains). XCD chunk swizzle (speed-only), Ybf emit.
// ------------------------------------------------------------------
template<int SLOT>
__global__ __launch_bounds__(256)
void gemm_expert(const float* __restrict__ Hin, const float* __restrict__ We,
                 const float* __restrict__ be, const RInfo* __restrict__ info,
                 const int* __restrict__ list, const int* __restrict__ cnts,
                 const int* __restrict__ offs, float* __restrict__ P,
                 short* __restrict__ Ybf)
{
    __shared__ float As[128][36];
    __shared__ float Bs[32][132];
    __shared__ int   rs[128];
    __shared__ float ss[128];

    int c = (blockIdx.x & 7) * CPX + (blockIdx.x >> 3);   // XCD-contiguous chunks
    int e;
    int cnt = 0;
    for (e = 0; e < NE; ++e) {
        cnt = cnts[e];
        const int nch = (cnt + 127) >> 7;
        if (c < nch) break;
        c -= nch;
    }
    if (e >= NE) return;
    const int m = min(128, cnt - c * 128);
    const int base = offs[e] + c * 128;
    const int tid = threadIdx.x;
    const int tx = tid & 15, ty = tid >> 4;
    const int colBase = blockIdx.y * 128;

    if (tid < 128) {
        const int g = list[base + min(tid, m - 1)];
        rs[tid] = g;
        const RInfo ri = info[g];
        ss[tid] = (SLOT == 0) ? ri.s1 : ri.s2;
    }
    __syncthreads();

    const float* B = We + (size_t)e * DH * DH;

    float acc[8][8];
#pragma unroll
    for (int i = 0; i < 8; ++i)
#pragma unroll
        for (int j = 0; j < 8; ++j) acc[i][j] = 0.f;

    for (int kt = 0; kt < DH; kt += 32) {
        {
            const int r = tid >> 3, k4 = (tid & 7) << 2;
#pragma unroll
            for (int it = 0; it < 4; ++it) {
                const int g = rs[r + 32 * it];
                const float4 v = *reinterpret_cast<const float4*>(
                    &Hin[(size_t)g * DH + kt + k4]);
                *reinterpret_cast<float4*>(&As[r + 32 * it][k4]) = v;
            }
        }
        {
            const int kr = tid >> 5, c4 = (tid & 31) << 2;
#pragma unroll
            for (int it = 0; it < 4; ++it) {
                const float4 v = *reinterpret_cast<const float4*>(
                    &B[(size_t)(kt + kr + 8 * it) * DH + colBase + c4]);
                *reinterpret_cast<float4*>(&Bs[kr + 8 * it][c4]) = v;
            }
        }
        __syncthreads();
#pragma unroll
        for (int k4 = 0; k4 < 32; k4 += 4) {
            alignas(16) float ar[8][4];
#pragma unroll
            for (int i = 0; i < 8; ++i)
                *reinterpret_cast<float4*>(ar[i]) =
                    *reinterpret_cast<const float4*>(&As[ty * 8 + i][k4]);
#pragma unroll
            for (int kk = 0; kk < 4; ++kk) {
                alignas(16) float br[8];
                *reinterpret_cast<float4*>(&br[0]) =
                    *reinterpret_cast<const float4*>(&Bs[k4 + kk][tx * 8]);
                *reinterpret_cast<float4*>(&br[4]) =
                    *reinterpret_cast<const float4*>(&Bs[k4 + kk][tx * 8 + 4]);
#pragma unroll
                for (int i = 0; i < 8; ++i) {
                    const float a = ar[i][kk];
#pragma unroll
                    for (int j = 0; j < 8; ++j)
                        acc[i][j] = fmaf(a, br[j], acc[i][j]);
                }
            }
        }
        __syncthreads();
    }

    alignas(16) float bb[8];
#pragma unroll
    for (int j = 0; j < 8; ++j) bb[j] = be[(size_t)e * DH + colBase + tx * 8 + j];
#pragma unroll
    for (int i = 0; i < 8; ++i) {
        const int rl = ty * 8 + i;
        if (rl < m) {
            const int g = rs[rl];
            const float s = ss[rl];
            alignas(16) float o[8];
#pragma unroll
            for (int j = 0; j < 8; ++j) o[j] = s * (acc[i][j] + bb[j]);
            float* pp = &P[(size_t)g * DH + colBase + tx * 8];
            if (SLOT == 0) {
                *reinterpret_cast<float4*>(pp)     = *reinterpret_cast<float4*>(&o[0]);
                *reinterpret_cast<float4*>(pp + 4) = *reinterpret_cast<float4*>(&o[4]);
            } else {
                const float4 p0 = *reinterpret_cast<const float4*>(pp);
                const float4 p1 = *reinterpret_cast<const float4*>(pp + 4);
                alignas(16) float h[8];
                h[0] = fmaxf(o[0] + p0.x, 0.f); h[1] = fmaxf(o[1] + p0.y, 0.f);
                h[2] = fmaxf(o[2] + p0.z, 0.f); h[3] = fmaxf(o[3] + p0.w, 0.f);
                h[4] = fmaxf(o[4] + p1.x, 0.f); h[5] = fmaxf(o[5] + p1.y, 0.f);
                h[6] = fmaxf(o[6] + p1.z, 0.f); h[7] = fmaxf(o[7] + p1.w, 0.f);
                *reinterpret_cast<float4*>(pp)     = *reinterpret_cast<float4*>(&h[0]);
                *reinterpret_cast<float4*>(pp + 4) = *reinterpret_cast<float4*>(&h[4]);
                if (Ybf) {
                    bh8 yb;
#pragma unroll
                    for (int j = 0; j < 8; ++j) yb[j] = f2bf(h[j]);
                    *reinterpret_cast<bh8*>(&Ybf[(size_t)g * DH + colBase + tx * 8]) = yb;
                }
            }
        }
    }
}

// ------------------------------------------------------------------
// Weight transpose+convert: W[K][N] fp32 -> WT[N][K] bf16 (per z-slab)
// ------------------------------------------------------------------
__global__ __launch_bounds__(256)
void transp_bf16(const float* __restrict__ W, short* __restrict__ WT,
                 int K, int N)
{
    __shared__ float t[32][33];
    const int k0 = blockIdx.x * 32, n0 = blockIdx.y * 32;
    const size_t off = (size_t)blockIdx.z * K * N;
    const int c = threadIdx.x & 31, r8 = threadIdx.x >> 5;
#pragma unroll
    for (int it = 0; it < 4; ++it) {
        const int r = r8 + it * 8;
        t[r][c] = W[off + (size_t)(k0 + r) * N + n0 + c];
    }
    __syncthreads();
#pragma unroll
    for (int it = 0; it < 4; ++it) {
        const int r = r8 + it * 8;
        WT[off + (size_t)(n0 + r) * K + k0 + c] = f2bf(t[c][r]);
    }
}

// ------------------------------------------------------------------
// bf16-MFMA grouped expert GEMM (MoE layer 2) — R4 numerics + XCD swizzle.
// BFA=1: A from pre-converted bf16 (identical bits); SLOT1+BFA writes Hbf.
// ------------------------------------------------------------------
template<int SLOT, int BFA>
__global__ __launch_bounds__(256)
void gemm_expert_bf16(const float* __restrict__ Yf, const short* __restrict__ Abf,
                      const short* __restrict__ WeT,
                      const float* __restrict__ be, const RInfo* __restrict__ info,
                      const int* __restrict__ list, const int* __restrict__ cnts,
                      const int* __restrict__ offs, float* __restrict__ P,
                      short* __restrict__ Hbf)
{
    __shared__ bh8 As8[512];
    __shared__ bh8 Bs8[512];
    __shared__ int   rs[128];
    __shared__ float ss[128];

    int c = (blockIdx.x & 7) * CPX + (blockIdx.x >> 3);
    int e;
    int cnt = 0;
    for (e = 0; e < NE; ++e) {
        cnt = cnts[e];
        const int nch = (cnt + 127) >> 7;
        if (c < nch) break;
        c -= nch;
    }
    if (e >= NE) return;
    const int m = min(128, cnt - c * 128);
    const int base = offs[e] + c * 128;
    const int tid = threadIdx.x;

    if (tid < 128) {
        const int g = list[base + min(tid, m - 1)];
        rs[tid] = g;
        const RInfo ri = info[g];
        ss[tid] = (SLOT == 0) ? ri.s1 : ri.s2;
    }
    __syncthreads();

    const int colBase = blockIdx.y * 128;
    const int lane = tid & 63, wave = tid >> 6;
    const int wr = wave >> 1, wc = wave & 1;
    const short* Bw = WeT + (size_t)e * DH * DH;

    fx4 acc[4][4];
    const fx4 z = {0.f, 0.f, 0.f, 0.f};
#pragma unroll
    for (int i = 0; i < 4; ++i)
#pragma unroll
        for (int j = 0; j < 4; ++j) acc[i][j] = z;

    const int d0 = tid, d1 = tid + 256;
    const int ar0 = d0 >> 2, ak0 = d0 & 3;
    const int ar1 = d1 >> 2, ak1 = d1 & 3;
    const int g0 = ar0 * 4 + (ak0 ^ ((ar0 >> 1) & 3));
    const int g1 = ar1 * 4 + (ak1 ^ ((ar1 >> 1) & 3));
    const size_t arow0 = (size_t)rs[ar0] * DH, arow1 = (size_t)rs[ar1] * DH;
    const size_t brow0 = (size_t)(colBase + ar0) * DH, brow1 = (size_t)(colBase + ar1) * DH;

    for (int kt = 0; kt < DH; kt += 32) {
        if (BFA) {
            As8[g0] = *reinterpret_cast<const bh8*>(&Abf[arow0 + kt + ak0 * 8]);
            As8[g1] = *reinterpret_cast<const bh8*>(&Abf[arow1 + kt + ak1 * 8]);
        } else {
            const float* s0 = &Yf[arow0 + kt + ak0 * 8];
            const float4 f0 = *reinterpret_cast<const float4*>(s0);
            const float4 f1 = *reinterpret_cast<const float4*>(s0 + 4);
            bh8 v;
            v[0]=f2bf(f0.x); v[1]=f2bf(f0.y); v[2]=f2bf(f0.z); v[3]=f2bf(f0.w);
            v[4]=f2bf(f1.x); v[5]=f2bf(f1.y); v[6]=f2bf(f1.z); v[7]=f2bf(f1.w);
            As8[g0] = v;
            const float* s1 = &Yf[arow1 + kt + ak1 * 8];
            const float4 f2 = *reinterpret_cast<const float4*>(s1);
            const float4 f3 = *reinterpret_cast<const float4*>(s1 + 4);
            bh8 w;
            w[0]=f2bf(f2.x); w[1]=f2bf(f2.y); w[2]=f2bf(f2.z); w[3]=f2bf(f2.w);
            w[4]=f2bf(f3.x); w[5]=f2bf(f3.y); w[6]=f2bf(f3.z); w[7]=f2bf(f3.w);
            As8[g1] = w;
        }
        {
            Bs8[g0] = *reinterpret_cast<const bh8*>(&Bw[brow0 + kt + ak0 * 8]);
            Bs8[g1] = *reinterpret_cast<const bh8*>(&Bw[brow1 + kt + ak1 * 8]);
        }
        __syncthreads();
        const int kq = lane >> 4, lm = lane & 15;
        bh8 af[4], bfr[4];
#pragma unroll
        for (int i = 0; i < 4; ++i) {
            const int rl = wr * 64 + i * 16 + lm;
            af[i] = As8[rl * 4 + (kq ^ ((rl >> 1) & 3))];
            const int cl = wc * 64 + i * 16 + lm;
            bfr[i] = Bs8[cl * 4 + (kq ^ ((cl >> 1) & 3))];
        }
#pragma unroll
        for (int i = 0; i < 4; ++i)
#pragma unroll
            for (int j = 0; j < 4; ++j)
                acc[i][j] = __builtin_amdgcn_mfma_f32_16x16x32_bf16(
                    af[i], bfr[j], acc[i][j], 0, 0, 0);
        __syncthreads();
    }

    const int rq = lane >> 4, lm = lane & 15;
#pragma unroll
    for (int i = 0; i < 4; ++i) {
#pragma unroll
        for (int j = 0; j < 4; ++j) {
            const int rl = wr * 64 + i * 16 + rq * 4 + j;
            if (rl < m) {
                const int g = rs[rl];
                const float s = ss[rl];
#pragma unroll
                for (int nf = 0; nf < 4; ++nf) {
                    const int cl = colBase + wc * 64 + nf * 16 + lm;
                    float* pp = &P[(size_t)g * DH + cl];
                    const float o = s * (acc[i][nf][j] + be[(size_t)e * DH + cl]);
                    if (SLOT == 0) {
                        *pp = o;
                    } else {
                        const float v = fmaxf(*pp + o, 0.f);
                        if (BFA) Hbf[(size_t)g * DH + cl] = f2bf(v);
                        else     *pp = v;
                    }
                }
            }
        }
    }
}

// ------------------------------------------------------------------
// bf16-MFMA final GEMM: out = H@Wf + bf (+ scalar). BFA=1 reads bf16 H.
// ------------------------------------------------------------------
template<int BFA>
__global__ __launch_bounds__(256)
void gemm_final_bf16(const float* __restrict__ Hf, const short* __restrict__ Habf,
                     const short* __restrict__ WT,
                     const float* __restrict__ bias, float* __restrict__ C,
                     const float* gsum, float* scalar_out)
{
    __shared__ bh8 As8[512];
    __shared__ bh8 Bs8[512];
    const int tid = threadIdx.x;
    const int rowBase = blockIdx.x * 128;

    if (blockIdx.x == 0 && tid == 0)
        *scalar_out = (gsum[0] + gsum[1]) * (0.5f / (float)NT);

    const int lane = tid & 63, wave = tid >> 6;
    const int wr = wave >> 1, wc = wave & 1;

    fx4 acc[4][4];
    const fx4 z = {0.f, 0.f, 0.f, 0.f};
#pragma unroll
    for (int i = 0; i < 4; ++i)
#pragma unroll
        for (int j = 0; j < 4; ++j) acc[i][j] = z;

    const int d0 = tid, d1 = tid + 256;
    const int ar0 = d0 >> 2, ak0 = d0 & 3;
    const int ar1 = d1 >> 2, ak1 = d1 & 3;
    const int g0 = ar0 * 4 + (ak0 ^ ((ar0 >> 1) & 3));
    const int g1 = ar1 * 4 + (ak1 ^ ((ar1 >> 1) & 3));
    const size_t arow0 = (size_t)(rowBase + ar0) * DH, arow1 = (size_t)(rowBase + ar1) * DH;
    const size_t brow0 = (size_t)ar0 * DH, brow1 = (size_t)ar1 * DH;

    for (int kt = 0; kt < DH; kt += 32) {
        if (BFA) {
            As8[g0] = *reinterpret_cast<const bh8*>(&Habf[arow0 + kt + ak0 * 8]);
            As8[g1] = *reinterpret_cast<const bh8*>(&Habf[arow1 + kt + ak1 * 8]);
        } else {
            const float* s0 = &Hf[arow0 + kt + ak0 * 8];
            const float4 f0 = *reinterpret_cast<const float4*>(s0);
            const float4 f1 = *reinterpret_cast<const float4*>(s0 + 4);
            bh8 v;
            v[0]=f2bf(f0.x); v[1]=f2bf(f0.y); v[2]=f2bf(f0.z); v[3]=f2bf(f0.w);
            v[4]=f2bf(f1.x); v[5]=f2bf(f1.y); v[6]=f2bf(f1.z); v[7]=f2bf(f1.w);
            As8[g0] = v;
            const float* s1 = &Hf[arow1 + kt + ak1 * 8];
            const float4 f2 = *reinterpret_cast<const float4*>(s1);
            const float4 f3 = *reinterpret_cast<const float4*>(s1 + 4);
            bh8 w;
            w[0]=f2bf(f2.x); w[1]=f2bf(f2.y); w[2]=f2bf(f2.z); w[3]=f2bf(f2.w);
            w[4]=f2bf(f3.x); w[5]=f2bf(f3.y); w[6]=f2bf(f3.z); w[7]=f2bf(f3.w);
            As8[g1] = w;
        }
        {
            Bs8[g0] = *reinterpret_cast<const bh8*>(&WT[brow0 + kt + ak0 * 8]);
            Bs8[g1] = *reinterpret_cast<const bh8*>(&WT[brow1 + kt + ak1 * 8]);
        }
        __syncthreads();
        const int kq = lane >> 4, lm = lane & 15;
        bh8 af[4], bfr[4];
#pragma unroll
        for (int i = 0; i < 4; ++i) {
            const int rl = wr * 64 + i * 16 + lm;
            af[i] = As8[rl * 4 + (kq ^ ((rl >> 1) & 3))];
            const int cl = wc * 64 + i * 16 + lm;
            bfr[i] = Bs8[cl * 4 + (kq ^ ((cl >> 1) & 3))];
        }
#pragma unroll
        for (int i = 0; i < 4; ++i)
#pragma unroll
            for (int j = 0; j < 4; ++j)
                acc[i][j] = __builtin_amdgcn_mfma_f32_16x16x32_bf16(
                    af[i], bfr[j], acc[i][j], 0, 0, 0);
        __syncthreads();
    }

    const int rq = lane >> 4, lm = lane & 15;
#pragma unroll
    for (int i = 0; i < 4; ++i) {
#pragma unroll
        for (int j = 0; j < 4; ++j) {
            const int rl = rowBase + wr * 64 + i * 16 + rq * 4 + j;
#pragma unroll
            for (int nf = 0; nf < 4; ++nf) {
                const int cl = wc * 64 + nf * 16 + lm;
                C[(size_t)rl * DO + cl] = acc[i][nf][j] + bias[cl];
            }
        }
    }
}

// ------------------------------------------------------------------
extern "C" void kernel_launch(void* const* d_in, const int* in_sizes, int n_in,
                              void* d_out, int out_size, void* d_ws, size_t ws_size,
                              hipStream_t stream)
{
    const float* x   = (const float*)d_in[0];
    const float* W0  = (const float*)d_in[1];
    const float* b0  = (const float*)d_in[2];
    const float* Wg1 = (const float*)d_in[3];
    const float* bg1 = (const float*)d_in[4];
    const float* We1 = (const float*)d_in[5];
    const float* be1 = (const float*)d_in[6];
    const float* Wg2 = (const float*)d_in[7];
    const float* bg2 = (const float*)d_in[8];
    const float* We2 = (const float*)d_in[9];
    const float* be2 = (const float*)d_in[10];
    const float* Wf  = (const float*)d_in[11];
    const float* bf  = (const float*)d_in[12];
    float* out = (float*)d_out;

    char* w = (char*)d_ws;
    float* H    = (float*)w; w += (size_t)NT * DH * 4;
    float* Y    = (float*)w; w += (size_t)NT * DH * 4;
    RInfo* info = (RInfo*)w; w += (size_t)NT * sizeof(RInfo);
    int* l0   = (int*)w; w += (size_t)NT * 4;
    int* l1   = (int*)w; w += (size_t)NT * 4;
    int* bc0  = (int*)w; w += NE * 256 * 4;
    int* bc1  = (int*)w; w += NE * 256 * 4;
    int* bo0  = (int*)w; w += NE * 256 * 4;
    int* bo1  = (int*)w; w += NE * 256 * 4;
    int* cnt0 = (int*)w; w += 64;
    int* cnt1 = (int*)w; w += 64;
    int* off0 = (int*)w; w += 64;
    int* off1 = (int*)w; w += 64;
    float* gsum = (float*)w; w += 64;
    short* WeT = (short*)w; w += (size_t)NE * DH * DH * 2;   // 2 MB
    short* WfT = (short*)w; w += (size_t)DH * DO * 2;        // 64 KB
    short* Ybf = (short*)w; w += (size_t)NT * DH * 2;        // 33.5 MB (optional)
    const bool roomy = (size_t)(w - (char*)d_ws) <= ws_size;
    short* Hbf = (short*)Y;   // aliases Y: Y fp32 dead after gate2 in roomy path

    zero_meta<<<dim3(16), dim3(256), 0, stream>>>(bc0, bc1, gsum);
    transp_bf16<<<dim3(8, 8, 16), dim3(256), 0, stream>>>(We2, WeT, DH, DH);
    transp_bf16<<<dim3(8, 4, 1),  dim3(256), 0, stream>>>(Wf,  WfT, DH, DO);

    // layer 0 (fp32, gate-critical): H = relu(x @ W0 + b0)
    gemm_dense<true><<<dim3(NT / 128, 2), dim3(256), 0, stream>>>(x, W0, b0, H, DH);

    // MoE layer 1 (fp32, gate-critical): read H, build Y (+Ybf)
    gate_kernel<<<dim3(NT / 16), dim3(256), 0, stream>>>(H, Wg1, bg1, info, &gsum[0], bc0, bc1);
    scan2_kernel<<<dim3(1), dim3(64), 0, stream>>>(bc0, bc1, cnt0, cnt1, off0, off1, bo0, bo1);
    scatter2_kernel<<<dim3(NT / 256), dim3(256), 0, stream>>>(info, bo0, bo1, l0, l1);
    gemm_expert<0><<<dim3(MAXCH, 2), dim3(256), 0, stream>>>(H, We1, be1, info, l0, cnt0, off0, Y, nullptr);
    gemm_expert<1><<<dim3(MAXCH, 2), dim3(256), 0, stream>>>(H, We1, be1, info, l1, cnt1, off1, Y,
                                                             roomy ? Ybf : nullptr);

    // MoE layer 2 (bf16 MFMA, output path): read Y/Ybf, build H/Hbf
    gate_kernel<<<dim3(NT / 16), dim3(256), 0, stream>>>(Y, Wg2, bg2, info, &gsum[1], bc0, bc1);
    scan2_kernel<<<dim3(1), dim3(64), 0, stream>>>(bc0, bc1, cnt0, cnt1, off0, off1, bo0, bo1);
    scatter2_kernel<<<dim3(NT / 256), dim3(256), 0, stream>>>(info, bo0, bo1, l0, l1);
    if (roomy) {
        gemm_expert_bf16<0,1><<<dim3(MAXCH, 2), dim3(256), 0, stream>>>(Y, Ybf, WeT, be2, info, l0, cnt0, off0, H, nullptr);
        gemm_expert_bf16<1,1><<<dim3(MAXCH, 2), dim3(256), 0, stream>>>(Y, Ybf, WeT, be2, info, l1, cnt1, off1, H, Hbf);
        gemm_final_bf16<1><<<dim3(NT / 128), dim3(256), 0, stream>>>(H, Hbf, WfT, bf, out, gsum, out + (size_t)NT * DO);
    } else {
        gemm_expert_bf16<0,0><<<dim3(MAXCH, 2), dim3(256), 0, stream>>>(Y, nullptr, WeT, be2, info, l0, cnt0, off0, H, nullptr);
        gemm_expert_bf16<1,0><<<dim3(MAXCH, 2), dim3(256), 0, stream>>>(Y, nullptr, WeT, be2, info, l1, cnt1, off1, H, nullptr);
        gemm_final_bf16<0><<<dim3(NT / 128), dim3(256), 0, stream>>>(H, nullptr, WfT, bf, out, gsum, out + (size_t)NT * DO);
    }
}

// Round 13
// 557.417 us; speedup vs baseline: 1.4192x; 1.0827x over previous
//
#include <hip/hip_runtime.h>
#include <math.h>

#define NT 65536
#define DH 256
#define DO 128
#define NE 16
#define MAXCH 528        // NT/128 + NE
#define CPX 66           // MAXCH / 8 XCDs

struct RInfo { int e1, e2; float s1, s2; };

typedef __attribute__((ext_vector_type(8))) short bh8;   // 8 bf16 (4 VGPR)
typedef __attribute__((ext_vector_type(4))) float fx4;   // MFMA acc

static __device__ __forceinline__ short f2bf(float f) {
    union { float f; unsigned u; } v; v.f = f;
    return (short)((v.u + 0x7FFFu + ((v.u >> 16) & 1u)) >> 16);   // RNE
}

// ------------------------------------------------------------------
// fp32 dense GEMM (gate-critical layer 0) — EXACT R4 body (bit-exact).
// ------------------------------------------------------------------
template<bool RELU>
__global__ __launch_bounds__(256)
void gemm_dense(const float* __restrict__ A, const float* __restrict__ B,
                const float* __restrict__ bias, float* __restrict__ C,
                int ncols)
{
    __shared__ float As[128][36];
    __shared__ float Bs[32][132];
    const int tid = threadIdx.x;
    const int tx = tid & 15, ty = tid >> 4;
    const int rowBase = blockIdx.x * 128;
    const int colBase = blockIdx.y * 128;

    float acc[8][8];
#pragma unroll
    for (int i = 0; i < 8; ++i)
#pragma unroll
        for (int j = 0; j < 8; ++j) acc[i][j] = 0.f;

    for (int kt = 0; kt < DH; kt += 32) {
        {
            const int r = tid >> 3, k4 = (tid & 7) << 2;
#pragma unroll
            for (int it = 0; it < 4; ++it) {
                const float4 v = *reinterpret_cast<const float4*>(
                    &A[(size_t)(rowBase + r + 32 * it) * DH + kt + k4]);
                *reinterpret_cast<float4*>(&As[r + 32 * it][k4]) = v;
            }
        }
        {
            const int kr = tid >> 5, c4 = (tid & 31) << 2;
#pragma unroll
            for (int it = 0; it < 4; ++it) {
                const float4 v = *reinterpret_cast<const float4*>(
                    &B[(size_t)(kt + kr + 8 * it) * ncols + colBase + c4]);
                *reinterpret_cast<float4*>(&Bs[kr + 8 * it][c4]) = v;
            }
        }
        __syncthreads();
#pragma unroll
        for (int k4 = 0; k4 < 32; k4 += 4) {
            alignas(16) float ar[8][4];
#pragma unroll
            for (int i = 0; i < 8; ++i)
                *reinterpret_cast<float4*>(ar[i]) =
                    *reinterpret_cast<const float4*>(&As[ty * 8 + i][k4]);
#pragma unroll
            for (int kk = 0; kk < 4; ++kk) {
                alignas(16) float br[8];
                *reinterpret_cast<float4*>(&br[0]) =
                    *reinterpret_cast<const float4*>(&Bs[k4 + kk][tx * 8]);
                *reinterpret_cast<float4*>(&br[4]) =
                    *reinterpret_cast<const float4*>(&Bs[k4 + kk][tx * 8 + 4]);
#pragma unroll
                for (int i = 0; i < 8; ++i) {
                    const float a = ar[i][kk];
#pragma unroll
                    for (int j = 0; j < 8; ++j)
                        acc[i][j] = fmaf(a, br[j], acc[i][j]);
                }
            }
        }
        __syncthreads();
    }
    alignas(16) float bb[8];
#pragma unroll
    for (int j = 0; j < 8; ++j) bb[j] = bias[colBase + tx * 8 + j];
#pragma unroll
    for (int i = 0; i < 8; ++i) {
        const size_t row = rowBase + ty * 8 + i;
        alignas(16) float o[8];
#pragma unroll
        for (int j = 0; j < 8; ++j) {
            float v = acc[i][j] + bb[j];
            if (RELU) v = fmaxf(v, 0.f);
            o[j] = v;
        }
        float* p = &C[row * (size_t)ncols + colBase + tx * 8];
        *reinterpret_cast<float4*>(p)     = *reinterpret_cast<float4*>(&o[0]);
        *reinterpret_cast<float4*>(p + 4) = *reinterpret_cast<float4*>(&o[4]);
    }
}

// ------------------------------------------------------------------
// Gate v3 — 32 rows/block (halves Wg staging + block count). Per-row
// logit FMA chain bit-identical to R12 (float4 over wgsT). Fused histogram.
// ------------------------------------------------------------------
__global__ __launch_bounds__(256)
void gate_kernel(const float* __restrict__ H, const float* __restrict__ Wg,
                 const float* __restrict__ bg, RInfo* __restrict__ info,
                 float* gsum, int* __restrict__ bc0, int* __restrict__ bc1)
{
    __shared__ float wgsT[16][260];   // [e][k], transposed
    __shared__ float hs[32][260];     // [r][k]
    __shared__ float lg[32][17];
    __shared__ float sbg[16];
    __shared__ float sds[32];
    __shared__ int hh0[NE], hh1[NE];
    const int tid = threadIdx.x;
    const int rowBase = blockIdx.x * 32;

#pragma unroll
    for (int it = 0; it < 4; ++it) {
        const int flat = (tid + 256 * it) * 4;      // 0..16380
        const int k = flat >> 4, e4 = flat & 15;
        const float4 v = *reinterpret_cast<const float4*>(&Wg[flat]);
        wgsT[e4 + 0][k] = v.x;
        wgsT[e4 + 1][k] = v.y;
        wgsT[e4 + 2][k] = v.z;
        wgsT[e4 + 3][k] = v.w;
    }
    if (tid < 16) { sbg[tid] = bg[tid]; hh0[tid] = 0; hh1[tid] = 0; }
#pragma unroll
    for (int it = 0; it < 8; ++it) {
        const int flat = (tid + 256 * it) * 4;      // 0..32764
        const int r = flat >> 8, k = flat & 255;
        *reinterpret_cast<float4*>(&hs[r][k]) =
            *reinterpret_cast<const float4*>(&H[(size_t)(rowBase + r) * DH + k]);
    }
    __syncthreads();
#pragma unroll
    for (int rr = 0; rr < 2; ++rr) {
        const int r = (tid >> 4) + 16 * rr, e = tid & 15;
        float acc = 0.f;
#pragma unroll 8
        for (int k = 0; k < 256; k += 4) {
            const float4 hv = *reinterpret_cast<const float4*>(&hs[r][k]);
            const float4 wv = *reinterpret_cast<const float4*>(&wgsT[e][k]);
            acc = fmaf(hv.x, wv.x, acc);
            acc = fmaf(hv.y, wv.y, acc);
            acc = fmaf(hv.z, wv.z, acc);
            acc = fmaf(hv.w, wv.w, acc);
        }
        lg[r][e] = acc + sbg[e];
    }
    __syncthreads();
    if (tid < 32) {
        const int row = rowBase + tid;
        float l[16];
#pragma unroll
        for (int i = 0; i < 16; ++i) l[i] = lg[tid][i];
        int i1 = 0; float v1 = l[0];
#pragma unroll
        for (int i = 1; i < 16; ++i) if (l[i] > v1) { v1 = l[i]; i1 = i; }
        int i2 = -1; float v2 = -INFINITY;
#pragma unroll
        for (int i = 0; i < 16; ++i) if (i != i1 && l[i] > v2) { v2 = l[i]; i2 = i; }
        const float t = expf(v2 - v1);
        const float s1 = 1.f / (1.f + t);
        const float s2 = t / (1.f + t);
        float p[16]; float S = 0.f;
#pragma unroll
        for (int i = 0; i < 16; ++i) { p[i] = expf(l[i] - v1); S += p[i]; }
        const float inv = 1.f / S;
        float sq = 0.f;
#pragma unroll
        for (int i = 0; i < 16; ++i) { const float q = p[i] * inv; sq = fmaf(q, q, sq); }
        const float var = (sq - 1.0f / 16.0f) * (1.0f / 15.0f);
        const float sd = sqrtf(fmaxf(var, 0.f));

        RInfo ri; ri.e1 = i1; ri.e2 = i2; ri.s1 = s1; ri.s2 = s2;
        info[row] = ri;
        sds[tid] = sd;
        atomicAdd(&hh0[i1], 1);
        atomicAdd(&hh1[i2], 1);
    }
    __syncthreads();
    if (tid == 0) {
        float s = 0.f;
#pragma unroll
        for (int i = 0; i < 32; ++i) s += sds[i];
        atomicAdd(gsum, s);
    }
    if (tid < 16) {
        const int b = blockIdx.x >> 3;              // 256-row super-block
        if (hh0[tid]) atomicAdd(&bc0[tid * 256 + b], hh0[tid]);
        if (hh1[tid]) atomicAdd(&bc1[tid * 256 + b], hh1[tid]);
    }
}

__global__ void zero_meta(int* bc0, int* bc1, float* gsum)
{
    const int idx = blockIdx.x * 256 + threadIdx.x;   // grid 16 -> 4096
    bc0[idx] = 0; bc1[idx] = 0;
    if (idx < 2) gsum[idx] = 0.f;
}

// ------------------------------------------------------------------
// scan: totals + per-block offsets; re-zeros bc for the next layer.
// ------------------------------------------------------------------
__global__ void scan2_kernel(int* __restrict__ bc0, int* __restrict__ bc1,
                             int* cnt0, int* cnt1, int* off0, int* off1,
                             int* __restrict__ bo0, int* __restrict__ bo1)
{
    __shared__ int tot0[NE], tot1[NE], base0[NE], base1[NE];
    const int t = threadIdx.x;
    if (t < NE) {
        int s = 0;
        for (int b = 0; b < 256; ++b) s += bc0[t * 256 + b];
        tot0[t] = s; cnt0[t] = s;
    } else if (t < 2 * NE) {
        const int e = t - NE;
        int s = 0;
        for (int b = 0; b < 256; ++b) s += bc1[e * 256 + b];
        tot1[e] = s; cnt1[e] = s;
    }
    __syncthreads();
    if (t == 0) { int a = 0; for (int e = 0; e < NE; ++e) { base0[e] = a; off0[e] = a; a += tot0[e]; } }
    if (t == 1) { int a = 0; for (int e = 0; e < NE; ++e) { base1[e] = a; off1[e] = a; a += tot1[e]; } }
    __syncthreads();
    if (t < NE) {
        int run = base0[t];
        for (int b = 0; b < 256; ++b) { bo0[t * 256 + b] = run; run += bc0[t * 256 + b]; }
    } else if (t < 2 * NE) {
        const int e = t - NE;
        int run = base1[e];
        for (int b = 0; b < 256; ++b) { bo1[e * 256 + b] = run; run += bc1[e * 256 + b]; }
    }
    __syncthreads();
    for (int i = t; i < NE * 256; i += 64) { bc0[i] = 0; bc1[i] = 0; }
}

__global__ __launch_bounds__(256)
void scatter2_kernel(const RInfo* __restrict__ info, const int* __restrict__ bo0,
                     const int* __restrict__ bo1, int* __restrict__ l0,
                     int* __restrict__ l1)
{
    __shared__ int h0[NE], h1[NE];
    const int tid = threadIdx.x, b = blockIdx.x;
    if (tid < NE) { h0[tid] = 0; h1[tid] = 0; }
    __syncthreads();
    const int r = b * 256 + tid;
    const RInfo ri = info[r];
    const int p0 = atomicAdd(&h0[ri.e1], 1);
    const int p1 = atomicAdd(&h1[ri.e2], 1);
    l0[bo0[ri.e1 * 256 + b] + p0] = r;
    l1[bo1[ri.e2 * 256 + b] + p1] = r;
}

// ------------------------------------------------------------------
// fp32 grouped expert GEMM (MoE layer 1, gate-critical) — EXACT R4 body
// (bit-exact FMA chains). XCD chunk swizzle, Ybf emit.
// ------------------------------------------------------------------
template<int SLOT>
__global__ __launch_bounds__(256)
void gemm_expert(const float* __restrict__ Hin, const float* __restrict__ We,
                 const float* __restrict__ be, const RInfo* __restrict__ info,
                 const int* __restrict__ list, const int* __restrict__ cnts,
                 const int* __restrict__ offs, float* __restrict__ P,
                 short* __restrict__ Ybf)
{
    __shared__ float As[128][36];
    __shared__ float Bs[32][132];
    __shared__ int   rs[128];
    __shared__ float ss[128];

    int c = (blockIdx.x & 7) * CPX + (blockIdx.x >> 3);   // XCD-contiguous chunks
    int e;
    int cnt = 0;
    for (e = 0; e < NE; ++e) {
        cnt = cnts[e];
        const int nch = (cnt + 127) >> 7;
        if (c < nch) break;
        c -= nch;
    }
    if (e >= NE) return;
    const int m = min(128, cnt - c * 128);
    const int base = offs[e] + c * 128;
    const int tid = threadIdx.x;
    const int tx = tid & 15, ty = tid >> 4;
    const int colBase = blockIdx.y * 128;

    if (tid < 128) {
        const int g = list[base + min(tid, m - 1)];
        rs[tid] = g;
        const RInfo ri = info[g];
        ss[tid] = (SLOT == 0) ? ri.s1 : ri.s2;
    }
    __syncthreads();

    const float* B = We + (size_t)e * DH * DH;

    float acc[8][8];
#pragma unroll
    for (int i = 0; i < 8; ++i)
#pragma unroll
        for (int j = 0; j < 8; ++j) acc[i][j] = 0.f;

    for (int kt = 0; kt < DH; kt += 32) {
        {
            const int r = tid >> 3, k4 = (tid & 7) << 2;
#pragma unroll
            for (int it = 0; it < 4; ++it) {
                const int g = rs[r + 32 * it];
                const float4 v = *reinterpret_cast<const float4*>(
                    &Hin[(size_t)g * DH + kt + k4]);
                *reinterpret_cast<float4*>(&As[r + 32 * it][k4]) = v;
            }
        }
        {
            const int kr = tid >> 5, c4 = (tid & 31) << 2;
#pragma unroll
            for (int it = 0; it < 4; ++it) {
                const float4 v = *reinterpret_cast<const float4*>(
                    &B[(size_t)(kt + kr + 8 * it) * DH + colBase + c4]);
                *reinterpret_cast<float4*>(&Bs[kr + 8 * it][c4]) = v;
            }
        }
        __syncthreads();
#pragma unroll
        for (int k4 = 0; k4 < 32; k4 += 4) {
            alignas(16) float ar[8][4];
#pragma unroll
            for (int i = 0; i < 8; ++i)
                *reinterpret_cast<float4*>(ar[i]) =
                    *reinterpret_cast<const float4*>(&As[ty * 8 + i][k4]);
#pragma unroll
            for (int kk = 0; kk < 4; ++kk) {
                alignas(16) float br[8];
                *reinterpret_cast<float4*>(&br[0]) =
                    *reinterpret_cast<const float4*>(&Bs[k4 + kk][tx * 8]);
                *reinterpret_cast<float4*>(&br[4]) =
                    *reinterpret_cast<const float4*>(&Bs[k4 + kk][tx * 8 + 4]);
#pragma unroll
                for (int i = 0; i < 8; ++i) {
                    const float a = ar[i][kk];
#pragma unroll
                    for (int j = 0; j < 8; ++j)
                        acc[i][j] = fmaf(a, br[j], acc[i][j]);
                }
            }
        }
        __syncthreads();
    }

    alignas(16) float bb[8];
#pragma unroll
    for (int j = 0; j < 8; ++j) bb[j] = be[(size_t)e * DH + colBase + tx * 8 + j];
#pragma unroll
    for (int i = 0; i < 8; ++i) {
        const int rl = ty * 8 + i;
        if (rl < m) {
            const int g = rs[rl];
            const float s = ss[rl];
            alignas(16) float o[8];
#pragma unroll
            for (int j = 0; j < 8; ++j) o[j] = s * (acc[i][j] + bb[j]);
            float* pp = &P[(size_t)g * DH + colBase + tx * 8];
            if (SLOT == 0) {
                *reinterpret_cast<float4*>(pp)     = *reinterpret_cast<float4*>(&o[0]);
                *reinterpret_cast<float4*>(pp + 4) = *reinterpret_cast<float4*>(&o[4]);
            } else {
                const float4 p0 = *reinterpret_cast<const float4*>(pp);
                const float4 p1 = *reinterpret_cast<const float4*>(pp + 4);
                alignas(16) float h[8];
                h[0] = fmaxf(o[0] + p0.x, 0.f); h[1] = fmaxf(o[1] + p0.y, 0.f);
                h[2] = fmaxf(o[2] + p0.z, 0.f); h[3] = fmaxf(o[3] + p0.w, 0.f);
                h[4] = fmaxf(o[4] + p1.x, 0.f); h[5] = fmaxf(o[5] + p1.y, 0.f);
                h[6] = fmaxf(o[6] + p1.z, 0.f); h[7] = fmaxf(o[7] + p1.w, 0.f);
                *reinterpret_cast<float4*>(pp)     = *reinterpret_cast<float4*>(&h[0]);
                *reinterpret_cast<float4*>(pp + 4) = *reinterpret_cast<float4*>(&h[4]);
                if (Ybf) {
                    bh8 yb;
#pragma unroll
                    for (int j = 0; j < 8; ++j) yb[j] = f2bf(h[j]);
                    *reinterpret_cast<bh8*>(&Ybf[(size_t)g * DH + colBase + tx * 8]) = yb;
                }
            }
        }
    }
}

// ------------------------------------------------------------------
// Weight transpose+convert: W[K][N] fp32 -> WT[N][K] bf16 (per z-slab)
// ------------------------------------------------------------------
__global__ __launch_bounds__(256)
void transp_bf16(const float* __restrict__ W, short* __restrict__ WT,
                 int K, int N)
{
    __shared__ float t[32][33];
    const int k0 = blockIdx.x * 32, n0 = blockIdx.y * 32;
    const size_t off = (size_t)blockIdx.z * K * N;
    const int c = threadIdx.x & 31, r8 = threadIdx.x >> 5;
#pragma unroll
    for (int it = 0; it < 4; ++it) {
        const int r = r8 + it * 8;
        t[r][c] = W[off + (size_t)(k0 + r) * N + n0 + c];
    }
    __syncthreads();
#pragma unroll
    for (int it = 0; it < 4; ++it) {
        const int r = r8 + it * 8;
        WT[off + (size_t)(n0 + r) * K + k0 + c] = f2bf(t[c][r]);
    }
}

// ------------------------------------------------------------------
// bf16-MFMA grouped expert GEMM (MoE layer 2) — double-buffered LDS,
// ONE barrier per K-step; next-tile loads issued before MFMA (latency
// hides under compute). MFMA accumulation order unchanged -> bit-exact.
// BFA=1: A from pre-converted bf16; SLOT1+BFA writes Hbf.
// ------------------------------------------------------------------
template<int SLOT, int BFA>
__global__ __launch_bounds__(256)
void gemm_expert_bf16(const float* __restrict__ Yf, const short* __restrict__ Abf,
                      const short* __restrict__ WeT,
                      const float* __restrict__ be, const RInfo* __restrict__ info,
                      const int* __restrict__ list, const int* __restrict__ cnts,
                      const int* __restrict__ offs, float* __restrict__ P,
                      short* __restrict__ Hbf)
{
    __shared__ bh8 As8[2][512];
    __shared__ bh8 Bs8[2][512];
    __shared__ int   rs[128];
    __shared__ float ss[128];

    int c = (blockIdx.x & 7) * CPX + (blockIdx.x >> 3);
    int e;
    int cnt = 0;
    for (e = 0; e < NE; ++e) {
        cnt = cnts[e];
        const int nch = (cnt + 127) >> 7;
        if (c < nch) break;
        c -= nch;
    }
    if (e >= NE) return;
    const int m = min(128, cnt - c * 128);
    const int base = offs[e] + c * 128;
    const int tid = threadIdx.x;

    if (tid < 128) {
        const int g = list[base + min(tid, m - 1)];
        rs[tid] = g;
        const RInfo ri = info[g];
        ss[tid] = (SLOT == 0) ? ri.s1 : ri.s2;
    }
    __syncthreads();

    const int colBase = blockIdx.y * 128;
    const int lane = tid & 63, wave = tid >> 6;
    const int wr = wave >> 1, wc = wave & 1;
    const short* Bw = WeT + (size_t)e * DH * DH;

    fx4 acc[4][4];
    const fx4 z = {0.f, 0.f, 0.f, 0.f};
#pragma unroll
    for (int i = 0; i < 4; ++i)
#pragma unroll
        for (int j = 0; j < 4; ++j) acc[i][j] = z;

    const int d0 = tid, d1 = tid + 256;
    const int ar0 = d0 >> 2, ak0 = d0 & 3;
    const int ar1 = d1 >> 2, ak1 = d1 & 3;
    const int g0 = ar0 * 4 + (ak0 ^ ((ar0 >> 1) & 3));
    const int g1 = ar1 * 4 + (ak1 ^ ((ar1 >> 1) & 3));
    const size_t arow0 = (size_t)rs[ar0] * DH, arow1 = (size_t)rs[ar1] * DH;
    const size_t brow0 = (size_t)(colBase + ar0) * DH, brow1 = (size_t)(colBase + ar1) * DH;

    // prologue: stage tile 0 into buffer 0
    if (BFA) {
        As8[0][g0] = *reinterpret_cast<const bh8*>(&Abf[arow0 + ak0 * 8]);
        As8[0][g1] = *reinterpret_cast<const bh8*>(&Abf[arow1 + ak1 * 8]);
    } else {
        const float4 f0 = *reinterpret_cast<const float4*>(&Yf[arow0 + ak0 * 8]);
        const float4 f1 = *reinterpret_cast<const float4*>(&Yf[arow0 + ak0 * 8 + 4]);
        bh8 v;
        v[0]=f2bf(f0.x); v[1]=f2bf(f0.y); v[2]=f2bf(f0.z); v[3]=f2bf(f0.w);
        v[4]=f2bf(f1.x); v[5]=f2bf(f1.y); v[6]=f2bf(f1.z); v[7]=f2bf(f1.w);
        As8[0][g0] = v;
        const float4 f2 = *reinterpret_cast<const float4*>(&Yf[arow1 + ak1 * 8]);
        const float4 f3 = *reinterpret_cast<const float4*>(&Yf[arow1 + ak1 * 8 + 4]);
        bh8 w;
        w[0]=f2bf(f2.x); w[1]=f2bf(f2.y); w[2]=f2bf(f2.z); w[3]=f2bf(f2.w);
        w[4]=f2bf(f3.x); w[5]=f2bf(f3.y); w[6]=f2bf(f3.z); w[7]=f2bf(f3.w);
        As8[0][g1] = w;
    }
    Bs8[0][g0] = *reinterpret_cast<const bh8*>(&Bw[brow0 + ak0 * 8]);
    Bs8[0][g1] = *reinterpret_cast<const bh8*>(&Bw[brow1 + ak1 * 8]);
    __syncthreads();

    for (int kti = 0; kti < 8; ++kti) {
        const int cur = kti & 1;
        const int ktn = (kti + 1) * 32;
        const bool more = (kti < 7);

        // issue next-tile global loads (latency hides under MFMA below)
        bh8 pA0, pA1, pb0, pb1;
        float4 fa0, fa1, fa2, fa3;
        if (more) {
            if (BFA) {
                pA0 = *reinterpret_cast<const bh8*>(&Abf[arow0 + ktn + ak0 * 8]);
                pA1 = *reinterpret_cast<const bh8*>(&Abf[arow1 + ktn + ak1 * 8]);
            } else {
                fa0 = *reinterpret_cast<const float4*>(&Yf[arow0 + ktn + ak0 * 8]);
                fa1 = *reinterpret_cast<const float4*>(&Yf[arow0 + ktn + ak0 * 8 + 4]);
                fa2 = *reinterpret_cast<const float4*>(&Yf[arow1 + ktn + ak1 * 8]);
                fa3 = *reinterpret_cast<const float4*>(&Yf[arow1 + ktn + ak1 * 8 + 4]);
            }
            pb0 = *reinterpret_cast<const bh8*>(&Bw[brow0 + ktn + ak0 * 8]);
            pb1 = *reinterpret_cast<const bh8*>(&Bw[brow1 + ktn + ak1 * 8]);
        }

        const int kq = lane >> 4, lm = lane & 15;
        bh8 af[4], bfr[4];
#pragma unroll
        for (int i = 0; i < 4; ++i) {
            const int rl = wr * 64 + i * 16 + lm;
            af[i] = As8[cur][rl * 4 + (kq ^ ((rl >> 1) & 3))];
            const int cl = wc * 64 + i * 16 + lm;
            bfr[i] = Bs8[cur][cl * 4 + (kq ^ ((cl >> 1) & 3))];
        }
#pragma unroll
        for (int i = 0; i < 4; ++i)
#pragma unroll
            for (int j = 0; j < 4; ++j)
                acc[i][j] = __builtin_amdgcn_mfma_f32_16x16x32_bf16(
                    af[i], bfr[j], acc[i][j], 0, 0, 0);

        if (more) {
            if (BFA) {
                As8[cur ^ 1][g0] = pA0;
                As8[cur ^ 1][g1] = pA1;
            } else {
                bh8 v;
                v[0]=f2bf(fa0.x); v[1]=f2bf(fa0.y); v[2]=f2bf(fa0.z); v[3]=f2bf(fa0.w);
                v[4]=f2bf(fa1.x); v[5]=f2bf(fa1.y); v[6]=f2bf(fa1.z); v[7]=f2bf(fa1.w);
                As8[cur ^ 1][g0] = v;
                bh8 w;
                w[0]=f2bf(fa2.x); w[1]=f2bf(fa2.y); w[2]=f2bf(fa2.z); w[3]=f2bf(fa2.w);
                w[4]=f2bf(fa3.x); w[5]=f2bf(fa3.y); w[6]=f2bf(fa3.z); w[7]=f2bf(fa3.w);
                As8[cur ^ 1][g1] = w;
            }
            Bs8[cur ^ 1][g0] = pb0;
            Bs8[cur ^ 1][g1] = pb1;
        }
        __syncthreads();
    }

    const int rq = lane >> 4, lm = lane & 15;
#pragma unroll
    for (int i = 0; i < 4; ++i) {
#pragma unroll
        for (int j = 0; j < 4; ++j) {
            const int rl = wr * 64 + i * 16 + rq * 4 + j;
            if (rl < m) {
                const int g = rs[rl];
                const float s = ss[rl];
#pragma unroll
                for (int nf = 0; nf < 4; ++nf) {
                    const int cl = colBase + wc * 64 + nf * 16 + lm;
                    float* pp = &P[(size_t)g * DH + cl];
                    const float o = s * (acc[i][nf][j] + be[(size_t)e * DH + cl]);
                    if (SLOT == 0) {
                        *pp = o;
                    } else {
                        const float v = fmaxf(*pp + o, 0.f);
                        if (BFA) Hbf[(size_t)g * DH + cl] = f2bf(v);
                        else     *pp = v;
                    }
                }
            }
        }
    }
}

// ------------------------------------------------------------------
// bf16-MFMA final GEMM — same double-buffer structure. BFA=1 reads bf16 H.
// ------------------------------------------------------------------
template<int BFA>
__global__ __launch_bounds__(256)
void gemm_final_bf16(const float* __restrict__ Hf, const short* __restrict__ Habf,
                     const short* __restrict__ WT,
                     const float* __restrict__ bias, float* __restrict__ C,
                     const float* gsum, float* scalar_out)
{
    __shared__ bh8 As8[2][512];
    __shared__ bh8 Bs8[2][512];
    const int tid = threadIdx.x;
    const int rowBase = blockIdx.x * 128;

    if (blockIdx.x == 0 && tid == 0)
        *scalar_out = (gsum[0] + gsum[1]) * (0.5f / (float)NT);

    const int lane = tid & 63, wave = tid >> 6;
    const int wr = wave >> 1, wc = wave & 1;

    fx4 acc[4][4];
    const fx4 z = {0.f, 0.f, 0.f, 0.f};
#pragma unroll
    for (int i = 0; i < 4; ++i)
#pragma unroll
        for (int j = 0; j < 4; ++j) acc[i][j] = z;

    const int d0 = tid, d1 = tid + 256;
    const int ar0 = d0 >> 2, ak0 = d0 & 3;
    const int ar1 = d1 >> 2, ak1 = d1 & 3;
    const int g0 = ar0 * 4 + (ak0 ^ ((ar0 >> 1) & 3));
    const int g1 = ar1 * 4 + (ak1 ^ ((ar1 >> 1) & 3));
    const size_t arow0 = (size_t)(rowBase + ar0) * DH, arow1 = (size_t)(rowBase + ar1) * DH;
    const size_t brow0 = (size_t)ar0 * DH, brow1 = (size_t)ar1 * DH;

    if (BFA) {
        As8[0][g0] = *reinterpret_cast<const bh8*>(&Habf[arow0 + ak0 * 8]);
        As8[0][g1] = *reinterpret_cast<const bh8*>(&Habf[arow1 + ak1 * 8]);
    } else {
        const float4 f0 = *reinterpret_cast<const float4*>(&Hf[arow0 + ak0 * 8]);
        const float4 f1 = *reinterpret_cast<const float4*>(&Hf[arow0 + ak0 * 8 + 4]);
        bh8 v;
        v[0]=f2bf(f0.x); v[1]=f2bf(f0.y); v[2]=f2bf(f0.z); v[3]=f2bf(f0.w);
        v[4]=f2bf(f1.x); v[5]=f2bf(f1.y); v[6]=f2bf(f1.z); v[7]=f2bf(f1.w);
        As8[0][g0] = v;
        const float4 f2 = *reinterpret_cast<const float4*>(&Hf[arow1 + ak1 * 8]);
        const float4 f3 = *reinterpret_cast<const float4*>(&Hf[arow1 + ak1 * 8 + 4]);
        bh8 w;
        w[0]=f2bf(f2.x); w[1]=f2bf(f2.y); w[2]=f2bf(f2.z); w[3]=f2bf(f2.w);
        w[4]=f2bf(f3.x); w[5]=f2bf(f3.y); w[6]=f2bf(f3.z); w[7]=f2bf(f3.w);
        As8[0][g1] = w;
    }
    Bs8[0][g0] = *reinterpret_cast<const bh8*>(&WT[brow0 + ak0 * 8]);
    Bs8[0][g1] = *reinterpret_cast<const bh8*>(&WT[brow1 + ak1 * 8]);
    __syncthreads();

    for (int kti = 0; kti < 8; ++kti) {
        const int cur = kti & 1;
        const int ktn = (kti + 1) * 32;
        const bool more = (kti < 7);

        bh8 pA0, pA1, pb0, pb1;
        float4 fa0, fa1, fa2, fa3;
        if (more) {
            if (BFA) {
                pA0 = *reinterpret_cast<const bh8*>(&Habf[arow0 + ktn + ak0 * 8]);
                pA1 = *reinterpret_cast<const bh8*>(&Habf[arow1 + ktn + ak1 * 8]);
            } else {
                fa0 = *reinterpret_cast<const float4*>(&Hf[arow0 + ktn + ak0 * 8]);
                fa1 = *reinterpret_cast<const float4*>(&Hf[arow0 + ktn + ak0 * 8 + 4]);
                fa2 = *reinterpret_cast<const float4*>(&Hf[arow1 + ktn + ak1 * 8]);
                fa3 = *reinterpret_cast<const float4*>(&Hf[arow1 + ktn + ak1 * 8 + 4]);
            }
            pb0 = *reinterpret_cast<const bh8*>(&WT[brow0 + ktn + ak0 * 8]);
            pb1 = *reinterpret_cast<const bh8*>(&WT[brow1 + ktn + ak1 * 8]);
        }

        const int kq = lane >> 4, lm = lane & 15;
        bh8 af[4], bfr[4];
#pragma unroll
        for (int i = 0; i < 4; ++i) {
            const int rl = wr * 64 + i * 16 + lm;
            af[i] = As8[cur][rl * 4 + (kq ^ ((rl >> 1) & 3))];
            const int cl = wc * 64 + i * 16 + lm;
            bfr[i] = Bs8[cur][cl * 4 + (kq ^ ((cl >> 1) & 3))];
        }
#pragma unroll
        for (int i = 0; i < 4; ++i)
#pragma unroll
            for (int j = 0; j < 4; ++j)
                acc[i][j] = __builtin_amdgcn_mfma_f32_16x16x32_bf16(
                    af[i], bfr[j], acc[i][j], 0, 0, 0);

        if (more) {
            if (BFA) {
                As8[cur ^ 1][g0] = pA0;
                As8[cur ^ 1][g1] = pA1;
            } else {
                bh8 v;
                v[0]=f2bf(fa0.x); v[1]=f2bf(fa0.y); v[2]=f2bf(fa0.z); v[3]=f2bf(fa0.w);
                v[4]=f2bf(fa1.x); v[5]=f2bf(fa1.y); v[6]=f2bf(fa1.z); v[7]=f2bf(fa1.w);
                As8[cur ^ 1][g0] = v;
                bh8 w;
                w[0]=f2bf(fa2.x); w[1]=f2bf(fa2.y); w[2]=f2bf(fa2.z); w[3]=f2bf(fa2.w);
                w[4]=f2bf(fa3.x); w[5]=f2bf(fa3.y); w[6]=f2bf(fa3.z); w[7]=f2bf(fa3.w);
                As8[cur ^ 1][g1] = w;
            }
            Bs8[cur ^ 1][g0] = pb0;
            Bs8[cur ^ 1][g1] = pb1;
        }
        __syncthreads();
    }

    const int rq = lane >> 4, lm = lane & 15;
#pragma unroll
    for (int i = 0; i < 4; ++i) {
#pragma unroll
        for (int j = 0; j < 4; ++j) {
            const int rl = rowBase + wr * 64 + i * 16 + rq * 4 + j;
#pragma unroll
            for (int nf = 0; nf < 4; ++nf) {
                const int cl = wc * 64 + nf * 16 + lm;
                C[(size_t)rl * DO + cl] = acc[i][nf][j] + bias[cl];
            }
        }
    }
}

// ------------------------------------------------------------------
extern "C" void kernel_launch(void* const* d_in, const int* in_sizes, int n_in,
                              void* d_out, int out_size, void* d_ws, size_t ws_size,
                              hipStream_t stream)
{
    const float* x   = (const float*)d_in[0];
    const float* W0  = (const float*)d_in[1];
    const float* b0  = (const float*)d_in[2];
    const float* Wg1 = (const float*)d_in[3];
    const float* bg1 = (const float*)d_in[4];
    const float* We1 = (const float*)d_in[5];
    const float* be1 = (const float*)d_in[6];
    const float* Wg2 = (const float*)d_in[7];
    const float* bg2 = (const float*)d_in[8];
    const float* We2 = (const float*)d_in[9];
    const float* be2 = (const float*)d_in[10];
    const float* Wf  = (const float*)d_in[11];
    const float* bf  = (const float*)d_in[12];
    float* out = (float*)d_out;

    char* w = (char*)d_ws;
    float* H    = (float*)w; w += (size_t)NT * DH * 4;
    float* Y    = (float*)w; w += (size_t)NT * DH * 4;
    RInfo* info = (RInfo*)w; w += (size_t)NT * sizeof(RInfo);
    int* l0   = (int*)w; w += (size_t)NT * 4;
    int* l1   = (int*)w; w += (size_t)NT * 4;
    int* bc0  = (int*)w; w += NE * 256 * 4;
    int* bc1  = (int*)w; w += NE * 256 * 4;
    int* bo0  = (int*)w; w += NE * 256 * 4;
    int* bo1  = (int*)w; w += NE * 256 * 4;
    int* cnt0 = (int*)w; w += 64;
    int* cnt1 = (int*)w; w += 64;
    int* off0 = (int*)w; w += 64;
    int* off1 = (int*)w; w += 64;
    float* gsum = (float*)w; w += 64;
    short* WeT = (short*)w; w += (size_t)NE * DH * DH * 2;   // 2 MB
    short* WfT = (short*)w; w += (size_t)DH * DO * 2;        // 64 KB
    short* Ybf = (short*)w; w += (size_t)NT * DH * 2;        // 33.5 MB (optional)
    const bool roomy = (size_t)(w - (char*)d_ws) <= ws_size;
    short* Hbf = (short*)Y;   // aliases Y: Y fp32 dead after gate2 in roomy path

    zero_meta<<<dim3(16), dim3(256), 0, stream>>>(bc0, bc1, gsum);
    transp_bf16<<<dim3(8, 8, 16), dim3(256), 0, stream>>>(We2, WeT, DH, DH);
    transp_bf16<<<dim3(8, 4, 1),  dim3(256), 0, stream>>>(Wf,  WfT, DH, DO);

    // layer 0 (fp32, gate-critical): H = relu(x @ W0 + b0)
    gemm_dense<true><<<dim3(NT / 128, 2), dim3(256), 0, stream>>>(x, W0, b0, H, DH);

    // MoE layer 1 (fp32, gate-critical): read H, build Y (+Ybf)
    gate_kernel<<<dim3(NT / 32), dim3(256), 0, stream>>>(H, Wg1, bg1, info, &gsum[0], bc0, bc1);
    scan2_kernel<<<dim3(1), dim3(64), 0, stream>>>(bc0, bc1, cnt0, cnt1, off0, off1, bo0, bo1);
    scatter2_kernel<<<dim3(NT / 256), dim3(256), 0, stream>>>(info, bo0, bo1, l0, l1);
    gemm_expert<0><<<dim3(MAXCH, 2), dim3(256), 0, stream>>>(H, We1, be1, info, l0, cnt0, off0, Y, nullptr);
    gemm_expert<1><<<dim3(MAXCH, 2), dim3(256), 0, stream>>>(H, We1, be1, info, l1, cnt1, off1, Y,
                                                             roomy ? Ybf : nullptr);

    // MoE layer 2 (bf16 MFMA, output path): read Y/Ybf, build H/Hbf
    gate_kernel<<<dim3(NT / 32), dim3(256), 0, stream>>>(Y, Wg2, bg2, info, &gsum[1], bc0, bc1);
    scan2_kernel<<<dim3(1), dim3(64), 0, stream>>>(bc0, bc1, cnt0, cnt1, off0, off1, bo0, bo1);
    scatter2_kernel<<<dim3(NT / 256), dim3(256), 0, stream>>>(info, bo0, bo1, l0, l1);
    if (roomy) {
        gemm_expert_bf16<0,1><<<dim3(MAXCH, 2), dim3(256), 0, stream>>>(Y, Ybf, WeT, be2, info, l0, cnt0, off0, H, nullptr);
        gemm_expert_bf16<1,1><<<dim3(MAXCH, 2), dim3(256), 0, stream>>>(Y, Ybf, WeT, be2, info, l1, cnt1, off1, H, Hbf);
        gemm_final_bf16<1><<<dim3(NT / 128), dim3(256), 0, stream>>>(H, Hbf, WfT, bf, out, gsum, out + (size_t)NT * DO);
    } else {
        gemm_expert_bf16<0,0><<<dim3(MAXCH, 2), dim3(256), 0, stream>>>(Y, nullptr, WeT, be2, info, l0, cnt0, off0, H, nullptr);
        gemm_expert_bf16<1,0><<<dim3(MAXCH, 2), dim3(256), 0, stream>>>(Y, nullptr, WeT, be2, info, l1, cnt1, off1, H, nullptr);
        gemm_final_bf16<0><<<dim3(NT / 128), dim3(256), 0, stream>>>(H, nullptr, WfT, bf, out, gsum, out + (size_t)NT * DO);
    }
}